// Round 12
// baseline (157.803 us; speedup 1.0000x reference)
//
#include <hip/hip_runtime.h>
#include <math.h>

#define D_MODEL 32
#define S_LEN   2048
#define B_SZ    8
#define NTOK    (B_SZ * S_LEN)
#define LN_EPS  1e-5f
#define LOG2E   1.44269504088896340736f
#define QK_SCALE 0.35355339059327373f   /* 1/sqrt(8) */
#define MASKV   (-1.0e9f)               /* v_exp_f32(-1e9) == 0 */

typedef __attribute__((ext_vector_type(8)))  short    short8b;
typedef __attribute__((ext_vector_type(4)))  short    short4b;
typedef __attribute__((ext_vector_type(4)))  unsigned uint4v;
typedef __attribute__((ext_vector_type(16))) float    f32x16;

__device__ __forceinline__ unsigned short f2bf(float f) {   // RNE f32->bf16
    unsigned u = __builtin_bit_cast(unsigned, f);
    unsigned r = (u + 0x7FFFu + ((u >> 16) & 1u)) >> 16;
    return (unsigned short)r;
}
__device__ __forceinline__ float bf2f(unsigned short h) {
    return __builtin_bit_cast(float, (unsigned)h << 16);
}
__device__ __forceinline__ unsigned cvtpk_bf16(float lo, float hi) {
    unsigned r;
    asm("v_cvt_pk_bf16_f32 %0, %1, %2" : "=v"(r) : "v"(lo), "v"(hi));
    return r;
}

// ---------------------------------------------------------------------------
// QKV projection. Q (pre-scaled by 1/sqrt(8)*log2e) and K are stored as
// SPLIT bf16 (hi = bf16(x), lo = bf16(x - hi)) so QK^T can be computed
// exactly with two MFMAs. V stored transposed per head, single bf16.
__global__ __launch_bounds__(256) void proj_kernel(
    const float* __restrict__ xQ, const float* __restrict__ xK,
    const float* __restrict__ xV,
    const float* __restrict__ WQ, const float* __restrict__ bQ,
    const float* __restrict__ WK, const float* __restrict__ bK,
    const float* __restrict__ WV, const float* __restrict__ bV,
    unsigned short* __restrict__ Qh, unsigned short* __restrict__ Ql,
    unsigned short* __restrict__ Kh, unsigned short* __restrict__ Kl,
    unsigned short* __restrict__ Vt)
{
    const float* x; const float* W; const float* bias; float scale;
    if (blockIdx.y == 0)      { x = xQ; W = WQ; bias = bQ; scale = QK_SCALE * LOG2E; }
    else if (blockIdx.y == 1) { x = xK; W = WK; bias = bK; scale = 1.0f; }
    else                      { x = xV; W = WV; bias = bV; scale = 1.0f; }

    __shared__ float xs[8][32];
    __shared__ float Ws[32][32];
    int t = threadIdx.x;
    long base = (long)blockIdx.x * 256;    // 8 rows x 32 cols
    xs[t >> 5][t & 31] = x[base + t];
#pragma unroll
    for (int i = 0; i < 4; ++i) {
        int f = i * 256 + t;
        Ws[f >> 5][f & 31] = W[f];
    }
    __syncthreads();
    int r = t >> 5, j = t & 31;
    float acc = bias[j];
#pragma unroll
    for (int i = 0; i < 32; ++i) acc = fmaf(xs[r][i], Ws[i][j], acc);
    acc *= scale;

    if (blockIdx.y == 0) {
        unsigned short hv = f2bf(acc);
        Qh[base + t] = hv;
        Ql[base + t] = f2bf(acc - bf2f(hv));
    } else if (blockIdx.y == 1) {
        unsigned short hv = f2bf(acc);
        Kh[base + t] = hv;
        Kl[base + t] = f2bf(acc - bf2f(hv));
    } else {
        long tok = (long)blockIdx.x * 8 + r;
        long b   = tok >> 11;
        long ti  = tok & (S_LEN - 1);
        int  h   = j >> 3, dv = j & 7;
        Vt[((b * 4 + h) * 8 + dv) * S_LEN + ti] = f2bf(acc);
    }
}

// ---------------------------------------------------------------------------
// MFMA flash attention, fused mask via in-kernel ballot bit-pack (no-max,
// exp2 domain, split-K, exact QK via split-bf16).
// Block = 4 waves = 4 consecutive 32-q tiles of one (b, seg). Prologue:
// block cooperatively stages its 128-row x SEGLEN mask tile -> LDS bits
// (coalesced lane=key reads + __ballot; HBM touches mask exactly once).
// Main loop per 32-key chunk: madd from LDS bits (R10-verified extraction),
// then per head: 2 QK MFMA -> exp2(acc+madd) -> cvt_pk bf16 -> 2 PV MFMA.
template<int NSEG>
__global__ __launch_bounds__(256) void attn_kernel(
    const unsigned short* __restrict__ Qh, const unsigned short* __restrict__ Ql,
    const unsigned short* __restrict__ Kh, const unsigned short* __restrict__ Kl,
    const unsigned short* __restrict__ Vt, const void* __restrict__ mask,
    float* __restrict__ pl, float* __restrict__ pctx)
{
    constexpr int SEGLEN  = S_LEN / NSEG;
    constexpr int NCH     = SEGLEN / 32;
    constexpr int NWORDS  = SEGLEN / 64;
    constexpr int WSTRIDE = NWORDS + 1;          // odd -> 2-way LDS conflict (free)
    __shared__ unsigned long long Mbits[128 * WSTRIDE];

    const int nb = NSEG * 16;                    // blocks per batch
    int raw   = blockIdx.x;
    int total = B_SZ * nb;
    int cpx   = total >> 3;
    int cid   = (raw & 7) * cpx + (raw >> 3);    // XCD-contiguous
    int b     = cid / nb;
    int rem   = cid - b * nb;
    int seg   = rem >> 4;
    int qt0   = (rem & 15) * 4;
    int widx  = threadIdx.x >> 6;
    int lane  = threadIdx.x & 63;
    int q     = lane & 31;
    int half  = lane >> 5;
    long tokbase = (long)b * S_LEN + qt0 * 32;   // block's first mask row
    long tokq    = tokbase + widx * 32 + q;      // this lane's q-row
    int k0    = seg * SEGLEN;

    // ---- inline mask dtype probe (proven in R11): int32 => upper 3 bytes 0
    int probe = ((const int*)mask)[lane];
    bool is32 = (__ballot((probe & ~0xFF) == 0) == ~0ULL);

    // ---- stage block's mask tile as bits: rows 0..127, words 0..NWORDS-1
    if (is32) {
        const int* m32 = (const int*)mask;
#pragma unroll 4
        for (int it = 0; it < 128 * NWORDS / 4; ++it) {
            int p = it * 4 + widx;
            int r = p >> (NWORDS == 1 ? 0 : (NWORDS == 2 ? 1 : (NWORDS == 4 ? 2 : (NWORDS == 8 ? 3 : 5))));
            int w = p & (NWORDS - 1);
            int v = m32[(tokbase + r) * S_LEN + k0 + w * 64 + lane];
            unsigned long long wv = __ballot(v != 0);
            if (lane == 0) Mbits[r * WSTRIDE + w] = wv;
        }
    } else {
        const unsigned char* m8 = (const unsigned char*)mask;
#pragma unroll 4
        for (int it = 0; it < 128 * NWORDS / 4; ++it) {
            int p = it * 4 + widx;
            int r = p >> (NWORDS == 1 ? 0 : (NWORDS == 2 ? 1 : (NWORDS == 4 ? 2 : (NWORDS == 8 ? 3 : 5))));
            int w = p & (NWORDS - 1);
            unsigned char v = m8[(tokbase + r) * S_LEN + k0 + w * 64 + lane];
            unsigned long long wv = __ballot(v != 0);
            if (lane == 0) Mbits[r * WSTRIDE + w] = wv;
        }
    }
    __syncthreads();

    f32x16 zero16;
#pragma unroll
    for (int i = 0; i < 16; ++i) zero16[i] = 0.0f;

    short8b qhf[4], qlf[4];
#pragma unroll
    for (int h = 0; h < 4; ++h) {
        qhf[h] = *(const short8b*)(Qh + tokq * 32 + h * 8);
        qlf[h] = *(const short8b*)(Ql + tokq * 32 + h * 8);
    }
    f32x16 cpv[4];
#pragma unroll
    for (int h = 0; h < 4; ++h) cpv[h] = zero16;

    const unsigned short* Ksel = (half ? Kl : Kh) + (long)b * S_LEN * 32;
    const unsigned long long* myrow = &Mbits[(widx * 32 + q) * WSTRIDE];

#pragma unroll 1
    for (int ch = 0; ch < NCH; ++ch) {
        int kc = k0 + ch * 32;

        unsigned long long wv = myrow[ch >> 1];
        unsigned wh  = (ch & 1) ? (unsigned)(wv >> 32) : (unsigned)wv;
        unsigned wsh = wh >> (half * 4);
        float madd[16];
#pragma unroll
        for (int r = 0; r < 16; ++r) {
            const int cr = (r & 3) + 8 * (r >> 2);
            madd[r] = ((wsh >> cr) & 1u) ? MASKV : 0.0f;
        }

#pragma unroll
        for (int h = 0; h < 4; ++h) {
            // A rows m=lane&31 -> key kc+q; half0 supplies K_hi (k-slots 0-7),
            // half1 supplies K_lo (k-slots 8-15), both at d0-7 of head h.
            short8b kf = *(const short8b*)(Ksel + (long)(kc + q) * 32 + h * 8);
            f32x16 acc = __builtin_amdgcn_mfma_f32_32x32x16_bf16(kf, qhf[h], zero16, 0, 0, 0);
            acc = __builtin_amdgcn_mfma_f32_32x32x16_bf16(kf, qlf[h], acc, 0, 0, 0);

            unsigned pr[8];
#pragma unroll
            for (int j = 0; j < 8; ++j) {
                float p0 = __builtin_amdgcn_exp2f(acc[2 * j]     + madd[2 * j]);
                float p1 = __builtin_amdgcn_exp2f(acc[2 * j + 1] + madd[2 * j + 1]);
                pr[j] = cvtpk_bf16(p0, p1);
            }
            uint4v t1, t2;
            t1.x = pr[0]; t1.y = pr[1]; t1.z = pr[2]; t1.w = pr[3];
            t2.x = pr[4]; t2.y = pr[5]; t2.z = pr[6]; t2.w = pr[7];
            short8b pfa = __builtin_bit_cast(short8b, t1);
            short8b pfb = __builtin_bit_cast(short8b, t2);

            // V^T A-frags mirror P's (half, elem)->key mapping exactly, so the
            // shared k-slot permutation cancels regardless of HW slot order.
            short8b vf1, vf2;
            if (q < 8) {
                const unsigned short* vr =
                    Vt + (((long)b * 4 + h) * 8 + q) * S_LEN + kc + half * 4;
                short4b a0 = *(const short4b*)(vr);
                short4b a1 = *(const short4b*)(vr + 8);
                short4b a2 = *(const short4b*)(vr + 16);
                short4b a3 = *(const short4b*)(vr + 24);
                vf1 = __builtin_shufflevector(a0, a1, 0, 1, 2, 3, 4, 5, 6, 7);
                vf2 = __builtin_shufflevector(a2, a3, 0, 1, 2, 3, 4, 5, 6, 7);
            } else {
                short ov = (q == 8) ? (short)0x3F80 : (short)0;  // ones row -> l-sum
#pragma unroll
                for (int i = 0; i < 8; ++i) { vf1[i] = ov; vf2[i] = ov; }
            }
            cpv[h] = __builtin_amdgcn_mfma_f32_32x32x16_bf16(vf1, pfa, cpv[h], 0, 0, 0);
            cpv[h] = __builtin_amdgcn_mfma_f32_32x32x16_bf16(vf2, pfb, cpv[h], 0, 0, 0);
        }
    }

    // C_PV: col=q; lower half regs0-3 = dv0-3, reg4 = row8 = l-sum;
    // upper half regs0-3 = dv4-7.
#pragma unroll
    for (int h = 0; h < 4; ++h) {
        float4 cv = make_float4(cpv[h][0], cpv[h][1], cpv[h][2], cpv[h][3]);
        *(float4*)(pctx + ((size_t)seg * NTOK + tokq) * 32 + h * 8 + half * 4) = cv;
        if (half == 0)
            pl[(size_t)seg * NTOK * 4 + tokq * 4 + h] = cpv[h][4];
    }
}

// ---------------------------------------------------------------------------
// Merge split-K partials (plain sums) -> sa; attn_out = sa@WO + bO + resid; LN.
template<int NSEG>
__global__ __launch_bounds__(256) void combine_epilogue(
    const float* __restrict__ pl, const float* __restrict__ pctx,
    const float* __restrict__ WO, const float* __restrict__ bO,
    const float* __restrict__ resid,
    float* __restrict__ sa_out, float* __restrict__ out0)
{
    __shared__ float sas[8][32];
    __shared__ float Ws[32][32];
    int t = threadIdx.x;
    long base = (long)blockIdx.x * 256;      // 8 tokens x 32
    int r = t >> 5, j = t & 31;
    long tok = (long)blockIdx.x * 8 + r;
    int h = j >> 3;

#pragma unroll
    for (int i = 0; i < 4; ++i) {
        int f = i * 256 + t;
        Ws[f >> 5][f & 31] = WO[f];
    }

    float L = 0.f, ctx = 0.f;
#pragma unroll
    for (int s2 = 0; s2 < NSEG; ++s2) {
        L   += pl[(size_t)s2 * NTOK * 4 + tok * 4 + h];
        ctx += pctx[((size_t)s2 * NTOK + tok) * 32 + j];
    }
    float sa = ctx / L;
    sa_out[base + t] = sa;
    sas[r][j] = sa;
    __syncthreads();

    float y = bO[j] + resid[base + t];
#pragma unroll
    for (int i = 0; i < 32; ++i) y = fmaf(sas[r][i], Ws[i][j], y);

    float sum = y;
#pragma unroll
    for (int o = 16; o >= 1; o >>= 1) sum += __shfl_xor(sum, o, 32);
    float mu = sum * (1.0f / 32.0f);
    float d  = y - mu;
    float sq = d * d;
#pragma unroll
    for (int o = 16; o >= 1; o >>= 1) sq += __shfl_xor(sq, o, 32);
    float var = sq * (1.0f / 32.0f);
    out0[base + t] = d * rsqrtf(var + LN_EPS);
}

// ---------------------------------------------------------------------------
extern "C" void kernel_launch(void* const* d_in, const int* in_sizes, int n_in,
                              void* d_out, int out_size, void* d_ws, size_t ws_size,
                              hipStream_t stream)
{
    const float* inQ = (const float*)d_in[0];
    const float* inK = (const float*)d_in[1];
    const float* inV = (const float*)d_in[2];
    const void*  mask = d_in[3];
    const float* WQ = (const float*)d_in[4];
    const float* bQ = (const float*)d_in[5];
    const float* WK = (const float*)d_in[6];
    const float* bK = (const float*)d_in[7];
    const float* WV = (const float*)d_in[8];
    const float* bV = (const float*)d_in[9];
    const float* WO = (const float*)d_in[10];
    const float* bO = (const float*)d_in[11];

    float* out0 = (float*)d_out;                    // layernorm output
    float* sa   = (float*)d_out + (long)NTOK * 32;  // self_attn output

    char* ws = (char*)d_ws;
    unsigned short* Qh = (unsigned short*)(ws + 256);
    unsigned short* Ql = Qh + (long)NTOK * 32;
    unsigned short* Kh = Ql + (long)NTOK * 32;
    unsigned short* Kl = Kh + (long)NTOK * 32;
    unsigned short* Vt = Kl + (long)NTOK * 32;
    float* pbase = (float*)(Vt + (long)NTOK * 32);

    size_t fixed  = 256 + 5ul * NTOK * 32 * 2;
    size_t perseg = (size_t)NTOK * 36 * 4;
    int NS = 1;
    if      (fixed + 16 * perseg <= ws_size) NS = 16;
    else if (fixed +  8 * perseg <= ws_size) NS = 8;
    else if (fixed +  4 * perseg <= ws_size) NS = 4;
    else if (fixed +  2 * perseg <= ws_size) NS = 2;

    float* pl   = pbase;
    float* pctx = pl + (long)NS * NTOK * 4;

    proj_kernel<<<dim3(NTOK / 8, 3), 256, 0, stream>>>(
        inQ, inK, inV, WQ, bQ, WK, bK, WV, bV, Qh, Ql, Kh, Kl, Vt);

    int agrid = B_SZ * NS * 16;
    int cgrid = NTOK / 8;
    switch (NS) {
    case 16:
        attn_kernel<16><<<agrid, 256, 0, stream>>>(Qh, Ql, Kh, Kl, Vt, mask, pl, pctx);
        combine_epilogue<16><<<cgrid, 256, 0, stream>>>(pl, pctx, WO, bO, inQ, sa, out0);
        break;
    case 8:
        attn_kernel<8><<<agrid, 256, 0, stream>>>(Qh, Ql, Kh, Kl, Vt, mask, pl, pctx);
        combine_epilogue<8><<<cgrid, 256, 0, stream>>>(pl, pctx, WO, bO, inQ, sa, out0);
        break;
    case 4:
        attn_kernel<4><<<agrid, 256, 0, stream>>>(Qh, Ql, Kh, Kl, Vt, mask, pl, pctx);
        combine_epilogue<4><<<cgrid, 256, 0, stream>>>(pl, pctx, WO, bO, inQ, sa, out0);
        break;
    case 2:
        attn_kernel<2><<<agrid, 256, 0, stream>>>(Qh, Ql, Kh, Kl, Vt, mask, pl, pctx);
        combine_epilogue<2><<<cgrid, 256, 0, stream>>>(pl, pctx, WO, bO, inQ, sa, out0);
        break;
    default:
        attn_kernel<1><<<agrid, 256, 0, stream>>>(Qh, Ql, Kh, Kl, Vt, mask, pl, pctx);
        combine_epilogue<1><<<cgrid, 256, 0, stream>>>(pl, pctx, WO, bO, inQ, sa, out0);
        break;
    }
}

// Round 13
// 101.466 us; speedup vs baseline: 1.5552x; 1.5552x over previous
//
#include <hip/hip_runtime.h>
#include <math.h>

#define D_MODEL 32
#define S_LEN   2048
#define B_SZ    8
#define NTOK    (B_SZ * S_LEN)
#define LN_EPS  1e-5f
#define LOG2E   1.44269504088896340736f
#define QK_SCALE 0.35355339059327373f   /* 1/sqrt(8) */
#define MASKV   (-1.0e9f)               /* v_exp_f32(-1e9) == 0 */

typedef __attribute__((ext_vector_type(8)))  short    short8b;
typedef __attribute__((ext_vector_type(4)))  short    short4b;
typedef __attribute__((ext_vector_type(4)))  unsigned uint4v;
typedef __attribute__((ext_vector_type(16))) float    f32x16;

__device__ __forceinline__ unsigned short f2bf(float f) {   // RNE f32->bf16
    unsigned u = __builtin_bit_cast(unsigned, f);
    unsigned r = (u + 0x7FFFu + ((u >> 16) & 1u)) >> 16;
    return (unsigned short)r;
}
__device__ __forceinline__ float bf2f(unsigned short h) {
    return __builtin_bit_cast(float, (unsigned)h << 16);
}
__device__ __forceinline__ unsigned cvtpk_bf16(float lo, float hi) {
    unsigned r;
    asm("v_cvt_pk_bf16_f32 %0, %1, %2" : "=v"(r) : "v"(lo), "v"(hi));
    return r;
}

// ---------------------------------------------------------------------------
// Row-bitpack the mask: pack[tok][w] bit j = mask[tok][64w+j]!=0.
// Dtype probed inline per block (ballot over first 64 words; R11/R12-proven).
__global__ __launch_bounds__(256) void maskpack_kernel(
    const void* __restrict__ mask, unsigned long long* __restrict__ pack)
{
    int tid = threadIdx.x;
    long row = (long)blockIdx.x * 4 + (tid >> 6);
    int lane = tid & 63;

    int probe = ((const int*)mask)[lane];
    bool is32 = (__ballot((probe & ~0xFF) == 0) == ~0ULL);

    unsigned long long* prow = pack + row * (S_LEN / 64);
    if (is32) {
        const int* mr = (const int*)mask + row * S_LEN;
#pragma unroll 4
        for (int it = 0; it < 32; ++it) {
            unsigned long long wv = __ballot(mr[it * 64 + lane] != 0);
            if (lane == 0) prow[it] = wv;
        }
    } else {
        const unsigned char* mr = (const unsigned char*)mask + row * S_LEN;
#pragma unroll 4
        for (int it = 0; it < 32; ++it) {
            unsigned long long wv = __ballot(mr[it * 64 + lane] != 0);
            if (lane == 0) prow[it] = wv;
        }
    }
}

// ---------------------------------------------------------------------------
// QKV projection. Q (pre-scaled by 1/sqrt(8)*log2e) and K are stored as
// SPLIT bf16 (hi = bf16(x), lo = bf16(x - hi)) so QK^T can be computed
// exactly with two MFMAs. V stored transposed per head, single bf16.
__global__ __launch_bounds__(256) void proj_kernel(
    const float* __restrict__ xQ, const float* __restrict__ xK,
    const float* __restrict__ xV,
    const float* __restrict__ WQ, const float* __restrict__ bQ,
    const float* __restrict__ WK, const float* __restrict__ bK,
    const float* __restrict__ WV, const float* __restrict__ bV,
    unsigned short* __restrict__ Qh, unsigned short* __restrict__ Ql,
    unsigned short* __restrict__ Kh, unsigned short* __restrict__ Kl,
    unsigned short* __restrict__ Vt)
{
    const float* x; const float* W; const float* bias; float scale;
    if (blockIdx.y == 0)      { x = xQ; W = WQ; bias = bQ; scale = QK_SCALE * LOG2E; }
    else if (blockIdx.y == 1) { x = xK; W = WK; bias = bK; scale = 1.0f; }
    else                      { x = xV; W = WV; bias = bV; scale = 1.0f; }

    __shared__ float xs[8][32];
    __shared__ float Ws[32][32];
    int t = threadIdx.x;
    long base = (long)blockIdx.x * 256;    // 8 rows x 32 cols
    xs[t >> 5][t & 31] = x[base + t];
#pragma unroll
    for (int i = 0; i < 4; ++i) {
        int f = i * 256 + t;
        Ws[f >> 5][f & 31] = W[f];
    }
    __syncthreads();
    int r = t >> 5, j = t & 31;
    float acc = bias[j];
#pragma unroll
    for (int i = 0; i < 32; ++i) acc = fmaf(xs[r][i], Ws[i][j], acc);
    acc *= scale;

    if (blockIdx.y == 0) {
        unsigned short hv = f2bf(acc);
        Qh[base + t] = hv;
        Ql[base + t] = f2bf(acc - bf2f(hv));
    } else if (blockIdx.y == 1) {
        unsigned short hv = f2bf(acc);
        Kh[base + t] = hv;
        Kl[base + t] = f2bf(acc - bf2f(hv));
    } else {
        long tok = (long)blockIdx.x * 8 + r;
        long b   = tok >> 11;
        long ti  = tok & (S_LEN - 1);
        int  h   = j >> 3, dv = j & 7;
        Vt[((b * 4 + h) * 8 + dv) * S_LEN + ti] = f2bf(acc);
    }
}

// ---------------------------------------------------------------------------
// MFMA flash attention (no-max, exp2 domain, split-K, EXACT QK via split-bf16).
// Wave = (b, seg, 32-q tile). Head loop OUTER (R10-verified); K explicitly
// prefetched one chunk ahead so the global->MFMA chain pipelines despite the
// unroll-1 chunk loop. Per-output arithmetic identical to R10.
template<int NSEG>
__global__ __launch_bounds__(256) void attn_kernel(
    const unsigned short* __restrict__ Qh, const unsigned short* __restrict__ Ql,
    const unsigned short* __restrict__ Kh, const unsigned short* __restrict__ Kl,
    const unsigned short* __restrict__ Vt,
    const unsigned long long* __restrict__ pack,
    float* __restrict__ pl, float* __restrict__ pctx)
{
    constexpr int SEGLEN = S_LEN / NSEG;
    constexpr int NCH    = SEGLEN / 32;
    const int nb    = NSEG * 16;            // blocks per batch (4 waves/block)
    int raw   = blockIdx.x;
    int total = B_SZ * nb;
    int cpx   = total >> 3;
    int cid   = (raw & 7) * cpx + (raw >> 3);   // XCD-contiguous
    int b     = cid / nb;
    int rem   = cid - b * nb;
    int seg   = rem >> 4;
    int qt    = (rem & 15) * 4 + (threadIdx.x >> 6);
    int lane  = threadIdx.x & 63;
    int q     = lane & 31;
    int half  = lane >> 5;
    int tok0  = qt * 32;
    long tokq = (long)b * S_LEN + tok0 + q;
    int k0    = seg * SEGLEN;

    f32x16 zero16;
#pragma unroll
    for (int i = 0; i < 16; ++i) zero16[i] = 0.0f;

    const unsigned long long* prow = pack + tokq * (S_LEN / 64);
    const unsigned short* Ksel = (half ? Kl : Kh) + (long)b * S_LEN * 32;

#pragma unroll 1
    for (int h = 0; h < 4; ++h) {
        short8b qhf = *(const short8b*)(Qh + tokq * 32 + h * 8);
        short8b qlf = *(const short8b*)(Ql + tokq * 32 + h * 8);
        f32x16 cpv = zero16;

        // prologue: K fragment for chunk 0
        short8b kf = *(const short8b*)(Ksel + (long)(k0 + q) * 32 + h * 8);

        unsigned long long w = 0;
#pragma unroll 1
        for (int ch = 0; ch < NCH; ++ch) {
            int kc = k0 + ch * 32;
            // prefetch next chunk's K before this chunk's dependent compute
            short8b kf_next = kf;
            if (ch + 1 < NCH)
                kf_next = *(const short8b*)(Ksel + (long)(kc + 32 + q) * 32 + h * 8);

            if ((ch & 1) == 0) w = prow[kc >> 6];
            unsigned wh  = (ch & 1) ? (unsigned)(w >> 32) : (unsigned)w;
            unsigned wsh = wh >> (half * 4);
            float madd[16];
#pragma unroll
            for (int r = 0; r < 16; ++r) {
                const int cr = (r & 3) + 8 * (r >> 2);
                madd[r] = ((wsh >> cr) & 1u) ? MASKV : 0.0f;
            }

            // A rows m=lane&31 -> key kc+q; half0 supplies K_hi (k-slots 0-7),
            // half1 supplies K_lo (k-slots 8-15), both at d0-7 of head h.
            f32x16 acc = __builtin_amdgcn_mfma_f32_32x32x16_bf16(kf, qhf, zero16, 0, 0, 0);
            acc = __builtin_amdgcn_mfma_f32_32x32x16_bf16(kf, qlf, acc, 0, 0, 0);

            unsigned pr[8];
#pragma unroll
            for (int j = 0; j < 8; ++j) {
                float p0 = __builtin_amdgcn_exp2f(acc[2 * j]     + madd[2 * j]);
                float p1 = __builtin_amdgcn_exp2f(acc[2 * j + 1] + madd[2 * j + 1]);
                pr[j] = cvtpk_bf16(p0, p1);
            }
            uint4v t1, t2;
            t1.x = pr[0]; t1.y = pr[1]; t1.z = pr[2]; t1.w = pr[3];
            t2.x = pr[4]; t2.y = pr[5]; t2.z = pr[6]; t2.w = pr[7];
            short8b pfa = __builtin_bit_cast(short8b, t1);
            short8b pfb = __builtin_bit_cast(short8b, t2);

            // V^T A-frags mirror P's (half, elem)->key mapping exactly, so the
            // shared k-slot permutation cancels regardless of HW slot order.
            short8b vf1, vf2;
            if (q < 8) {
                const unsigned short* vr =
                    Vt + (((long)b * 4 + h) * 8 + q) * S_LEN + kc + half * 4;
                short4b a0 = *(const short4b*)(vr);
                short4b a1 = *(const short4b*)(vr + 8);
                short4b a2 = *(const short4b*)(vr + 16);
                short4b a3 = *(const short4b*)(vr + 24);
                vf1 = __builtin_shufflevector(a0, a1, 0, 1, 2, 3, 4, 5, 6, 7);
                vf2 = __builtin_shufflevector(a2, a3, 0, 1, 2, 3, 4, 5, 6, 7);
            } else {
                short ov = (q == 8) ? (short)0x3F80 : (short)0;  // ones row -> l-sum
#pragma unroll
                for (int i = 0; i < 8; ++i) { vf1[i] = ov; vf2[i] = ov; }
            }
            cpv = __builtin_amdgcn_mfma_f32_32x32x16_bf16(vf1, pfa, cpv, 0, 0, 0);
            cpv = __builtin_amdgcn_mfma_f32_32x32x16_bf16(vf2, pfb, cpv, 0, 0, 0);

            kf = kf_next;
        }

        // C_PV: col=q; lower half regs0-3 = dv0-3, reg4 = row8 = l-sum;
        // upper half regs0-3 = dv4-7.
        float4 cv = make_float4(cpv[0], cpv[1], cpv[2], cpv[3]);
        *(float4*)(pctx + ((size_t)seg * NTOK + tokq) * 32 + h * 8 + half * 4) = cv;
        if (half == 0)
            pl[(size_t)seg * NTOK * 4 + tokq * 4 + h] = cpv[4];
    }
}

// ---------------------------------------------------------------------------
// Merge split-K partials (plain sums) -> sa; attn_out = sa@WO + bO + resid; LN.
template<int NSEG>
__global__ __launch_bounds__(256) void combine_epilogue(
    const float* __restrict__ pl, const float* __restrict__ pctx,
    const float* __restrict__ WO, const float* __restrict__ bO,
    const float* __restrict__ resid,
    float* __restrict__ sa_out, float* __restrict__ out0)
{
    __shared__ float sas[8][32];
    __shared__ float Ws[32][32];
    int t = threadIdx.x;
    long base = (long)blockIdx.x * 256;      // 8 tokens x 32
    int r = t >> 5, j = t & 31;
    long tok = (long)blockIdx.x * 8 + r;
    int h = j >> 3;

#pragma unroll
    for (int i = 0; i < 4; ++i) {
        int f = i * 256 + t;
        Ws[f >> 5][f & 31] = WO[f];
    }

    float L = 0.f, ctx = 0.f;
#pragma unroll
    for (int s2 = 0; s2 < NSEG; ++s2) {
        L   += pl[(size_t)s2 * NTOK * 4 + tok * 4 + h];
        ctx += pctx[((size_t)s2 * NTOK + tok) * 32 + j];
    }
    float sa = ctx / L;
    sa_out[base + t] = sa;
    sas[r][j] = sa;
    __syncthreads();

    float y = bO[j] + resid[base + t];
#pragma unroll
    for (int i = 0; i < 32; ++i) y = fmaf(sas[r][i], Ws[i][j], y);

    float sum = y;
#pragma unroll
    for (int o = 16; o >= 1; o >>= 1) sum += __shfl_xor(sum, o, 32);
    float mu = sum * (1.0f / 32.0f);
    float d  = y - mu;
    float sq = d * d;
#pragma unroll
    for (int o = 16; o >= 1; o >>= 1) sq += __shfl_xor(sq, o, 32);
    float var = sq * (1.0f / 32.0f);
    out0[base + t] = d * rsqrtf(var + LN_EPS);
}

// ---------------------------------------------------------------------------
extern "C" void kernel_launch(void* const* d_in, const int* in_sizes, int n_in,
                              void* d_out, int out_size, void* d_ws, size_t ws_size,
                              hipStream_t stream)
{
    const float* inQ = (const float*)d_in[0];
    const float* inK = (const float*)d_in[1];
    const float* inV = (const float*)d_in[2];
    const void*  mask = d_in[3];
    const float* WQ = (const float*)d_in[4];
    const float* bQ = (const float*)d_in[5];
    const float* WK = (const float*)d_in[6];
    const float* bK = (const float*)d_in[7];
    const float* WV = (const float*)d_in[8];
    const float* bV = (const float*)d_in[9];
    const float* WO = (const float*)d_in[10];
    const float* bO = (const float*)d_in[11];

    float* out0 = (float*)d_out;                    // layernorm output
    float* sa   = (float*)d_out + (long)NTOK * 32;  // self_attn output

    char* ws = (char*)d_ws;
    unsigned short* Qh = (unsigned short*)(ws + 256);
    unsigned short* Ql = Qh + (long)NTOK * 32;
    unsigned short* Kh = Ql + (long)NTOK * 32;
    unsigned short* Kl = Kh + (long)NTOK * 32;
    unsigned short* Vt = Kl + (long)NTOK * 32;
    unsigned long long* pack = (unsigned long long*)(Vt + (long)NTOK * 32);
    float* pbase = (float*)(pack + (long)NTOK * (S_LEN / 64));

    size_t fixed  = 256 + 5ul * NTOK * 32 * 2 + (size_t)NTOK * (S_LEN / 64) * 8;
    size_t perseg = (size_t)NTOK * 36 * 4;
    int NS = 1;
    if      (fixed + 16 * perseg <= ws_size) NS = 16;
    else if (fixed +  8 * perseg <= ws_size) NS = 8;
    else if (fixed +  4 * perseg <= ws_size) NS = 4;
    else if (fixed +  2 * perseg <= ws_size) NS = 2;

    float* pl   = pbase;
    float* pctx = pl + (long)NS * NTOK * 4;

    maskpack_kernel<<<NTOK / 4, 256, 0, stream>>>(mask, pack);
    proj_kernel<<<dim3(NTOK / 8, 3), 256, 0, stream>>>(
        inQ, inK, inV, WQ, bQ, WK, bK, WV, bV, Qh, Ql, Kh, Kl, Vt);

    int agrid = B_SZ * NS * 16;
    int cgrid = NTOK / 8;
    switch (NS) {
    case 16:
        attn_kernel<16><<<agrid, 256, 0, stream>>>(Qh, Ql, Kh, Kl, Vt, pack, pl, pctx);
        combine_epilogue<16><<<cgrid, 256, 0, stream>>>(pl, pctx, WO, bO, inQ, sa, out0);
        break;
    case 8:
        attn_kernel<8><<<agrid, 256, 0, stream>>>(Qh, Ql, Kh, Kl, Vt, pack, pl, pctx);
        combine_epilogue<8><<<cgrid, 256, 0, stream>>>(pl, pctx, WO, bO, inQ, sa, out0);
        break;
    case 4:
        attn_kernel<4><<<agrid, 256, 0, stream>>>(Qh, Ql, Kh, Kl, Vt, pack, pl, pctx);
        combine_epilogue<4><<<cgrid, 256, 0, stream>>>(pl, pctx, WO, bO, inQ, sa, out0);
        break;
    case 2:
        attn_kernel<2><<<agrid, 256, 0, stream>>>(Qh, Ql, Kh, Kl, Vt, pack, pl, pctx);
        combine_epilogue<2><<<cgrid, 256, 0, stream>>>(pl, pctx, WO, bO, inQ, sa, out0);
        break;
    default:
        attn_kernel<1><<<agrid, 256, 0, stream>>>(Qh, Ql, Kh, Kl, Vt, pack, pl, pctx);
        combine_epilogue<1><<<cgrid, 256, 0, stream>>>(pl, pctx, WO, bO, inQ, sa, out0);
        break;
    }
}

// Round 14
// 89.692 us; speedup vs baseline: 1.7594x; 1.1313x over previous
//
#include <hip/hip_runtime.h>
#include <math.h>

#define D_MODEL 32
#define S_LEN   2048
#define B_SZ    8
#define NTOK    (B_SZ * S_LEN)
#define LN_EPS  1e-5f
#define LOG2E   1.44269504088896340736f
#define QK_SCALE 0.35355339059327373f   /* 1/sqrt(8) */
#define PROJ_BLKS (NTOK / 8)            /* 2048 blocks per projection matrix */

typedef __attribute__((ext_vector_type(8)))  short    short8b;
typedef __attribute__((ext_vector_type(4)))  short    short4b;
typedef __attribute__((ext_vector_type(4)))  unsigned uint4v;
typedef __attribute__((ext_vector_type(16))) float    f32x16;

__device__ __forceinline__ unsigned short f2bf(float f) {   // RNE f32->bf16
    unsigned u = __builtin_bit_cast(unsigned, f);
    unsigned r = (u + 0x7FFFu + ((u >> 16) & 1u)) >> 16;
    return (unsigned short)r;
}
__device__ __forceinline__ float bf2f(unsigned short h) {
    return __builtin_bit_cast(float, (unsigned)h << 16);
}
__device__ __forceinline__ unsigned cvtpk_bf16(float lo, float hi) {
    unsigned r;
    asm("v_cvt_pk_bf16_f32 %0, %1, %2" : "=v"(r) : "v"(lo), "v"(hi));
    return r;
}

// ---------------------------------------------------------------------------
// Fused prep: projection (blocks 0..3*PROJ_BLKS-1) + mask row-bitpack (rest).
// Bodies are byte-identical to the R13 proj_kernel / maskpack_kernel.
__global__ __launch_bounds__(256) void prep_kernel(
    const void* __restrict__ mask,
    const float* __restrict__ xQ, const float* __restrict__ xK,
    const float* __restrict__ xV,
    const float* __restrict__ WQ, const float* __restrict__ bQ,
    const float* __restrict__ WK, const float* __restrict__ bK,
    const float* __restrict__ WV, const float* __restrict__ bV,
    unsigned short* __restrict__ Qh, unsigned short* __restrict__ Ql,
    unsigned short* __restrict__ Kh, unsigned short* __restrict__ Kl,
    unsigned short* __restrict__ Vt,
    unsigned long long* __restrict__ pack)
{
    int bid = blockIdx.x;
    int t   = threadIdx.x;

    if (bid < 3 * PROJ_BLKS) {
        // ---------------- projection role (identical to R13 proj) ----------
        int which = bid / PROJ_BLKS;
        int xb    = bid - which * PROJ_BLKS;
        const float* x; const float* W; const float* bias; float scale;
        if (which == 0)      { x = xQ; W = WQ; bias = bQ; scale = QK_SCALE * LOG2E; }
        else if (which == 1) { x = xK; W = WK; bias = bK; scale = 1.0f; }
        else                 { x = xV; W = WV; bias = bV; scale = 1.0f; }

        __shared__ float xs[8][32];
        __shared__ float Ws[32][32];
        long base = (long)xb * 256;    // 8 rows x 32 cols
        xs[t >> 5][t & 31] = x[base + t];
#pragma unroll
        for (int i = 0; i < 4; ++i) {
            int f = i * 256 + t;
            Ws[f >> 5][f & 31] = W[f];
        }
        __syncthreads();
        int r = t >> 5, j = t & 31;
        float acc = bias[j];
#pragma unroll
        for (int i = 0; i < 32; ++i) acc = fmaf(xs[r][i], Ws[i][j], acc);
        acc *= scale;

        if (which == 0) {
            unsigned short hv = f2bf(acc);
            Qh[base + t] = hv;
            Ql[base + t] = f2bf(acc - bf2f(hv));
        } else if (which == 1) {
            unsigned short hv = f2bf(acc);
            Kh[base + t] = hv;
            Kl[base + t] = f2bf(acc - bf2f(hv));
        } else {
            long tok = (long)xb * 8 + r;
            long b   = tok >> 11;
            long ti  = tok & (S_LEN - 1);
            int  h   = j >> 3, dv = j & 7;
            Vt[((b * 4 + h) * 8 + dv) * S_LEN + ti] = f2bf(acc);
        }
    } else {
        // ---------------- maskpack role (identical to R13 maskpack) --------
        int mb   = bid - 3 * PROJ_BLKS;
        long row = (long)mb * 4 + (t >> 6);
        int lane = t & 63;

        int probe = ((const int*)mask)[lane];
        bool is32 = (__ballot((probe & ~0xFF) == 0) == ~0ULL);

        unsigned long long* prow = pack + row * (S_LEN / 64);
        if (is32) {
            const int* mr = (const int*)mask + row * S_LEN;
#pragma unroll 4
            for (int it = 0; it < 32; ++it) {
                unsigned long long wv = __ballot(mr[it * 64 + lane] != 0);
                if (lane == 0) prow[it] = wv;
            }
        } else {
            const unsigned char* mr = (const unsigned char*)mask + row * S_LEN;
#pragma unroll 4
            for (int it = 0; it < 32; ++it) {
                unsigned long long wv = __ballot(mr[it * 64 + lane] != 0);
                if (lane == 0) prow[it] = wv;
            }
        }
    }
}

// ---------------------------------------------------------------------------
// MFMA flash attention (no-max, exp2 domain, split-K, EXACT QK via split-bf16).
// Wave = (b, seg, 32-q tile), head loop outer. Critical-path fixes vs R13:
//  - all mask words hoisted to registers before the head loop
//  - p = bit ? 0 : exp2(acc)   (== exp2(acc-1e9), fewer VALU, no madd[])
//  - dual PV accumulators (cpvA/cpvB) break the per-chunk MFMA chain
//  - K and V fragments prefetched one chunk ahead
template<int NSEG>
__global__ __launch_bounds__(256) void attn_kernel(
    const unsigned short* __restrict__ Qh, const unsigned short* __restrict__ Ql,
    const unsigned short* __restrict__ Kh, const unsigned short* __restrict__ Kl,
    const unsigned short* __restrict__ Vt,
    const unsigned long long* __restrict__ pack,
    float* __restrict__ pl, float* __restrict__ pctx)
{
    constexpr int SEGLEN = S_LEN / NSEG;
    constexpr int NCH    = SEGLEN / 32;
    constexpr int NWORDS = SEGLEN / 64;
    const int nb    = NSEG * 16;            // blocks per batch (4 waves/block)
    int raw   = blockIdx.x;
    int total = B_SZ * nb;
    int cpx   = total >> 3;
    int cid   = (raw & 7) * cpx + (raw >> 3);   // XCD-contiguous
    int b     = cid / nb;
    int rem   = cid - b * nb;
    int seg   = rem >> 4;
    int qt    = (rem & 15) * 4 + (threadIdx.x >> 6);
    int lane  = threadIdx.x & 63;
    int q     = lane & 31;
    int half  = lane >> 5;
    int tok0  = qt * 32;
    long tokq = (long)b * S_LEN + tok0 + q;
    int k0    = seg * SEGLEN;

    f32x16 zero16;
#pragma unroll
    for (int i = 0; i < 16; ++i) zero16[i] = 0.0f;

    // hoist mask words for this lane's q-row across the whole segment
    const unsigned long long* prow = pack + tokq * (S_LEN / 64);
    unsigned long long mw[NWORDS];
#pragma unroll
    for (int i = 0; i < NWORDS; ++i) mw[i] = prow[(k0 >> 6) + i];

    const unsigned short* Ksel = (half ? Kl : Kh) + (long)b * S_LEN * 32;

    // constant V fragments for the l-sum lanes (q >= 8), built once
    short ovv = (q == 8) ? (short)0x3F80 : (short)0;
    short8b ovf;
#pragma unroll
    for (int i = 0; i < 8; ++i) ovf[i] = ovv;

#pragma unroll 1
    for (int h = 0; h < 4; ++h) {
        short8b qhf = *(const short8b*)(Qh + tokq * 32 + h * 8);
        short8b qlf = *(const short8b*)(Ql + tokq * 32 + h * 8);
        f32x16 cpvA = zero16, cpvB = zero16;

        const unsigned short* Vrow =
            Vt + (((long)b * 4 + h) * 8 + q) * S_LEN;   // valid lanes q<8 only

        // prologue: chunk-0 K fragment and V fragments
        short8b kf = *(const short8b*)(Ksel + (long)(k0 + q) * 32 + h * 8);
        short4b va0, va1, va2, va3;
        if (q < 8) {
            const unsigned short* vr = Vrow + k0 + half * 4;
            va0 = *(const short4b*)(vr);
            va1 = *(const short4b*)(vr + 8);
            va2 = *(const short4b*)(vr + 16);
            va3 = *(const short4b*)(vr + 24);
        }

#pragma unroll 1
        for (int ch = 0; ch < NCH; ++ch) {
            int kc = k0 + ch * 32;

            // prefetch next chunk's K and V fragments
            short8b kf_next = kf;
            short4b vb0 = va0, vb1 = va1, vb2 = va2, vb3 = va3;
            if (ch + 1 < NCH) {
                kf_next = *(const short8b*)(Ksel + (long)(kc + 32 + q) * 32 + h * 8);
                if (q < 8) {
                    const unsigned short* vr = Vrow + kc + 32 + half * 4;
                    vb0 = *(const short4b*)(vr);
                    vb1 = *(const short4b*)(vr + 8);
                    vb2 = *(const short4b*)(vr + 16);
                    vb3 = *(const short4b*)(vr + 24);
                }
            }

            unsigned long long wv = mw[ch >> 1];
            unsigned wh  = (ch & 1) ? (unsigned)(wv >> 32) : (unsigned)wv;
            unsigned wsh = wh >> (half * 4);

            // A rows m=lane&31 -> key kc+q; half0 = K_hi (k-slots 0-7),
            // half1 = K_lo (k-slots 8-15), both at d0-7 of head h.
            f32x16 acc = __builtin_amdgcn_mfma_f32_32x32x16_bf16(kf, qhf, zero16, 0, 0, 0);
            acc = __builtin_amdgcn_mfma_f32_32x32x16_bf16(kf, qlf, acc, 0, 0, 0);

            unsigned pr[8];
#pragma unroll
            for (int j = 0; j < 8; ++j) {
                int r0 = 2 * j, r1 = 2 * j + 1;
                int cr0 = (r0 & 3) + 8 * (r0 >> 2);    // C/D row formula
                int cr1 = (r1 & 3) + 8 * (r1 >> 2);
                float p0 = ((wsh >> cr0) & 1u) ? 0.0f : __builtin_amdgcn_exp2f(acc[r0]);
                float p1 = ((wsh >> cr1) & 1u) ? 0.0f : __builtin_amdgcn_exp2f(acc[r1]);
                pr[j] = cvtpk_bf16(p0, p1);
            }
            uint4v t1, t2;
            t1.x = pr[0]; t1.y = pr[1]; t1.z = pr[2]; t1.w = pr[3];
            t2.x = pr[4]; t2.y = pr[5]; t2.z = pr[6]; t2.w = pr[7];
            short8b pfa = __builtin_bit_cast(short8b, t1);
            short8b pfb = __builtin_bit_cast(short8b, t2);

            // V^T A-frags mirror P's (half, elem)->key mapping exactly.
            short8b vf1, vf2;
            if (q < 8) {
                vf1 = __builtin_shufflevector(va0, va1, 0, 1, 2, 3, 4, 5, 6, 7);
                vf2 = __builtin_shufflevector(va2, va3, 0, 1, 2, 3, 4, 5, 6, 7);
            } else {
                vf1 = ovf; vf2 = ovf;
            }
            cpvA = __builtin_amdgcn_mfma_f32_32x32x16_bf16(vf1, pfa, cpvA, 0, 0, 0);
            cpvB = __builtin_amdgcn_mfma_f32_32x32x16_bf16(vf2, pfb, cpvB, 0, 0, 0);

            kf = kf_next;
            va0 = vb0; va1 = vb1; va2 = vb2; va3 = vb3;
        }

        // C_PV: col=q; lower half regs0-3 = dv0-3, reg4 = row8 = l-sum;
        // upper half regs0-3 = dv4-7.  (cpvA+cpvB: pure f32 reassociation)
        float4 cv = make_float4(cpvA[0] + cpvB[0], cpvA[1] + cpvB[1],
                                cpvA[2] + cpvB[2], cpvA[3] + cpvB[3]);
        *(float4*)(pctx + ((size_t)seg * NTOK + tokq) * 32 + h * 8 + half * 4) = cv;
        if (half == 0)
            pl[(size_t)seg * NTOK * 4 + tokq * 4 + h] = cpvA[4] + cpvB[4];
    }
}

// ---------------------------------------------------------------------------
// Merge split-K partials (plain sums) -> sa; attn_out = sa@WO + bO + resid; LN.
template<int NSEG>
__global__ __launch_bounds__(256) void combine_epilogue(
    const float* __restrict__ pl, const float* __restrict__ pctx,
    const float* __restrict__ WO, const float* __restrict__ bO,
    const float* __restrict__ resid,
    float* __restrict__ sa_out, float* __restrict__ out0)
{
    __shared__ float sas[8][32];
    __shared__ float Ws[32][32];
    int t = threadIdx.x;
    long base = (long)blockIdx.x * 256;      // 8 tokens x 32
    int r = t >> 5, j = t & 31;
    long tok = (long)blockIdx.x * 8 + r;
    int h = j >> 3;

#pragma unroll
    for (int i = 0; i < 4; ++i) {
        int f = i * 256 + t;
        Ws[f >> 5][f & 31] = WO[f];
    }

    float L = 0.f, ctx = 0.f;
#pragma unroll
    for (int s2 = 0; s2 < NSEG; ++s2) {
        L   += pl[(size_t)s2 * NTOK * 4 + tok * 4 + h];
        ctx += pctx[((size_t)s2 * NTOK + tok) * 32 + j];
    }
    float sa = ctx / L;
    sa_out[base + t] = sa;
    sas[r][j] = sa;
    __syncthreads();

    float y = bO[j] + resid[base + t];
#pragma unroll
    for (int i = 0; i < 32; ++i) y = fmaf(sas[r][i], Ws[i][j], y);

    float sum = y;
#pragma unroll
    for (int o = 16; o >= 1; o >>= 1) sum += __shfl_xor(sum, o, 32);
    float mu = sum * (1.0f / 32.0f);
    float d  = y - mu;
    float sq = d * d;
#pragma unroll
    for (int o = 16; o >= 1; o >>= 1) sq += __shfl_xor(sq, o, 32);
    float var = sq * (1.0f / 32.0f);
    out0[base + t] = d * rsqrtf(var + LN_EPS);
}

// ---------------------------------------------------------------------------
extern "C" void kernel_launch(void* const* d_in, const int* in_sizes, int n_in,
                              void* d_out, int out_size, void* d_ws, size_t ws_size,
                              hipStream_t stream)
{
    const float* inQ = (const float*)d_in[0];
    const float* inK = (const float*)d_in[1];
    const float* inV = (const float*)d_in[2];
    const void*  mask = d_in[3];
    const float* WQ = (const float*)d_in[4];
    const float* bQ = (const float*)d_in[5];
    const float* WK = (const float*)d_in[6];
    const float* bK = (const float*)d_in[7];
    const float* WV = (const float*)d_in[8];
    const float* bV = (const float*)d_in[9];
    const float* WO = (const float*)d_in[10];
    const float* bO = (const float*)d_in[11];

    float* out0 = (float*)d_out;                    // layernorm output
    float* sa   = (float*)d_out + (long)NTOK * 32;  // self_attn output

    char* ws = (char*)d_ws;
    unsigned short* Qh = (unsigned short*)(ws + 256);
    unsigned short* Ql = Qh + (long)NTOK * 32;
    unsigned short* Kh = Ql + (long)NTOK * 32;
    unsigned short* Kl = Kh + (long)NTOK * 32;
    unsigned short* Vt = Kl + (long)NTOK * 32;
    unsigned long long* pack = (unsigned long long*)(Vt + (long)NTOK * 32);
    float* pbase = (float*)(pack + (long)NTOK * (S_LEN / 64));

    size_t fixed  = 256 + 5ul * NTOK * 32 * 2 + (size_t)NTOK * (S_LEN / 64) * 8;
    size_t perseg = (size_t)NTOK * 36 * 4;
    int NS = 1;
    if      (fixed + 8 * perseg <= ws_size) NS = 8;
    else if (fixed + 4 * perseg <= ws_size) NS = 4;
    else if (fixed + 2 * perseg <= ws_size) NS = 2;

    float* pl   = pbase;
    float* pctx = pl + (long)NS * NTOK * 4;

    prep_kernel<<<3 * PROJ_BLKS + NTOK / 4, 256, 0, stream>>>(
        mask, inQ, inK, inV, WQ, bQ, WK, bK, WV, bV, Qh, Ql, Kh, Kl, Vt, pack);

    int agrid = B_SZ * NS * 16;
    int cgrid = NTOK / 8;
    switch (NS) {
    case 8:
        attn_kernel<8><<<agrid, 256, 0, stream>>>(Qh, Ql, Kh, Kl, Vt, pack, pl, pctx);
        combine_epilogue<8><<<cgrid, 256, 0, stream>>>(pl, pctx, WO, bO, inQ, sa, out0);
        break;
    case 4:
        attn_kernel<4><<<agrid, 256, 0, stream>>>(Qh, Ql, Kh, Kl, Vt, pack, pl, pctx);
        combine_epilogue<4><<<cgrid, 256, 0, stream>>>(pl, pctx, WO, bO, inQ, sa, out0);
        break;
    case 2:
        attn_kernel<2><<<agrid, 256, 0, stream>>>(Qh, Ql, Kh, Kl, Vt, pack, pl, pctx);
        combine_epilogue<2><<<cgrid, 256, 0, stream>>>(pl, pctx, WO, bO, inQ, sa, out0);
        break;
    default:
        attn_kernel<1><<<agrid, 256, 0, stream>>>(Qh, Ql, Kh, Kl, Vt, pack, pl, pctx);
        combine_epilogue<1><<<cgrid, 256, 0, stream>>>(pl, pctx, WO, bO, inQ, sa, out0);
        break;
    }
}

// Round 15
// 88.826 us; speedup vs baseline: 1.7765x; 1.0097x over previous
//
#include <hip/hip_runtime.h>
#include <math.h>

#define D_MODEL 32
#define S_LEN   2048
#define B_SZ    8
#define NTOK    (B_SZ * S_LEN)
#define LN_EPS  1e-5f
#define LOG2E   1.44269504088896340736f
#define QK_SCALE 0.35355339059327373f   /* 1/sqrt(8) */
#define PROJ_BLKS (NTOK / 8)            /* 2048 blocks per projection matrix */

typedef __attribute__((ext_vector_type(8)))  short    short8b;
typedef __attribute__((ext_vector_type(4)))  short    short4b;
typedef __attribute__((ext_vector_type(4)))  unsigned uint4v;
typedef __attribute__((ext_vector_type(16))) float    f32x16;

__device__ __forceinline__ unsigned short f2bf(float f) {   // RNE f32->bf16
    unsigned u = __builtin_bit_cast(unsigned, f);
    unsigned r = (u + 0x7FFFu + ((u >> 16) & 1u)) >> 16;
    return (unsigned short)r;
}
__device__ __forceinline__ float bf2f(unsigned short h) {
    return __builtin_bit_cast(float, (unsigned)h << 16);
}
__device__ __forceinline__ unsigned cvtpk_bf16(float lo, float hi) {
    unsigned r;
    asm("v_cvt_pk_bf16_f32 %0, %1, %2" : "=v"(r) : "v"(lo), "v"(hi));
    return r;
}

// ---------------------------------------------------------------------------
// Fused prep: projection (blocks 0..3*PROJ_BLKS-1) + mask row-bitpack (rest).
// Verbatim from R14 (verified).
__global__ __launch_bounds__(256) void prep_kernel(
    const void* __restrict__ mask,
    const float* __restrict__ xQ, const float* __restrict__ xK,
    const float* __restrict__ xV,
    const float* __restrict__ WQ, const float* __restrict__ bQ,
    const float* __restrict__ WK, const float* __restrict__ bK,
    const float* __restrict__ WV, const float* __restrict__ bV,
    unsigned short* __restrict__ Qh, unsigned short* __restrict__ Ql,
    unsigned short* __restrict__ Kh, unsigned short* __restrict__ Kl,
    unsigned short* __restrict__ Vt,
    unsigned long long* __restrict__ pack)
{
    int bid = blockIdx.x;
    int t   = threadIdx.x;

    if (bid < 3 * PROJ_BLKS) {
        int which = bid / PROJ_BLKS;
        int xb    = bid - which * PROJ_BLKS;
        const float* x; const float* W; const float* bias; float scale;
        if (which == 0)      { x = xQ; W = WQ; bias = bQ; scale = QK_SCALE * LOG2E; }
        else if (which == 1) { x = xK; W = WK; bias = bK; scale = 1.0f; }
        else                 { x = xV; W = WV; bias = bV; scale = 1.0f; }

        __shared__ float xs[8][32];
        __shared__ float Ws[32][32];
        long base = (long)xb * 256;    // 8 rows x 32 cols
        xs[t >> 5][t & 31] = x[base + t];
#pragma unroll
        for (int i = 0; i < 4; ++i) {
            int f = i * 256 + t;
            Ws[f >> 5][f & 31] = W[f];
        }
        __syncthreads();
        int r = t >> 5, j = t & 31;
        float acc = bias[j];
#pragma unroll
        for (int i = 0; i < 32; ++i) acc = fmaf(xs[r][i], Ws[i][j], acc);
        acc *= scale;

        if (which == 0) {
            unsigned short hv = f2bf(acc);
            Qh[base + t] = hv;
            Ql[base + t] = f2bf(acc - bf2f(hv));
        } else if (which == 1) {
            unsigned short hv = f2bf(acc);
            Kh[base + t] = hv;
            Kl[base + t] = f2bf(acc - bf2f(hv));
        } else {
            long tok = (long)xb * 8 + r;
            long b   = tok >> 11;
            long ti  = tok & (S_LEN - 1);
            int  h   = j >> 3, dv = j & 7;
            Vt[((b * 4 + h) * 8 + dv) * S_LEN + ti] = f2bf(acc);
        }
    } else {
        int mb   = bid - 3 * PROJ_BLKS;
        long row = (long)mb * 4 + (t >> 6);
        int lane = t & 63;

        int probe = ((const int*)mask)[lane];
        bool is32 = (__ballot((probe & ~0xFF) == 0) == ~0ULL);

        unsigned long long* prow = pack + row * (S_LEN / 64);
        if (is32) {
            const int* mr = (const int*)mask + row * S_LEN;
#pragma unroll 4
            for (int it = 0; it < 32; ++it) {
                unsigned long long wv = __ballot(mr[it * 64 + lane] != 0);
                if (lane == 0) prow[it] = wv;
            }
        } else {
            const unsigned char* mr = (const unsigned char*)mask + row * S_LEN;
#pragma unroll 4
            for (int it = 0; it < 32; ++it) {
                unsigned long long wv = __ballot(mr[it * 64 + lane] != 0);
                if (lane == 0) prow[it] = wv;
            }
        }
    }
}

// ---------------------------------------------------------------------------
// MFMA flash attention (no-max, exp2 domain, split-K, EXACT QK via split-bf16).
// HEAD PER WAVE: block = 4 waves = the 4 heads of one (b, seg, 32-q tile).
// Per-head body is verbatim R14 (arithmetic identical); h = wave index.
// ~100 VGPR -> 5 waves/SIMD resident (launch_bounds cap 102).
template<int NSEG>
__global__ __launch_bounds__(256, 5) void attn_kernel(
    const unsigned short* __restrict__ Qh, const unsigned short* __restrict__ Ql,
    const unsigned short* __restrict__ Kh, const unsigned short* __restrict__ Kl,
    const unsigned short* __restrict__ Vt,
    const unsigned long long* __restrict__ pack,
    float* __restrict__ pl, float* __restrict__ pctx)
{
    constexpr int SEGLEN = S_LEN / NSEG;
    constexpr int NCH    = SEGLEN / 32;
    constexpr int NWORDS = SEGLEN / 64;
    const int nb    = NSEG * 64;            // blocks per batch (64 q-tiles)
    int raw   = blockIdx.x;
    int total = B_SZ * nb;
    int cpx   = total >> 3;
    int cid   = (raw & 7) * cpx + (raw >> 3);   // XCD-contiguous (total%8==0)
    int b     = cid / nb;
    int rem   = cid - b * nb;
    int seg   = rem >> 6;
    int qt    = rem & 63;
    int h     = threadIdx.x >> 6;           // wave = head
    int lane  = threadIdx.x & 63;
    int q     = lane & 31;
    int half  = lane >> 5;
    int tok0  = qt * 32;
    long tokq = (long)b * S_LEN + tok0 + q;
    int k0    = seg * SEGLEN;

    f32x16 zero16;
#pragma unroll
    for (int i = 0; i < 16; ++i) zero16[i] = 0.0f;

    // hoist mask words for this lane's q-row across the whole segment
    const unsigned long long* prow = pack + tokq * (S_LEN / 64);
    unsigned long long mw[NWORDS];
#pragma unroll
    for (int i = 0; i < NWORDS; ++i) mw[i] = prow[(k0 >> 6) + i];

    const unsigned short* Ksel = (half ? Kl : Kh) + (long)b * S_LEN * 32;

    short ovv = (q == 8) ? (short)0x3F80 : (short)0;
    short8b ovf;
#pragma unroll
    for (int i = 0; i < 8; ++i) ovf[i] = ovv;

    short8b qhf = *(const short8b*)(Qh + tokq * 32 + h * 8);
    short8b qlf = *(const short8b*)(Ql + tokq * 32 + h * 8);
    f32x16 cpvA = zero16, cpvB = zero16;

    const unsigned short* Vrow =
        Vt + (((long)b * 4 + h) * 8 + q) * S_LEN;   // valid lanes q<8 only

    // prologue: chunk-0 K fragment (K prefetch pipeline)
    short8b kf = *(const short8b*)(Ksel + (long)(k0 + q) * 32 + h * 8);

#pragma unroll 1
    for (int ch = 0; ch < NCH; ++ch) {
        int kc = k0 + ch * 32;

        short8b kf_next = kf;
        if (ch + 1 < NCH)
            kf_next = *(const short8b*)(Ksel + (long)(kc + 32 + q) * 32 + h * 8);

        unsigned long long wv = mw[ch >> 1];
        unsigned wh  = (ch & 1) ? (unsigned)(wv >> 32) : (unsigned)wv;
        unsigned wsh = wh >> (half * 4);

        // A rows m=lane&31 -> key kc+q; half0 = K_hi (k-slots 0-7),
        // half1 = K_lo (k-slots 8-15), both at d0-7 of head h.
        __builtin_amdgcn_s_setprio(1);
        f32x16 acc = __builtin_amdgcn_mfma_f32_32x32x16_bf16(kf, qhf, zero16, 0, 0, 0);
        acc = __builtin_amdgcn_mfma_f32_32x32x16_bf16(kf, qlf, acc, 0, 0, 0);
        __builtin_amdgcn_s_setprio(0);

        unsigned pr[8];
#pragma unroll
        for (int j = 0; j < 8; ++j) {
            int r0 = 2 * j, r1 = 2 * j + 1;
            int cr0 = (r0 & 3) + 8 * (r0 >> 2);    // C/D row formula
            int cr1 = (r1 & 3) + 8 * (r1 >> 2);
            float p0 = ((wsh >> cr0) & 1u) ? 0.0f : __builtin_amdgcn_exp2f(acc[r0]);
            float p1 = ((wsh >> cr1) & 1u) ? 0.0f : __builtin_amdgcn_exp2f(acc[r1]);
            pr[j] = cvtpk_bf16(p0, p1);
        }
        uint4v t1, t2;
        t1.x = pr[0]; t1.y = pr[1]; t1.z = pr[2]; t1.w = pr[3];
        t2.x = pr[4]; t2.y = pr[5]; t2.z = pr[6]; t2.w = pr[7];
        short8b pfa = __builtin_bit_cast(short8b, t1);
        short8b pfb = __builtin_bit_cast(short8b, t2);

        // V^T A-frags mirror P's (half, elem)->key mapping exactly.
        short8b vf1, vf2;
        if (q < 8) {
            const unsigned short* vr = Vrow + kc + half * 4;
            short4b a0 = *(const short4b*)(vr);
            short4b a1 = *(const short4b*)(vr + 8);
            short4b a2 = *(const short4b*)(vr + 16);
            short4b a3 = *(const short4b*)(vr + 24);
            vf1 = __builtin_shufflevector(a0, a1, 0, 1, 2, 3, 4, 5, 6, 7);
            vf2 = __builtin_shufflevector(a2, a3, 0, 1, 2, 3, 4, 5, 6, 7);
        } else {
            vf1 = ovf; vf2 = ovf;
        }
        __builtin_amdgcn_s_setprio(1);
        cpvA = __builtin_amdgcn_mfma_f32_32x32x16_bf16(vf1, pfa, cpvA, 0, 0, 0);
        cpvB = __builtin_amdgcn_mfma_f32_32x32x16_bf16(vf2, pfb, cpvB, 0, 0, 0);
        __builtin_amdgcn_s_setprio(0);

        kf = kf_next;
    }

    // C_PV: col=q; lower half regs0-3 = dv0-3, reg4 = row8 = l-sum;
    // upper half regs0-3 = dv4-7.  (cpvA+cpvB: pure f32 reassociation)
    float4 cv = make_float4(cpvA[0] + cpvB[0], cpvA[1] + cpvB[1],
                            cpvA[2] + cpvB[2], cpvA[3] + cpvB[3]);
    *(float4*)(pctx + ((size_t)seg * NTOK + tokq) * 32 + h * 8 + half * 4) = cv;
    if (half == 0)
        pl[(size_t)seg * NTOK * 4 + tokq * 4 + h] = cpvA[4] + cpvB[4];
}

// ---------------------------------------------------------------------------
// Merge split-K partials (plain sums) -> sa; attn_out = sa@WO + bO + resid; LN.
template<int NSEG>
__global__ __launch_bounds__(256) void combine_epilogue(
    const float* __restrict__ pl, const float* __restrict__ pctx,
    const float* __restrict__ WO, const float* __restrict__ bO,
    const float* __restrict__ resid,
    float* __restrict__ sa_out, float* __restrict__ out0)
{
    __shared__ float sas[8][32];
    __shared__ float Ws[32][32];
    int t = threadIdx.x;
    long base = (long)blockIdx.x * 256;      // 8 tokens x 32
    int r = t >> 5, j = t & 31;
    long tok = (long)blockIdx.x * 8 + r;
    int h = j >> 3;

#pragma unroll
    for (int i = 0; i < 4; ++i) {
        int f = i * 256 + t;
        Ws[f >> 5][f & 31] = WO[f];
    }

    float L = 0.f, ctx = 0.f;
#pragma unroll
    for (int s2 = 0; s2 < NSEG; ++s2) {
        L   += pl[(size_t)s2 * NTOK * 4 + tok * 4 + h];
        ctx += pctx[((size_t)s2 * NTOK + tok) * 32 + j];
    }
    float sa = ctx / L;
    sa_out[base + t] = sa;
    sas[r][j] = sa;
    __syncthreads();

    float y = bO[j] + resid[base + t];
#pragma unroll
    for (int i = 0; i < 32; ++i) y = fmaf(sas[r][i], Ws[i][j], y);

    float sum = y;
#pragma unroll
    for (int o = 16; o >= 1; o >>= 1) sum += __shfl_xor(sum, o, 32);
    float mu = sum * (1.0f / 32.0f);
    float d  = y - mu;
    float sq = d * d;
#pragma unroll
    for (int o = 16; o >= 1; o >>= 1) sq += __shfl_xor(sq, o, 32);
    float var = sq * (1.0f / 32.0f);
    out0[base + t] = d * rsqrtf(var + LN_EPS);
}

// ---------------------------------------------------------------------------
extern "C" void kernel_launch(void* const* d_in, const int* in_sizes, int n_in,
                              void* d_out, int out_size, void* d_ws, size_t ws_size,
                              hipStream_t stream)
{
    const float* inQ = (const float*)d_in[0];
    const float* inK = (const float*)d_in[1];
    const float* inV = (const float*)d_in[2];
    const void*  mask = d_in[3];
    const float* WQ = (const float*)d_in[4];
    const float* bQ = (const float*)d_in[5];
    const float* WK = (const float*)d_in[6];
    const float* bK = (const float*)d_in[7];
    const float* WV = (const float*)d_in[8];
    const float* bV = (const float*)d_in[9];
    const float* WO = (const float*)d_in[10];
    const float* bO = (const float*)d_in[11];

    float* out0 = (float*)d_out;                    // layernorm output
    float* sa   = (float*)d_out + (long)NTOK * 32;  // self_attn output

    char* ws = (char*)d_ws;
    unsigned short* Qh = (unsigned short*)(ws + 256);
    unsigned short* Ql = Qh + (long)NTOK * 32;
    unsigned short* Kh = Ql + (long)NTOK * 32;
    unsigned short* Kl = Kh + (long)NTOK * 32;
    unsigned short* Vt = Kl + (long)NTOK * 32;
    unsigned long long* pack = (unsigned long long*)(Vt + (long)NTOK * 32);
    float* pbase = (float*)(pack + (long)NTOK * (S_LEN / 64));

    size_t fixed  = 256 + 5ul * NTOK * 32 * 2 + (size_t)NTOK * (S_LEN / 64) * 8;
    size_t perseg = (size_t)NTOK * 36 * 4;
    int NS = 1;
    if      (fixed + 8 * perseg <= ws_size) NS = 8;
    else if (fixed + 4 * perseg <= ws_size) NS = 4;
    else if (fixed + 2 * perseg <= ws_size) NS = 2;

    float* pl   = pbase;
    float* pctx = pl + (long)NS * NTOK * 4;

    prep_kernel<<<3 * PROJ_BLKS + NTOK / 4, 256, 0, stream>>>(
        mask, inQ, inK, inV, WQ, bQ, WK, bK, WV, bV, Qh, Ql, Kh, Kl, Vt, pack);

    int cgrid = NTOK / 8;
    switch (NS) {
    case 8: {
        int agrid = B_SZ * 8 * 64;
        attn_kernel<8><<<agrid, 256, 0, stream>>>(Qh, Ql, Kh, Kl, Vt, pack, pl, pctx);
        combine_epilogue<8><<<cgrid, 256, 0, stream>>>(pl, pctx, WO, bO, inQ, sa, out0);
        break;
    }
    case 4: {
        int agrid = B_SZ * 4 * 64;
        attn_kernel<4><<<agrid, 256, 0, stream>>>(Qh, Ql, Kh, Kl, Vt, pack, pl, pctx);
        combine_epilogue<4><<<cgrid, 256, 0, stream>>>(pl, pctx, WO, bO, inQ, sa, out0);
        break;
    }
    case 2: {
        int agrid = B_SZ * 2 * 64;
        attn_kernel<2><<<agrid, 256, 0, stream>>>(Qh, Ql, Kh, Kl, Vt, pack, pl, pctx);
        combine_epilogue<2><<<cgrid, 256, 0, stream>>>(pl, pctx, WO, bO, inQ, sa, out0);
        break;
    }
    default: {
        int agrid = B_SZ * 1 * 64;
        attn_kernel<1><<<agrid, 256, 0, stream>>>(Qh, Ql, Kh, Kl, Vt, pack, pl, pctx);
        combine_epilogue<1><<<cgrid, 256, 0, stream>>>(pl, pctx, WO, bO, inQ, sa, out0);
        break;
    }
    }
}

// Round 16
// 87.391 us; speedup vs baseline: 1.8057x; 1.0164x over previous
//
#include <hip/hip_runtime.h>
#include <math.h>

#define D_MODEL 32
#define S_LEN   2048
#define B_SZ    8
#define NTOK    (B_SZ * S_LEN)
#define LN_EPS  1e-5f
#define LOG2E   1.44269504088896340736f
#define QK_SCALE 0.35355339059327373f   /* 1/sqrt(8) */
#define PROJ_BLKS (NTOK / 8)            /* 2048 blocks per projection matrix */

typedef __attribute__((ext_vector_type(8)))  short    short8b;
typedef __attribute__((ext_vector_type(4)))  short    short4b;
typedef __attribute__((ext_vector_type(4)))  unsigned uint4v;
typedef __attribute__((ext_vector_type(16))) float    f32x16;

__device__ __forceinline__ unsigned short f2bf(float f) {   // RNE f32->bf16
    unsigned u = __builtin_bit_cast(unsigned, f);
    unsigned r = (u + 0x7FFFu + ((u >> 16) & 1u)) >> 16;
    return (unsigned short)r;
}
__device__ __forceinline__ float bf2f(unsigned short h) {
    return __builtin_bit_cast(float, (unsigned)h << 16);
}
__device__ __forceinline__ unsigned cvtpk_bf16(float lo, float hi) {
    unsigned r;
    asm("v_cvt_pk_bf16_f32 %0, %1, %2" : "=v"(r) : "v"(lo), "v"(hi));
    return r;
}

// ---------------------------------------------------------------------------
// Fused prep: projection (blocks 0..3*PROJ_BLKS-1) + mask row-bitpack (rest).
// Verbatim from R14/R15 (verified).
__global__ __launch_bounds__(256) void prep_kernel(
    const void* __restrict__ mask,
    const float* __restrict__ xQ, const float* __restrict__ xK,
    const float* __restrict__ xV,
    const float* __restrict__ WQ, const float* __restrict__ bQ,
    const float* __restrict__ WK, const float* __restrict__ bK,
    const float* __restrict__ WV, const float* __restrict__ bV,
    unsigned short* __restrict__ Qh, unsigned short* __restrict__ Ql,
    unsigned short* __restrict__ Kh, unsigned short* __restrict__ Kl,
    unsigned short* __restrict__ Vt,
    unsigned long long* __restrict__ pack)
{
    int bid = blockIdx.x;
    int t   = threadIdx.x;

    if (bid < 3 * PROJ_BLKS) {
        int which = bid / PROJ_BLKS;
        int xb    = bid - which * PROJ_BLKS;
        const float* x; const float* W; const float* bias; float scale;
        if (which == 0)      { x = xQ; W = WQ; bias = bQ; scale = QK_SCALE * LOG2E; }
        else if (which == 1) { x = xK; W = WK; bias = bK; scale = 1.0f; }
        else                 { x = xV; W = WV; bias = bV; scale = 1.0f; }

        __shared__ float xs[8][32];
        __shared__ float Ws[32][32];
        long base = (long)xb * 256;    // 8 rows x 32 cols
        xs[t >> 5][t & 31] = x[base + t];
#pragma unroll
        for (int i = 0; i < 4; ++i) {
            int f = i * 256 + t;
            Ws[f >> 5][f & 31] = W[f];
        }
        __syncthreads();
        int r = t >> 5, j = t & 31;
        float acc = bias[j];
#pragma unroll
        for (int i = 0; i < 32; ++i) acc = fmaf(xs[r][i], Ws[i][j], acc);
        acc *= scale;

        if (which == 0) {
            unsigned short hv = f2bf(acc);
            Qh[base + t] = hv;
            Ql[base + t] = f2bf(acc - bf2f(hv));
        } else if (which == 1) {
            unsigned short hv = f2bf(acc);
            Kh[base + t] = hv;
            Kl[base + t] = f2bf(acc - bf2f(hv));
        } else {
            long tok = (long)xb * 8 + r;
            long b   = tok >> 11;
            long ti  = tok & (S_LEN - 1);
            int  h   = j >> 3, dv = j & 7;
            Vt[((b * 4 + h) * 8 + dv) * S_LEN + ti] = f2bf(acc);
        }
    } else {
        int mb   = bid - 3 * PROJ_BLKS;
        long row = (long)mb * 4 + (t >> 6);
        int lane = t & 63;

        int probe = ((const int*)mask)[lane];
        bool is32 = (__ballot((probe & ~0xFF) == 0) == ~0ULL);

        unsigned long long* prow = pack + row * (S_LEN / 64);
        if (is32) {
            const int* mr = (const int*)mask + row * S_LEN;
#pragma unroll 4
            for (int it = 0; it < 32; ++it) {
                unsigned long long wv = __ballot(mr[it * 64 + lane] != 0);
                if (lane == 0) prow[it] = wv;
            }
        } else {
            const unsigned char* mr = (const unsigned char*)mask + row * S_LEN;
#pragma unroll 4
            for (int it = 0; it < 32; ++it) {
                unsigned long long wv = __ballot(mr[it * 64 + lane] != 0);
                if (lane == 0) prow[it] = wv;
            }
        }
    }
}

// ---------------------------------------------------------------------------
// MFMA flash attention (no-max, exp2 domain, split-K, EXACT QK via split-bf16).
// HEAD PER WAVE; TWO CHUNKS PER ITERATION with hand-interleaved chains:
//   QK_A1, QK_B1, QK_A2, QK_B2  (independent pairs feed the matrix pipe)
//   exp/cvt/PV of A  (B's MFMAs drain underneath)
//   exp/cvt/PV of B  (next pair's K loads fly underneath)
// Per-chunk arithmetic identical to R15.
template<int NSEG>
__global__ __launch_bounds__(256, 3) void attn_kernel(
    const unsigned short* __restrict__ Qh, const unsigned short* __restrict__ Ql,
    const unsigned short* __restrict__ Kh, const unsigned short* __restrict__ Kl,
    const unsigned short* __restrict__ Vt,
    const unsigned long long* __restrict__ pack,
    float* __restrict__ pl, float* __restrict__ pctx)
{
    constexpr int SEGLEN = S_LEN / NSEG;
    constexpr int NCH    = SEGLEN / 32;
    constexpr int NPAIR  = NCH / 2;
    constexpr int NWORDS = SEGLEN / 64;
    const int nb    = NSEG * 64;            // blocks per batch (64 q-tiles)
    int raw   = blockIdx.x;
    int total = B_SZ * nb;
    int cpx   = total >> 3;
    int cid   = (raw & 7) * cpx + (raw >> 3);   // XCD-contiguous (total%8==0)
    int b     = cid / nb;
    int rem   = cid - b * nb;
    int seg   = rem >> 6;
    int qt    = rem & 63;
    int h     = threadIdx.x >> 6;           // wave = head
    int lane  = threadIdx.x & 63;
    int q     = lane & 31;
    int half  = lane >> 5;
    int tok0  = qt * 32;
    long tokq = (long)b * S_LEN + tok0 + q;
    int k0    = seg * SEGLEN;

    f32x16 zero16;
#pragma unroll
    for (int i = 0; i < 16; ++i) zero16[i] = 0.0f;

    // hoist mask words for this lane's q-row across the whole segment
    const unsigned long long* prow = pack + tokq * (S_LEN / 64);
    unsigned long long mw[NWORDS];
#pragma unroll
    for (int i = 0; i < NWORDS; ++i) mw[i] = prow[(k0 >> 6) + i];

    const unsigned short* Ksel = (half ? Kl : Kh) + (long)b * S_LEN * 32;

    short ovv = (q == 8) ? (short)0x3F80 : (short)0;
    short8b ovf;
#pragma unroll
    for (int i = 0; i < 8; ++i) ovf[i] = ovv;

    short8b qhf = *(const short8b*)(Qh + tokq * 32 + h * 8);
    short8b qlf = *(const short8b*)(Ql + tokq * 32 + h * 8);
    f32x16 cpvA = zero16, cpvB = zero16;

    const unsigned short* Vrow =
        Vt + (((long)b * 4 + h) * 8 + q) * S_LEN;   // valid lanes q<8 only

    // prologue: K fragments for chunks 0 and 1
    short8b kfA = *(const short8b*)(Ksel + (long)(k0 + q) * 32 + h * 8);
    short8b kfB = *(const short8b*)(Ksel + (long)(k0 + 32 + q) * 32 + h * 8);

#pragma unroll 1
    for (int cp = 0; cp < NPAIR; ++cp) {
        int kcA = k0 + cp * 64;
        int kcB = kcA + 32;

        // prefetch next pair's K fragments
        short8b kfA_n = kfA, kfB_n = kfB;
        if (cp + 1 < NPAIR) {
            kfA_n = *(const short8b*)(Ksel + (long)(kcA + 64 + q) * 32 + h * 8);
            kfB_n = *(const short8b*)(Ksel + (long)(kcB + 64 + q) * 32 + h * 8);
        }

        unsigned long long wv = mw[cp];
        unsigned wshA = ((unsigned)wv) >> (half * 4);
        unsigned wshB = ((unsigned)(wv >> 32)) >> (half * 4);

        // ---- interleaved QK MFMAs: A1, B1, A2, B2
        __builtin_amdgcn_s_setprio(1);
        f32x16 accA = __builtin_amdgcn_mfma_f32_32x32x16_bf16(kfA, qhf, zero16, 0, 0, 0);
        f32x16 accB = __builtin_amdgcn_mfma_f32_32x32x16_bf16(kfB, qhf, zero16, 0, 0, 0);
        accA = __builtin_amdgcn_mfma_f32_32x32x16_bf16(kfA, qlf, accA, 0, 0, 0);
        accB = __builtin_amdgcn_mfma_f32_32x32x16_bf16(kfB, qlf, accB, 0, 0, 0);
        __builtin_amdgcn_s_setprio(0);

        // ---- chunk A: exp/cvt/PV
        {
            unsigned pr[8];
#pragma unroll
            for (int j = 0; j < 8; ++j) {
                int r0 = 2 * j, r1 = 2 * j + 1;
                int cr0 = (r0 & 3) + 8 * (r0 >> 2);    // C/D row formula
                int cr1 = (r1 & 3) + 8 * (r1 >> 2);
                float p0 = ((wshA >> cr0) & 1u) ? 0.0f : __builtin_amdgcn_exp2f(accA[r0]);
                float p1 = ((wshA >> cr1) & 1u) ? 0.0f : __builtin_amdgcn_exp2f(accA[r1]);
                pr[j] = cvtpk_bf16(p0, p1);
            }
            uint4v t1, t2;
            t1.x = pr[0]; t1.y = pr[1]; t1.z = pr[2]; t1.w = pr[3];
            t2.x = pr[4]; t2.y = pr[5]; t2.z = pr[6]; t2.w = pr[7];
            short8b pfa = __builtin_bit_cast(short8b, t1);
            short8b pfb = __builtin_bit_cast(short8b, t2);

            short8b vf1, vf2;
            if (q < 8) {
                const unsigned short* vr = Vrow + kcA + half * 4;
                short4b a0 = *(const short4b*)(vr);
                short4b a1 = *(const short4b*)(vr + 8);
                short4b a2 = *(const short4b*)(vr + 16);
                short4b a3 = *(const short4b*)(vr + 24);
                vf1 = __builtin_shufflevector(a0, a1, 0, 1, 2, 3, 4, 5, 6, 7);
                vf2 = __builtin_shufflevector(a2, a3, 0, 1, 2, 3, 4, 5, 6, 7);
            } else {
                vf1 = ovf; vf2 = ovf;
            }
            __builtin_amdgcn_s_setprio(1);
            cpvA = __builtin_amdgcn_mfma_f32_32x32x16_bf16(vf1, pfa, cpvA, 0, 0, 0);
            cpvB = __builtin_amdgcn_mfma_f32_32x32x16_bf16(vf2, pfb, cpvB, 0, 0, 0);
            __builtin_amdgcn_s_setprio(0);
        }

        // ---- chunk B: exp/cvt/PV
        {
            unsigned pr[8];
#pragma unroll
            for (int j = 0; j < 8; ++j) {
                int r0 = 2 * j, r1 = 2 * j + 1;
                int cr0 = (r0 & 3) + 8 * (r0 >> 2);
                int cr1 = (r1 & 3) + 8 * (r1 >> 2);
                float p0 = ((wshB >> cr0) & 1u) ? 0.0f : __builtin_amdgcn_exp2f(accB[r0]);
                float p1 = ((wshB >> cr1) & 1u) ? 0.0f : __builtin_amdgcn_exp2f(accB[r1]);
                pr[j] = cvtpk_bf16(p0, p1);
            }
            uint4v t1, t2;
            t1.x = pr[0]; t1.y = pr[1]; t1.z = pr[2]; t1.w = pr[3];
            t2.x = pr[4]; t2.y = pr[5]; t2.z = pr[6]; t2.w = pr[7];
            short8b pfa = __builtin_bit_cast(short8b, t1);
            short8b pfb = __builtin_bit_cast(short8b, t2);

            short8b vf1, vf2;
            if (q < 8) {
                const unsigned short* vr = Vrow + kcB + half * 4;
                short4b a0 = *(const short4b*)(vr);
                short4b a1 = *(const short4b*)(vr + 8);
                short4b a2 = *(const short4b*)(vr + 16);
                short4b a3 = *(const short4b*)(vr + 24);
                vf1 = __builtin_shufflevector(a0, a1, 0, 1, 2, 3, 4, 5, 6, 7);
                vf2 = __builtin_shufflevector(a2, a3, 0, 1, 2, 3, 4, 5, 6, 7);
            } else {
                vf1 = ovf; vf2 = ovf;
            }
            __builtin_amdgcn_s_setprio(1);
            cpvA = __builtin_amdgcn_mfma_f32_32x32x16_bf16(vf1, pfa, cpvA, 0, 0, 0);
            cpvB = __builtin_amdgcn_mfma_f32_32x32x16_bf16(vf2, pfb, cpvB, 0, 0, 0);
            __builtin_amdgcn_s_setprio(0);
        }

        kfA = kfA_n;
        kfB = kfB_n;
    }

    // C_PV: col=q; lower half regs0-3 = dv0-3, reg4 = row8 = l-sum;
    // upper half regs0-3 = dv4-7.  (cpvA+cpvB: pure f32 reassociation)
    float4 cv = make_float4(cpvA[0] + cpvB[0], cpvA[1] + cpvB[1],
                            cpvA[2] + cpvB[2], cpvA[3] + cpvB[3]);
    *(float4*)(pctx + ((size_t)seg * NTOK + tokq) * 32 + h * 8 + half * 4) = cv;
    if (half == 0)
        pl[(size_t)seg * NTOK * 4 + tokq * 4 + h] = cpvA[4] + cpvB[4];
}

// ---------------------------------------------------------------------------
// Merge split-K partials (plain sums) -> sa; attn_out = sa@WO + bO + resid; LN.
template<int NSEG>
__global__ __launch_bounds__(256) void combine_epilogue(
    const float* __restrict__ pl, const float* __restrict__ pctx,
    const float* __restrict__ WO, const float* __restrict__ bO,
    const float* __restrict__ resid,
    float* __restrict__ sa_out, float* __restrict__ out0)
{
    __shared__ float sas[8][32];
    __shared__ float Ws[32][32];
    int t = threadIdx.x;
    long base = (long)blockIdx.x * 256;      // 8 tokens x 32
    int r = t >> 5, j = t & 31;
    long tok = (long)blockIdx.x * 8 + r;
    int h = j >> 3;

#pragma unroll
    for (int i = 0; i < 4; ++i) {
        int f = i * 256 + t;
        Ws[f >> 5][f & 31] = WO[f];
    }

    float L = 0.f, ctx = 0.f;
#pragma unroll
    for (int s2 = 0; s2 < NSEG; ++s2) {
        L   += pl[(size_t)s2 * NTOK * 4 + tok * 4 + h];
        ctx += pctx[((size_t)s2 * NTOK + tok) * 32 + j];
    }
    float sa = ctx / L;
    sa_out[base + t] = sa;
    sas[r][j] = sa;
    __syncthreads();

    float y = bO[j] + resid[base + t];
#pragma unroll
    for (int i = 0; i < 32; ++i) y = fmaf(sas[r][i], Ws[i][j], y);

    float sum = y;
#pragma unroll
    for (int o = 16; o >= 1; o >>= 1) sum += __shfl_xor(sum, o, 32);
    float mu = sum * (1.0f / 32.0f);
    float d  = y - mu;
    float sq = d * d;
#pragma unroll
    for (int o = 16; o >= 1; o >>= 1) sq += __shfl_xor(sq, o, 32);
    float var = sq * (1.0f / 32.0f);
    out0[base + t] = d * rsqrtf(var + LN_EPS);
}

// ---------------------------------------------------------------------------
extern "C" void kernel_launch(void* const* d_in, const int* in_sizes, int n_in,
                              void* d_out, int out_size, void* d_ws, size_t ws_size,
                              hipStream_t stream)
{
    const float* inQ = (const float*)d_in[0];
    const float* inK = (const float*)d_in[1];
    const float* inV = (const float*)d_in[2];
    const void*  mask = d_in[3];
    const float* WQ = (const float*)d_in[4];
    const float* bQ = (const float*)d_in[5];
    const float* WK = (const float*)d_in[6];
    const float* bK = (const float*)d_in[7];
    const float* WV = (const float*)d_in[8];
    const float* bV = (const float*)d_in[9];
    const float* WO = (const float*)d_in[10];
    const float* bO = (const float*)d_in[11];

    float* out0 = (float*)d_out;                    // layernorm output
    float* sa   = (float*)d_out + (long)NTOK * 32;  // self_attn output

    char* ws = (char*)d_ws;
    unsigned short* Qh = (unsigned short*)(ws + 256);
    unsigned short* Ql = Qh + (long)NTOK * 32;
    unsigned short* Kh = Ql + (long)NTOK * 32;
    unsigned short* Kl = Kh + (long)NTOK * 32;
    unsigned short* Vt = Kl + (long)NTOK * 32;
    unsigned long long* pack = (unsigned long long*)(Vt + (long)NTOK * 32);
    float* pbase = (float*)(pack + (long)NTOK * (S_LEN / 64));

    size_t fixed  = 256 + 5ul * NTOK * 32 * 2 + (size_t)NTOK * (S_LEN / 64) * 8;
    size_t perseg = (size_t)NTOK * 36 * 4;
    int NS = 1;
    if      (fixed + 8 * perseg <= ws_size) NS = 8;
    else if (fixed + 4 * perseg <= ws_size) NS = 4;
    else if (fixed + 2 * perseg <= ws_size) NS = 2;

    float* pl   = pbase;
    float* pctx = pl + (long)NS * NTOK * 4;

    prep_kernel<<<3 * PROJ_BLKS + NTOK / 4, 256, 0, stream>>>(
        mask, inQ, inK, inV, WQ, bQ, WK, bK, WV, bV, Qh, Ql, Kh, Kl, Vt, pack);

    int cgrid = NTOK / 8;
    switch (NS) {
    case 8: {
        int agrid = B_SZ * 8 * 64;
        attn_kernel<8><<<agrid, 256, 0, stream>>>(Qh, Ql, Kh, Kl, Vt, pack, pl, pctx);
        combine_epilogue<8><<<cgrid, 256, 0, stream>>>(pl, pctx, WO, bO, inQ, sa, out0);
        break;
    }
    case 4: {
        int agrid = B_SZ * 4 * 64;
        attn_kernel<4><<<agrid, 256, 0, stream>>>(Qh, Ql, Kh, Kl, Vt, pack, pl, pctx);
        combine_epilogue<4><<<cgrid, 256, 0, stream>>>(pl, pctx, WO, bO, inQ, sa, out0);
        break;
    }
    case 2: {
        int agrid = B_SZ * 2 * 64;
        attn_kernel<2><<<agrid, 256, 0, stream>>>(Qh, Ql, Kh, Kl, Vt, pack, pl, pctx);
        combine_epilogue<2><<<cgrid, 256, 0, stream>>>(pl, pctx, WO, bO, inQ, sa, out0);
        break;
    }
    default: {
        int agrid = B_SZ * 1 * 64;
        attn_kernel<1><<<agrid, 256, 0, stream>>>(Qh, Ql, Kh, Kl, Vt, pack, pl, pctx);
        combine_epilogue<1><<<cgrid, 256, 0, stream>>>(pl, pctx, WO, bO, inQ, sa, out0);
        break;
    }
    }
}

// Round 17
// 81.338 us; speedup vs baseline: 1.9401x; 1.0744x over previous
//
#include <hip/hip_runtime.h>
#include <math.h>

#define D_MODEL 32
#define S_LEN   2048
#define B_SZ    8
#define NTOK    (B_SZ * S_LEN)
#define LN_EPS  1e-5f
#define LOG2E   1.44269504088896340736f
#define QK_SCALE 0.35355339059327373f   /* 1/sqrt(8) */
#define PROJ_BLKS (NTOK / 8)            /* 2048 blocks per projection matrix */

typedef __attribute__((ext_vector_type(8)))  short    short8b;
typedef __attribute__((ext_vector_type(4)))  short    short4b;
typedef __attribute__((ext_vector_type(4)))  unsigned uint4v;
typedef __attribute__((ext_vector_type(16))) float    f32x16;

__device__ __forceinline__ unsigned short f2bf(float f) {   // RNE f32->bf16
    unsigned u = __builtin_bit_cast(unsigned, f);
    unsigned r = (u + 0x7FFFu + ((u >> 16) & 1u)) >> 16;
    return (unsigned short)r;
}
__device__ __forceinline__ float bf2f(unsigned short h) {
    return __builtin_bit_cast(float, (unsigned)h << 16);
}
__device__ __forceinline__ unsigned cvtpk_bf16(float lo, float hi) {
    unsigned r;
    asm("v_cvt_pk_bf16_f32 %0, %1, %2" : "=v"(r) : "v"(lo), "v"(hi));
    return r;
}

// Chunk-major layouts (shorts):
//  QHC/QLC: (((b*64 + qt)*4 + h)*32 + q)*8 + d          (1 MB each)
//  KC:      ((((b*64 + ch)*4 + h)*2 + half)*32 + k)*8+d (2 MB, hi|lo halves)
//  VC:      (((b*64 + ch)*4 + h)*8 + dv)*32 + k         (1 MB)

// ---------------------------------------------------------------------------
// Fused prep: projection (blocks 0..3*PROJ_BLKS-1) + mask row-bitpack (rest).
// Same arithmetic as R16; only the proj STORE addresses changed (chunk-major).
__global__ __launch_bounds__(256) void prep_kernel(
    const void* __restrict__ mask,
    const float* __restrict__ xQ, const float* __restrict__ xK,
    const float* __restrict__ xV,
    const float* __restrict__ WQ, const float* __restrict__ bQ,
    const float* __restrict__ WK, const float* __restrict__ bK,
    const float* __restrict__ WV, const float* __restrict__ bV,
    unsigned short* __restrict__ QHC, unsigned short* __restrict__ QLC,
    unsigned short* __restrict__ KC,  unsigned short* __restrict__ VC,
    unsigned long long* __restrict__ pack)
{
    int bid = blockIdx.x;
    int t   = threadIdx.x;

    if (bid < 3 * PROJ_BLKS) {
        int which = bid / PROJ_BLKS;
        int xb    = bid - which * PROJ_BLKS;
        const float* x; const float* W; const float* bias; float scale;
        if (which == 0)      { x = xQ; W = WQ; bias = bQ; scale = QK_SCALE * LOG2E; }
        else if (which == 1) { x = xK; W = WK; bias = bK; scale = 1.0f; }
        else                 { x = xV; W = WV; bias = bV; scale = 1.0f; }

        __shared__ float xs[8][32];
        __shared__ float Ws[32][32];
        long base = (long)xb * 256;    // 8 rows x 32 cols
        xs[t >> 5][t & 31] = x[base + t];
#pragma unroll
        for (int i = 0; i < 4; ++i) {
            int f = i * 256 + t;
            Ws[f >> 5][f & 31] = W[f];
        }
        __syncthreads();
        int r = t >> 5, j = t & 31;
        float acc = bias[j];
#pragma unroll
        for (int i = 0; i < 32; ++i) acc = fmaf(xs[r][i], Ws[i][j], acc);
        acc *= scale;

        long tok = (long)xb * 8 + r;
        long b   = tok >> 11;
        long ti  = tok & (S_LEN - 1);
        int  ch  = (int)(ti >> 5), kq = (int)(ti & 31);
        int  h   = j >> 3, d = j & 7;

        if (which == 0) {
            size_t qi = ((((size_t)b * 64 + ch) * 4 + h) * 32 + kq) * 8 + d;
            unsigned short hv = f2bf(acc);
            QHC[qi] = hv;
            QLC[qi] = f2bf(acc - bf2f(hv));
        } else if (which == 1) {
            size_t ki = (((((size_t)b * 64 + ch) * 4 + h) * 2 + 0) * 32 + kq) * 8 + d;
            unsigned short hv = f2bf(acc);
            KC[ki]       = hv;                       // half 0 (hi)
            KC[ki + 256] = f2bf(acc - bf2f(hv));     // half 1 (lo), +32*8 shorts
        } else {
            size_t vi = (((size_t)b * 64 + ch) * 4 + h) * 256 + (size_t)d * 32 + kq;
            VC[vi] = f2bf(acc);
        }
    } else {
        int mb   = bid - 3 * PROJ_BLKS;
        long row = (long)mb * 4 + (t >> 6);
        int lane = t & 63;

        int probe = ((const int*)mask)[lane];
        bool is32 = (__ballot((probe & ~0xFF) == 0) == ~0ULL);

        unsigned long long* prow = pack + row * (S_LEN / 64);
        if (is32) {
            const int* mr = (const int*)mask + row * S_LEN;
#pragma unroll 4
            for (int it = 0; it < 32; ++it) {
                unsigned long long wv = __ballot(mr[it * 64 + lane] != 0);
                if (lane == 0) prow[it] = wv;
            }
        } else {
            const unsigned char* mr = (const unsigned char*)mask + row * S_LEN;
#pragma unroll 4
            for (int it = 0; it < 32; ++it) {
                unsigned long long wv = __ballot(mr[it * 64 + lane] != 0);
                if (lane == 0) prow[it] = wv;
            }
        }
    }
}

// ---------------------------------------------------------------------------
// MFMA flash attention (no-max, exp2 domain, split-K, EXACT QK via split-bf16).
// HEAD PER WAVE, 2-chunk ILP — verbatim R16 arithmetic; only the LOAD
// addresses changed to the chunk-major layouts (each wave load is now one
// contiguous 0.5-1 KB region instead of a 64B-stride scatter).
template<int NSEG>
__global__ __launch_bounds__(256, 3) void attn_kernel(
    const unsigned short* __restrict__ QHC, const unsigned short* __restrict__ QLC,
    const unsigned short* __restrict__ KC,  const unsigned short* __restrict__ VC,
    const unsigned long long* __restrict__ pack,
    float* __restrict__ pl, float* __restrict__ pctx)
{
    constexpr int SEGLEN = S_LEN / NSEG;
    constexpr int NCH    = SEGLEN / 32;
    constexpr int NPAIR  = NCH / 2;
    constexpr int NWORDS = SEGLEN / 64;
    const int nb    = NSEG * 64;            // blocks per batch (64 q-tiles)
    int raw   = blockIdx.x;
    int total = B_SZ * nb;
    int cpx   = total >> 3;
    int cid   = (raw & 7) * cpx + (raw >> 3);   // XCD-contiguous (total%8==0)
    int b     = cid / nb;
    int rem   = cid - b * nb;
    int seg   = rem >> 6;
    int qt    = rem & 63;
    int h     = threadIdx.x >> 6;           // wave = head
    int lane  = threadIdx.x & 63;
    int q     = lane & 31;
    int half  = lane >> 5;
    int tok0  = qt * 32;
    long tokq = (long)b * S_LEN + tok0 + q;
    int k0    = seg * SEGLEN;
    int ch0   = k0 >> 5;                    // first global chunk of segment

    f32x16 zero16;
#pragma unroll
    for (int i = 0; i < 16; ++i) zero16[i] = 0.0f;

    // hoist mask words for this lane's q-row across the whole segment
    const unsigned long long* prow = pack + tokq * (S_LEN / 64);
    unsigned long long mw[NWORDS];
#pragma unroll
    for (int i = 0; i < NWORDS; ++i) mw[i] = prow[(k0 >> 6) + i];

    short ovv = (q == 8) ? (short)0x3F80 : (short)0;
    short8b ovf;
#pragma unroll
    for (int i = 0; i < 8; ++i) ovf[i] = ovv;

    // Q fragments: both halves read the same 512B block (broadcast lines)
    size_t qoff = ((((size_t)b * 64 + qt) * 4 + h) * 32 + q) * 8;
    short8b qhf = *(const short8b*)(QHC + qoff);
    short8b qlf = *(const short8b*)(QLC + qoff);
    f32x16 cpvA = zero16, cpvB = zero16;

    // K address helper: wave reads one contiguous 1KB block per chunk
    const unsigned short* Kb0 = KC + (((size_t)b * 64) * 4 + h) * 512
                                   + (size_t)half * 256 + (size_t)q * 8;
    // (per chunk ch: + ch*4*512 shorts)
    const unsigned short* Vb0 = VC + (((size_t)b * 64) * 4 + h) * 256
                                   + (size_t)q * 32 + half * 4;  // valid q<8
    // (per chunk ch: + ch*4*256 shorts)

    // prologue: K fragments for chunks ch0, ch0+1
    short8b kfA = *(const short8b*)(Kb0 + (size_t)ch0 * 2048);
    short8b kfB = *(const short8b*)(Kb0 + (size_t)(ch0 + 1) * 2048);

#pragma unroll 1
    for (int cp = 0; cp < NPAIR; ++cp) {
        int chA = ch0 + 2 * cp;
        int chB = chA + 1;

        // prefetch next pair's K fragments
        short8b kfA_n = kfA, kfB_n = kfB;
        if (cp + 1 < NPAIR) {
            kfA_n = *(const short8b*)(Kb0 + (size_t)(chA + 2) * 2048);
            kfB_n = *(const short8b*)(Kb0 + (size_t)(chB + 2) * 2048);
        }

        unsigned long long wv = mw[cp];
        unsigned wshA = ((unsigned)wv) >> (half * 4);
        unsigned wshB = ((unsigned)(wv >> 32)) >> (half * 4);

        // ---- interleaved QK MFMAs: A1, B1, A2, B2
        __builtin_amdgcn_s_setprio(1);
        f32x16 accA = __builtin_amdgcn_mfma_f32_32x32x16_bf16(kfA, qhf, zero16, 0, 0, 0);
        f32x16 accB = __builtin_amdgcn_mfma_f32_32x32x16_bf16(kfB, qhf, zero16, 0, 0, 0);
        accA = __builtin_amdgcn_mfma_f32_32x32x16_bf16(kfA, qlf, accA, 0, 0, 0);
        accB = __builtin_amdgcn_mfma_f32_32x32x16_bf16(kfB, qlf, accB, 0, 0, 0);
        __builtin_amdgcn_s_setprio(0);

        // ---- chunk A: exp/cvt/PV
        {
            unsigned pr[8];
#pragma unroll
            for (int j = 0; j < 8; ++j) {
                int r0 = 2 * j, r1 = 2 * j + 1;
                int cr0 = (r0 & 3) + 8 * (r0 >> 2);    // C/D row formula
                int cr1 = (r1 & 3) + 8 * (r1 >> 2);
                float p0 = ((wshA >> cr0) & 1u) ? 0.0f : __builtin_amdgcn_exp2f(accA[r0]);
                float p1 = ((wshA >> cr1) & 1u) ? 0.0f : __builtin_amdgcn_exp2f(accA[r1]);
                pr[j] = cvtpk_bf16(p0, p1);
            }
            uint4v t1, t2;
            t1.x = pr[0]; t1.y = pr[1]; t1.z = pr[2]; t1.w = pr[3];
            t2.x = pr[4]; t2.y = pr[5]; t2.z = pr[6]; t2.w = pr[7];
            short8b pfa = __builtin_bit_cast(short8b, t1);
            short8b pfb = __builtin_bit_cast(short8b, t2);

            short8b vf1, vf2;
            if (q < 8) {
                const unsigned short* vr = Vb0 + (size_t)chA * 1024;
                short4b a0 = *(const short4b*)(vr);
                short4b a1 = *(const short4b*)(vr + 8);
                short4b a2 = *(const short4b*)(vr + 16);
                short4b a3 = *(const short4b*)(vr + 24);
                vf1 = __builtin_shufflevector(a0, a1, 0, 1, 2, 3, 4, 5, 6, 7);
                vf2 = __builtin_shufflevector(a2, a3, 0, 1, 2, 3, 4, 5, 6, 7);
            } else {
                vf1 = ovf; vf2 = ovf;
            }
            __builtin_amdgcn_s_setprio(1);
            cpvA = __builtin_amdgcn_mfma_f32_32x32x16_bf16(vf1, pfa, cpvA, 0, 0, 0);
            cpvB = __builtin_amdgcn_mfma_f32_32x32x16_bf16(vf2, pfb, cpvB, 0, 0, 0);
            __builtin_amdgcn_s_setprio(0);
        }

        // ---- chunk B: exp/cvt/PV
        {
            unsigned pr[8];
#pragma unroll
            for (int j = 0; j < 8; ++j) {
                int r0 = 2 * j, r1 = 2 * j + 1;
                int cr0 = (r0 & 3) + 8 * (r0 >> 2);
                int cr1 = (r1 & 3) + 8 * (r1 >> 2);
                float p0 = ((wshB >> cr0) & 1u) ? 0.0f : __builtin_amdgcn_exp2f(accB[r0]);
                float p1 = ((wshB >> cr1) & 1u) ? 0.0f : __builtin_amdgcn_exp2f(accB[r1]);
                pr[j] = cvtpk_bf16(p0, p1);
            }
            uint4v t1, t2;
            t1.x = pr[0]; t1.y = pr[1]; t1.z = pr[2]; t1.w = pr[3];
            t2.x = pr[4]; t2.y = pr[5]; t2.z = pr[6]; t2.w = pr[7];
            short8b pfa = __builtin_bit_cast(short8b, t1);
            short8b pfb = __builtin_bit_cast(short8b, t2);

            short8b vf1, vf2;
            if (q < 8) {
                const unsigned short* vr = Vb0 + (size_t)chB * 1024;
                short4b a0 = *(const short4b*)(vr);
                short4b a1 = *(const short4b*)(vr + 8);
                short4b a2 = *(const short4b*)(vr + 16);
                short4b a3 = *(const short4b*)(vr + 24);
                vf1 = __builtin_shufflevector(a0, a1, 0, 1, 2, 3, 4, 5, 6, 7);
                vf2 = __builtin_shufflevector(a2, a3, 0, 1, 2, 3, 4, 5, 6, 7);
            } else {
                vf1 = ovf; vf2 = ovf;
            }
            __builtin_amdgcn_s_setprio(1);
            cpvA = __builtin_amdgcn_mfma_f32_32x32x16_bf16(vf1, pfa, cpvA, 0, 0, 0);
            cpvB = __builtin_amdgcn_mfma_f32_32x32x16_bf16(vf2, pfb, cpvB, 0, 0, 0);
            __builtin_amdgcn_s_setprio(0);
        }

        kfA = kfA_n;
        kfB = kfB_n;
    }

    // C_PV: col=q; lower half regs0-3 = dv0-3, reg4 = row8 = l-sum;
    // upper half regs0-3 = dv4-7.  (cpvA+cpvB: pure f32 reassociation)
    float4 cv = make_float4(cpvA[0] + cpvB[0], cpvA[1] + cpvB[1],
                            cpvA[2] + cpvB[2], cpvA[3] + cpvB[3]);
    *(float4*)(pctx + ((size_t)seg * NTOK + tokq) * 32 + h * 8 + half * 4) = cv;
    if (half == 0)
        pl[(size_t)seg * NTOK * 4 + tokq * 4 + h] = cpvA[4] + cpvB[4];
}

// ---------------------------------------------------------------------------
// Merge split-K partials (plain sums) -> sa; attn_out = sa@WO + bO + resid; LN.
template<int NSEG>
__global__ __launch_bounds__(256) void combine_epilogue(
    const float* __restrict__ pl, const float* __restrict__ pctx,
    const float* __restrict__ WO, const float* __restrict__ bO,
    const float* __restrict__ resid,
    float* __restrict__ sa_out, float* __restrict__ out0)
{
    __shared__ float sas[8][32];
    __shared__ float Ws[32][32];
    int t = threadIdx.x;
    long base = (long)blockIdx.x * 256;      // 8 tokens x 32
    int r = t >> 5, j = t & 31;
    long tok = (long)blockIdx.x * 8 + r;
    int h = j >> 3;

#pragma unroll
    for (int i = 0; i < 4; ++i) {
        int f = i * 256 + t;
        Ws[f >> 5][f & 31] = WO[f];
    }

    float L = 0.f, ctx = 0.f;
#pragma unroll
    for (int s2 = 0; s2 < NSEG; ++s2) {
        L   += pl[(size_t)s2 * NTOK * 4 + tok * 4 + h];
        ctx += pctx[((size_t)s2 * NTOK + tok) * 32 + j];
    }
    float sa = ctx / L;
    sa_out[base + t] = sa;
    sas[r][j] = sa;
    __syncthreads();

    float y = bO[j] + resid[base + t];
#pragma unroll
    for (int i = 0; i < 32; ++i) y = fmaf(sas[r][i], Ws[i][j], y);

    float sum = y;
#pragma unroll
    for (int o = 16; o >= 1; o >>= 1) sum += __shfl_xor(sum, o, 32);
    float mu = sum * (1.0f / 32.0f);
    float d  = y - mu;
    float sq = d * d;
#pragma unroll
    for (int o = 16; o >= 1; o >>= 1) sq += __shfl_xor(sq, o, 32);
    float var = sq * (1.0f / 32.0f);
    out0[base + t] = d * rsqrtf(var + LN_EPS);
}

// ---------------------------------------------------------------------------
extern "C" void kernel_launch(void* const* d_in, const int* in_sizes, int n_in,
                              void* d_out, int out_size, void* d_ws, size_t ws_size,
                              hipStream_t stream)
{
    const float* inQ = (const float*)d_in[0];
    const float* inK = (const float*)d_in[1];
    const float* inV = (const float*)d_in[2];
    const void*  mask = d_in[3];
    const float* WQ = (const float*)d_in[4];
    const float* bQ = (const float*)d_in[5];
    const float* WK = (const float*)d_in[6];
    const float* bK = (const float*)d_in[7];
    const float* WV = (const float*)d_in[8];
    const float* bV = (const float*)d_in[9];
    const float* WO = (const float*)d_in[10];
    const float* bO = (const float*)d_in[11];

    float* out0 = (float*)d_out;                    // layernorm output
    float* sa   = (float*)d_out + (long)NTOK * 32;  // self_attn output

    char* ws = (char*)d_ws;
    unsigned short* QHC = (unsigned short*)(ws + 256);
    unsigned short* QLC = QHC + (size_t)NTOK * 32;
    unsigned short* KC  = QLC + (size_t)NTOK * 32;
    unsigned short* VC  = KC  + (size_t)NTOK * 64;
    unsigned long long* pack = (unsigned long long*)(VC + (size_t)NTOK * 32);
    float* pbase = (float*)(pack + (size_t)NTOK * (S_LEN / 64));

    size_t fixed  = 256 + 5ul * NTOK * 32 * 2 + (size_t)NTOK * (S_LEN / 64) * 8;
    size_t perseg = (size_t)NTOK * 36 * 4;
    int NS = 1;
    if      (fixed + 8 * perseg <= ws_size) NS = 8;
    else if (fixed + 4 * perseg <= ws_size) NS = 4;
    else if (fixed + 2 * perseg <= ws_size) NS = 2;

    float* pl   = pbase;
    float* pctx = pl + (long)NS * NTOK * 4;

    prep_kernel<<<3 * PROJ_BLKS + NTOK / 4, 256, 0, stream>>>(
        mask, inQ, inK, inV, WQ, bQ, WK, bK, WV, bV, QHC, QLC, KC, VC, pack);

    int cgrid = NTOK / 8;
    switch (NS) {
    case 8: {
        int agrid = B_SZ * 8 * 64;
        attn_kernel<8><<<agrid, 256, 0, stream>>>(QHC, QLC, KC, VC, pack, pl, pctx);
        combine_epilogue<8><<<cgrid, 256, 0, stream>>>(pl, pctx, WO, bO, inQ, sa, out0);
        break;
    }
    case 4: {
        int agrid = B_SZ * 4 * 64;
        attn_kernel<4><<<agrid, 256, 0, stream>>>(QHC, QLC, KC, VC, pack, pl, pctx);
        combine_epilogue<4><<<cgrid, 256, 0, stream>>>(pl, pctx, WO, bO, inQ, sa, out0);
        break;
    }
    case 2: {
        int agrid = B_SZ * 2 * 64;
        attn_kernel<2><<<agrid, 256, 0, stream>>>(QHC, QLC, KC, VC, pack, pl, pctx);
        combine_epilogue<2><<<cgrid, 256, 0, stream>>>(pl, pctx, WO, bO, inQ, sa, out0);
        break;
    }
    default: {
        int agrid = B_SZ * 1 * 64;
        attn_kernel<1><<<agrid, 256, 0, stream>>>(QHC, QLC, KC, VC, pack, pl, pctx);
        combine_epilogue<1><<<cgrid, 256, 0, stream>>>(pl, pctx, WO, bO, inQ, sa, out0);
        break;
    }
    }
}

// Round 18
// 77.547 us; speedup vs baseline: 2.0349x; 1.0489x over previous
//
#include <hip/hip_runtime.h>
#include <math.h>

#define D_MODEL 32
#define S_LEN   2048
#define B_SZ    8
#define NTOK    (B_SZ * S_LEN)
#define LN_EPS  1e-5f
#define LOG2E   1.44269504088896340736f
#define QK_SCALE 0.35355339059327373f   /* 1/sqrt(8) */
#define PROJ_BLKS (NTOK / 8)            /* 2048 blocks per projection matrix */

typedef __attribute__((ext_vector_type(8)))  short    short8b;
typedef __attribute__((ext_vector_type(4)))  short    short4b;
typedef __attribute__((ext_vector_type(4)))  unsigned uint4v;
typedef __attribute__((ext_vector_type(16))) float    f32x16;

__device__ __forceinline__ unsigned short f2bf(float f) {   // RNE f32->bf16
    unsigned u = __builtin_bit_cast(unsigned, f);
    unsigned r = (u + 0x7FFFu + ((u >> 16) & 1u)) >> 16;
    return (unsigned short)r;
}
__device__ __forceinline__ float bf2f(unsigned short h) {
    return __builtin_bit_cast(float, (unsigned)h << 16);
}
__device__ __forceinline__ unsigned cvtpk_bf16(float lo, float hi) {
    unsigned r;
    asm("v_cvt_pk_bf16_f32 %0, %1, %2" : "=v"(r) : "v"(lo), "v"(hi));
    return r;
}

// Chunk-major layouts (shorts):
//  QHC/QLC: (((b*64 + qt)*4 + h)*32 + q)*8 + d          (1 MB each)
//  KC:      ((((b*64 + ch)*4 + h)*2 + half)*32 + k)*8+d (2 MB, hi|lo halves)
//  VC:      (((b*64 + ch)*4 + h)*8 + dv)*32 + k         (1 MB)

// ---------------------------------------------------------------------------
// Fused prep: projection (blocks 0..3*PROJ_BLKS-1) + mask row-bitpack (rest).
// Verbatim R17 (verified).
__global__ __launch_bounds__(256) void prep_kernel(
    const void* __restrict__ mask,
    const float* __restrict__ xQ, const float* __restrict__ xK,
    const float* __restrict__ xV,
    const float* __restrict__ WQ, const float* __restrict__ bQ,
    const float* __restrict__ WK, const float* __restrict__ bK,
    const float* __restrict__ WV, const float* __restrict__ bV,
    unsigned short* __restrict__ QHC, unsigned short* __restrict__ QLC,
    unsigned short* __restrict__ KC,  unsigned short* __restrict__ VC,
    unsigned long long* __restrict__ pack)
{
    int bid = blockIdx.x;
    int t   = threadIdx.x;

    if (bid < 3 * PROJ_BLKS) {
        int which = bid / PROJ_BLKS;
        int xb    = bid - which * PROJ_BLKS;
        const float* x; const float* W; const float* bias; float scale;
        if (which == 0)      { x = xQ; W = WQ; bias = bQ; scale = QK_SCALE * LOG2E; }
        else if (which == 1) { x = xK; W = WK; bias = bK; scale = 1.0f; }
        else                 { x = xV; W = WV; bias = bV; scale = 1.0f; }

        __shared__ float xs[8][32];
        __shared__ float Ws[32][32];
        long base = (long)xb * 256;    // 8 rows x 32 cols
        xs[t >> 5][t & 31] = x[base + t];
#pragma unroll
        for (int i = 0; i < 4; ++i) {
            int f = i * 256 + t;
            Ws[f >> 5][f & 31] = W[f];
        }
        __syncthreads();
        int r = t >> 5, j = t & 31;
        float acc = bias[j];
#pragma unroll
        for (int i = 0; i < 32; ++i) acc = fmaf(xs[r][i], Ws[i][j], acc);
        acc *= scale;

        long tok = (long)xb * 8 + r;
        long b   = tok >> 11;
        long ti  = tok & (S_LEN - 1);
        int  ch  = (int)(ti >> 5), kq = (int)(ti & 31);
        int  h   = j >> 3, d = j & 7;

        if (which == 0) {
            size_t qi = ((((size_t)b * 64 + ch) * 4 + h) * 32 + kq) * 8 + d;
            unsigned short hv = f2bf(acc);
            QHC[qi] = hv;
            QLC[qi] = f2bf(acc - bf2f(hv));
        } else if (which == 1) {
            size_t ki = (((((size_t)b * 64 + ch) * 4 + h) * 2 + 0) * 32 + kq) * 8 + d;
            unsigned short hv = f2bf(acc);
            KC[ki]       = hv;                       // half 0 (hi)
            KC[ki + 256] = f2bf(acc - bf2f(hv));     // half 1 (lo)
        } else {
            size_t vi = (((size_t)b * 64 + ch) * 4 + h) * 256 + (size_t)d * 32 + kq;
            VC[vi] = f2bf(acc);
        }
    } else {
        int mb   = bid - 3 * PROJ_BLKS;
        long row = (long)mb * 4 + (t >> 6);
        int lane = t & 63;

        int probe = ((const int*)mask)[lane];
        bool is32 = (__ballot((probe & ~0xFF) == 0) == ~0ULL);

        unsigned long long* prow = pack + row * (S_LEN / 64);
        if (is32) {
            const int* mr = (const int*)mask + row * S_LEN;
#pragma unroll 4
            for (int it = 0; it < 32; ++it) {
                unsigned long long wv = __ballot(mr[it * 64 + lane] != 0);
                if (lane == 0) prow[it] = wv;
            }
        } else {
            const unsigned char* mr = (const unsigned char*)mask + row * S_LEN;
#pragma unroll 4
            for (int it = 0; it < 32; ++it) {
                unsigned long long wv = __ballot(mr[it * 64 + lane] != 0);
                if (lane == 0) prow[it] = wv;
            }
        }
    }
}

// ---------------------------------------------------------------------------
// MFMA flash attention (no-max, exp2 domain, split-K, EXACT QK via split-bf16).
// HEAD PER WAVE, 2-chunk QK ILP, SINGLE cpv accumulator (dependent MFMA
// accumulation is full-rate), V software-pipelined one chunk ahead.
// launch_bounds (256,4): 128-VGPR cap -> 4 resident waves/SIMD.
template<int NSEG>
__global__ __launch_bounds__(256, 4) void attn_kernel(
    const unsigned short* __restrict__ QHC, const unsigned short* __restrict__ QLC,
    const unsigned short* __restrict__ KC,  const unsigned short* __restrict__ VC,
    const unsigned long long* __restrict__ pack,
    float* __restrict__ pl, float* __restrict__ pctx)
{
    constexpr int SEGLEN = S_LEN / NSEG;
    constexpr int NCH    = SEGLEN / 32;
    constexpr int NPAIR  = NCH / 2;
    constexpr int NWORDS = SEGLEN / 64;
    const int nb    = NSEG * 64;            // blocks per batch (64 q-tiles)
    int raw   = blockIdx.x;
    int total = B_SZ * nb;
    int cpx   = total >> 3;
    int cid   = (raw & 7) * cpx + (raw >> 3);   // XCD-contiguous (total%8==0)
    int b     = cid / nb;
    int rem   = cid - b * nb;
    int seg   = rem >> 6;
    int qt    = rem & 63;
    int h     = threadIdx.x >> 6;           // wave = head
    int lane  = threadIdx.x & 63;
    int q     = lane & 31;
    int half  = lane >> 5;
    int tok0  = qt * 32;
    long tokq = (long)b * S_LEN + tok0 + q;
    int k0    = seg * SEGLEN;
    int ch0   = k0 >> 5;                    // first global chunk of segment

    f32x16 zero16;
#pragma unroll
    for (int i = 0; i < 16; ++i) zero16[i] = 0.0f;

    // hoist mask words for this lane's q-row across the whole segment
    const unsigned long long* prow = pack + tokq * (S_LEN / 64);
    unsigned long long mw[NWORDS];
#pragma unroll
    for (int i = 0; i < NWORDS; ++i) mw[i] = prow[(k0 >> 6) + i];

    short ovv = (q == 8) ? (short)0x3F80 : (short)0;
    short8b ovf;
#pragma unroll
    for (int i = 0; i < 8; ++i) ovf[i] = ovv;

    // Q fragments: both halves read the same 512B block (broadcast lines)
    size_t qoff = ((((size_t)b * 64 + qt) * 4 + h) * 32 + q) * 8;
    short8b qhf = *(const short8b*)(QHC + qoff);
    short8b qlf = *(const short8b*)(QLC + qoff);
    f32x16 cpv = zero16;

    const unsigned short* Kb0 = KC + (((size_t)b * 64) * 4 + h) * 512
                                   + (size_t)half * 256 + (size_t)q * 8;
    const unsigned short* Vb0 = VC + (((size_t)b * 64) * 4 + h) * 256
                                   + (size_t)q * 32 + half * 4;  // valid q<8

    // prologue: K fragments for chunks ch0, ch0+1; V for chunk ch0
    short8b kfA = *(const short8b*)(Kb0 + (size_t)ch0 * 2048);
    short8b kfB = *(const short8b*)(Kb0 + (size_t)(ch0 + 1) * 2048);
    short8b vf1c, vf2c;                     // V frags for the CURRENT chunk
    if (q < 8) {
        const unsigned short* vr = Vb0 + (size_t)ch0 * 1024;
        short4b a0 = *(const short4b*)(vr);
        short4b a1 = *(const short4b*)(vr + 8);
        short4b a2 = *(const short4b*)(vr + 16);
        short4b a3 = *(const short4b*)(vr + 24);
        vf1c = __builtin_shufflevector(a0, a1, 0, 1, 2, 3, 4, 5, 6, 7);
        vf2c = __builtin_shufflevector(a2, a3, 0, 1, 2, 3, 4, 5, 6, 7);
    } else { vf1c = ovf; vf2c = ovf; }

#pragma unroll 1
    for (int cp = 0; cp < NPAIR; ++cp) {
        int chA = ch0 + 2 * cp;
        int chB = chA + 1;

        // prefetch next pair's K fragments
        short8b kfA_n = kfA, kfB_n = kfB;
        if (cp + 1 < NPAIR) {
            kfA_n = *(const short8b*)(Kb0 + (size_t)(chA + 2) * 2048);
            kfB_n = *(const short8b*)(Kb0 + (size_t)(chB + 2) * 2048);
        }

        unsigned long long wv = mw[cp];
        unsigned wshA = ((unsigned)wv) >> (half * 4);
        unsigned wshB = ((unsigned)(wv >> 32)) >> (half * 4);

        // ---- interleaved QK MFMAs: A1, B1, A2, B2
        __builtin_amdgcn_s_setprio(1);
        f32x16 accA = __builtin_amdgcn_mfma_f32_32x32x16_bf16(kfA, qhf, zero16, 0, 0, 0);
        f32x16 accB = __builtin_amdgcn_mfma_f32_32x32x16_bf16(kfB, qhf, zero16, 0, 0, 0);
        accA = __builtin_amdgcn_mfma_f32_32x32x16_bf16(kfA, qlf, accA, 0, 0, 0);
        accB = __builtin_amdgcn_mfma_f32_32x32x16_bf16(kfB, qlf, accB, 0, 0, 0);
        __builtin_amdgcn_s_setprio(0);

        // prefetch V for chunk B (hides under chunk A's exp/cvt/PV)
        short8b vf1n, vf2n;
        if (q < 8) {
            const unsigned short* vr = Vb0 + (size_t)chB * 1024;
            short4b a0 = *(const short4b*)(vr);
            short4b a1 = *(const short4b*)(vr + 8);
            short4b a2 = *(const short4b*)(vr + 16);
            short4b a3 = *(const short4b*)(vr + 24);
            vf1n = __builtin_shufflevector(a0, a1, 0, 1, 2, 3, 4, 5, 6, 7);
            vf2n = __builtin_shufflevector(a2, a3, 0, 1, 2, 3, 4, 5, 6, 7);
        } else { vf1n = ovf; vf2n = ovf; }

        // ---- chunk A: exp/cvt/PV (V already in vf1c/vf2c)
        {
            unsigned pr[8];
#pragma unroll
            for (int j = 0; j < 8; ++j) {
                int r0 = 2 * j, r1 = 2 * j + 1;
                int cr0 = (r0 & 3) + 8 * (r0 >> 2);    // C/D row formula
                int cr1 = (r1 & 3) + 8 * (r1 >> 2);
                float p0 = ((wshA >> cr0) & 1u) ? 0.0f : __builtin_amdgcn_exp2f(accA[r0]);
                float p1 = ((wshA >> cr1) & 1u) ? 0.0f : __builtin_amdgcn_exp2f(accA[r1]);
                pr[j] = cvtpk_bf16(p0, p1);
            }
            uint4v t1, t2;
            t1.x = pr[0]; t1.y = pr[1]; t1.z = pr[2]; t1.w = pr[3];
            t2.x = pr[4]; t2.y = pr[5]; t2.z = pr[6]; t2.w = pr[7];
            short8b pfa = __builtin_bit_cast(short8b, t1);
            short8b pfb = __builtin_bit_cast(short8b, t2);

            __builtin_amdgcn_s_setprio(1);
            cpv = __builtin_amdgcn_mfma_f32_32x32x16_bf16(vf1c, pfa, cpv, 0, 0, 0);
            cpv = __builtin_amdgcn_mfma_f32_32x32x16_bf16(vf2c, pfb, cpv, 0, 0, 0);
            __builtin_amdgcn_s_setprio(0);
        }

        // prefetch V for next pair's chunk A (hides under chunk B's tail)
        short8b vf1nn, vf2nn;
        if (cp + 1 < NPAIR && q < 8) {
            const unsigned short* vr = Vb0 + (size_t)(chA + 2) * 1024;
            short4b a0 = *(const short4b*)(vr);
            short4b a1 = *(const short4b*)(vr + 8);
            short4b a2 = *(const short4b*)(vr + 16);
            short4b a3 = *(const short4b*)(vr + 24);
            vf1nn = __builtin_shufflevector(a0, a1, 0, 1, 2, 3, 4, 5, 6, 7);
            vf2nn = __builtin_shufflevector(a2, a3, 0, 1, 2, 3, 4, 5, 6, 7);
        } else { vf1nn = ovf; vf2nn = ovf; }

        // ---- chunk B: exp/cvt/PV (V in vf1n/vf2n)
        {
            unsigned pr[8];
#pragma unroll
            for (int j = 0; j < 8; ++j) {
                int r0 = 2 * j, r1 = 2 * j + 1;
                int cr0 = (r0 & 3) + 8 * (r0 >> 2);
                int cr1 = (r1 & 3) + 8 * (r1 >> 2);
                float p0 = ((wshB >> cr0) & 1u) ? 0.0f : __builtin_amdgcn_exp2f(accB[r0]);
                float p1 = ((wshB >> cr1) & 1u) ? 0.0f : __builtin_amdgcn_exp2f(accB[r1]);
                pr[j] = cvtpk_bf16(p0, p1);
            }
            uint4v t1, t2;
            t1.x = pr[0]; t1.y = pr[1]; t1.z = pr[2]; t1.w = pr[3];
            t2.x = pr[4]; t2.y = pr[5]; t2.z = pr[6]; t2.w = pr[7];
            short8b pfa = __builtin_bit_cast(short8b, t1);
            short8b pfb = __builtin_bit_cast(short8b, t2);

            __builtin_amdgcn_s_setprio(1);
            cpv = __builtin_amdgcn_mfma_f32_32x32x16_bf16(vf1n, pfa, cpv, 0, 0, 0);
            cpv = __builtin_amdgcn_mfma_f32_32x32x16_bf16(vf2n, pfb, cpv, 0, 0, 0);
            __builtin_amdgcn_s_setprio(0);
        }

        kfA = kfA_n;
        kfB = kfB_n;
        vf1c = vf1nn;
        vf2c = vf2nn;
    }

    // C_PV: col=q; lower half regs0-3 = dv0-3, reg4 = row8 = l-sum;
    // upper half regs0-3 = dv4-7.
    float4 cv = make_float4(cpv[0], cpv[1], cpv[2], cpv[3]);
    *(float4*)(pctx + ((size_t)seg * NTOK + tokq) * 32 + h * 8 + half * 4) = cv;
    if (half == 0)
        pl[(size_t)seg * NTOK * 4 + tokq * 4 + h] = cpv[4];
}

// ---------------------------------------------------------------------------
// Merge split-K partials (plain sums) -> sa; attn_out = sa@WO + bO + resid; LN.
template<int NSEG>
__global__ __launch_bounds__(256) void combine_epilogue(
    const float* __restrict__ pl, const float* __restrict__ pctx,
    const float* __restrict__ WO, const float* __restrict__ bO,
    const float* __restrict__ resid,
    float* __restrict__ sa_out, float* __restrict__ out0)
{
    __shared__ float sas[8][32];
    __shared__ float Ws[32][32];
    int t = threadIdx.x;
    long base = (long)blockIdx.x * 256;      // 8 tokens x 32
    int r = t >> 5, j = t & 31;
    long tok = (long)blockIdx.x * 8 + r;
    int h = j >> 3;

#pragma unroll
    for (int i = 0; i < 4; ++i) {
        int f = i * 256 + t;
        Ws[f >> 5][f & 31] = WO[f];
    }

    float L = 0.f, ctx = 0.f;
#pragma unroll
    for (int s2 = 0; s2 < NSEG; ++s2) {
        L   += pl[(size_t)s2 * NTOK * 4 + tok * 4 + h];
        ctx += pctx[((size_t)s2 * NTOK + tok) * 32 + j];
    }
    float sa = ctx / L;
    sa_out[base + t] = sa;
    sas[r][j] = sa;
    __syncthreads();

    float y = bO[j] + resid[base + t];
#pragma unroll
    for (int i = 0; i < 32; ++i) y = fmaf(sas[r][i], Ws[i][j], y);

    float sum = y;
#pragma unroll
    for (int o = 16; o >= 1; o >>= 1) sum += __shfl_xor(sum, o, 32);
    float mu = sum * (1.0f / 32.0f);
    float d  = y - mu;
    float sq = d * d;
#pragma unroll
    for (int o = 16; o >= 1; o >>= 1) sq += __shfl_xor(sq, o, 32);
    float var = sq * (1.0f / 32.0f);
    out0[base + t] = d * rsqrtf(var + LN_EPS);
}

// ---------------------------------------------------------------------------
extern "C" void kernel_launch(void* const* d_in, const int* in_sizes, int n_in,
                              void* d_out, int out_size, void* d_ws, size_t ws_size,
                              hipStream_t stream)
{
    const float* inQ = (const float*)d_in[0];
    const float* inK = (const float*)d_in[1];
    const float* inV = (const float*)d_in[2];
    const void*  mask = d_in[3];
    const float* WQ = (const float*)d_in[4];
    const float* bQ = (const float*)d_in[5];
    const float* WK = (const float*)d_in[6];
    const float* bK = (const float*)d_in[7];
    const float* WV = (const float*)d_in[8];
    const float* bV = (const float*)d_in[9];
    const float* WO = (const float*)d_in[10];
    const float* bO = (const float*)d_in[11];

    float* out0 = (float*)d_out;                    // layernorm output
    float* sa   = (float*)d_out + (long)NTOK * 32;  // self_attn output

    char* ws = (char*)d_ws;
    unsigned short* QHC = (unsigned short*)(ws + 256);
    unsigned short* QLC = QHC + (size_t)NTOK * 32;
    unsigned short* KC  = QLC + (size_t)NTOK * 32;
    unsigned short* VC  = KC  + (size_t)NTOK * 64;
    unsigned long long* pack = (unsigned long long*)(VC + (size_t)NTOK * 32);
    float* pbase = (float*)(pack + (size_t)NTOK * (S_LEN / 64));

    size_t fixed  = 256 + 5ul * NTOK * 32 * 2 + (size_t)NTOK * (S_LEN / 64) * 8;
    size_t perseg = (size_t)NTOK * 36 * 4;
    int NS = 1;
    if      (fixed + 8 * perseg <= ws_size) NS = 8;
    else if (fixed + 4 * perseg <= ws_size) NS = 4;
    else if (fixed + 2 * perseg <= ws_size) NS = 2;

    float* pl   = pbase;
    float* pctx = pl + (long)NS * NTOK * 4;

    prep_kernel<<<3 * PROJ_BLKS + NTOK / 4, 256, 0, stream>>>(
        mask, inQ, inK, inV, WQ, bQ, WK, bK, WV, bV, QHC, QLC, KC, VC, pack);

    int cgrid = NTOK / 8;
    switch (NS) {
    case 8: {
        int agrid = B_SZ * 8 * 64;
        attn_kernel<8><<<agrid, 256, 0, stream>>>(QHC, QLC, KC, VC, pack, pl, pctx);
        combine_epilogue<8><<<cgrid, 256, 0, stream>>>(pl, pctx, WO, bO, inQ, sa, out0);
        break;
    }
    case 4: {
        int agrid = B_SZ * 4 * 64;
        attn_kernel<4><<<agrid, 256, 0, stream>>>(QHC, QLC, KC, VC, pack, pl, pctx);
        combine_epilogue<4><<<cgrid, 256, 0, stream>>>(pl, pctx, WO, bO, inQ, sa, out0);
        break;
    }
    case 2: {
        int agrid = B_SZ * 2 * 64;
        attn_kernel<2><<<agrid, 256, 0, stream>>>(QHC, QLC, KC, VC, pack, pl, pctx);
        combine_epilogue<2><<<cgrid, 256, 0, stream>>>(pl, pctx, WO, bO, inQ, sa, out0);
        break;
    }
    default: {
        int agrid = B_SZ * 1 * 64;
        attn_kernel<1><<<agrid, 256, 0, stream>>>(QHC, QLC, KC, VC, pack, pl, pctx);
        combine_epilogue<1><<<cgrid, 256, 0, stream>>>(pl, pctx, WO, bO, inQ, sa, out0);
        break;
    }
    }
}

// Round 19
// 70.658 us; speedup vs baseline: 2.2333x; 1.0975x over previous
//
#include <hip/hip_runtime.h>
#include <math.h>

#define D_MODEL 32
#define S_LEN   2048
#define B_SZ    8
#define NTOK    (B_SZ * S_LEN)
#define LN_EPS  1e-5f
#define LOG2E   1.44269504088896340736f
#define QK_SCALE 0.35355339059327373f   /* 1/sqrt(8) */
#define PROJ_BLKS (NTOK / 8)            /* 2048 blocks per projection matrix */

typedef __attribute__((ext_vector_type(8)))  short    short8b;
typedef __attribute__((ext_vector_type(4)))  short    short4b;
typedef __attribute__((ext_vector_type(4)))  unsigned uint4v;
typedef __attribute__((ext_vector_type(16))) float    f32x16;

__device__ __forceinline__ unsigned short f2bf(float f) {   // RNE f32->bf16
    unsigned u = __builtin_bit_cast(unsigned, f);
    unsigned r = (u + 0x7FFFu + ((u >> 16) & 1u)) >> 16;
    return (unsigned short)r;
}
__device__ __forceinline__ float bf2f(unsigned short h) {
    return __builtin_bit_cast(float, (unsigned)h << 16);
}
__device__ __forceinline__ unsigned cvtpk_bf16(float lo, float hi) {
    unsigned r;
    asm("v_cvt_pk_bf16_f32 %0, %1, %2" : "=v"(r) : "v"(lo), "v"(hi));
    return r;
}

// Chunk-major layouts (shorts):
//  QHC/QLC: (((b*64 + qt)*4 + h)*32 + q)*8 + d          (1 MB each)
//  KC:      ((((b*64 + ch)*4 + h)*2 + half)*32 + k)*8+d (2 MB, hi|lo halves)
//  VC:      (((b*64 + ch)*4 + h)*8 + dv)*32 + k         (1 MB)
// Mask pack (INTERLEAVED): prow[g*4+c] bit L = mask[row][256g + 4L + c]

// ---------------------------------------------------------------------------
// Fused prep: projection (blocks 0..3*PROJ_BLKS-1) + mask bitpack (rest).
// Proj role verbatim R17/R18. Maskpack role: int4-wide loads, interleaved
// ballot pack (4 ballots per 256-key group).
__global__ __launch_bounds__(256) void prep_kernel(
    const void* __restrict__ mask,
    const float* __restrict__ xQ, const float* __restrict__ xK,
    const float* __restrict__ xV,
    const float* __restrict__ WQ, const float* __restrict__ bQ,
    const float* __restrict__ WK, const float* __restrict__ bK,
    const float* __restrict__ WV, const float* __restrict__ bV,
    unsigned short* __restrict__ QHC, unsigned short* __restrict__ QLC,
    unsigned short* __restrict__ KC,  unsigned short* __restrict__ VC,
    unsigned long long* __restrict__ pack)
{
    int bid = blockIdx.x;
    int t   = threadIdx.x;

    if (bid < 3 * PROJ_BLKS) {
        int which = bid / PROJ_BLKS;
        int xb    = bid - which * PROJ_BLKS;
        const float* x; const float* W; const float* bias; float scale;
        if (which == 0)      { x = xQ; W = WQ; bias = bQ; scale = QK_SCALE * LOG2E; }
        else if (which == 1) { x = xK; W = WK; bias = bK; scale = 1.0f; }
        else                 { x = xV; W = WV; bias = bV; scale = 1.0f; }

        __shared__ float xs[8][32];
        __shared__ float Ws[32][32];
        long base = (long)xb * 256;    // 8 rows x 32 cols
        xs[t >> 5][t & 31] = x[base + t];
#pragma unroll
        for (int i = 0; i < 4; ++i) {
            int f = i * 256 + t;
            Ws[f >> 5][f & 31] = W[f];
        }
        __syncthreads();
        int r = t >> 5, j = t & 31;
        float acc = bias[j];
#pragma unroll
        for (int i = 0; i < 32; ++i) acc = fmaf(xs[r][i], Ws[i][j], acc);
        acc *= scale;

        long tok = (long)xb * 8 + r;
        long b   = tok >> 11;
        long ti  = tok & (S_LEN - 1);
        int  ch  = (int)(ti >> 5), kq = (int)(ti & 31);
        int  h   = j >> 3, d = j & 7;

        if (which == 0) {
            size_t qi = ((((size_t)b * 64 + ch) * 4 + h) * 32 + kq) * 8 + d;
            unsigned short hv = f2bf(acc);
            QHC[qi] = hv;
            QLC[qi] = f2bf(acc - bf2f(hv));
        } else if (which == 1) {
            size_t ki = (((((size_t)b * 64 + ch) * 4 + h) * 2 + 0) * 32 + kq) * 8 + d;
            unsigned short hv = f2bf(acc);
            KC[ki]       = hv;                       // half 0 (hi)
            KC[ki + 256] = f2bf(acc - bf2f(hv));     // half 1 (lo)
        } else {
            size_t vi = (((size_t)b * 64 + ch) * 4 + h) * 256 + (size_t)d * 32 + kq;
            VC[vi] = f2bf(acc);
        }
    } else {
        int mb   = bid - 3 * PROJ_BLKS;
        long row = (long)mb * 4 + (t >> 6);
        int lane = t & 63;

        int probe = ((const int*)mask)[lane];
        bool is32 = (__ballot((probe & ~0xFF) == 0) == ~0ULL);

        unsigned long long* prow = pack + row * (S_LEN / 64);
        if (is32) {
            const int4* mr4 = (const int4*)((const int*)mask + row * S_LEN);
#pragma unroll
            for (int g = 0; g < 8; ++g) {
                int4 v = mr4[g * 64 + lane];        // keys 256g+4*lane+{0..3}
                unsigned long long b0 = __ballot(v.x != 0);
                unsigned long long b1 = __ballot(v.y != 0);
                unsigned long long b2 = __ballot(v.z != 0);
                unsigned long long b3 = __ballot(v.w != 0);
                if (lane == 0) {
                    prow[g * 4 + 0] = b0; prow[g * 4 + 1] = b1;
                    prow[g * 4 + 2] = b2; prow[g * 4 + 3] = b3;
                }
            }
        } else {
            const int* mri = (const int*)((const unsigned char*)mask + row * S_LEN);
#pragma unroll
            for (int g = 0; g < 8; ++g) {
                int v = mri[g * 64 + lane];         // bytes = keys 256g+4*lane+{0..3}
                unsigned long long b0 = __ballot((v & 0x000000FF) != 0);
                unsigned long long b1 = __ballot((v & 0x0000FF00) != 0);
                unsigned long long b2 = __ballot((v & 0x00FF0000) != 0);
                unsigned long long b3 = __ballot((v & 0xFF000000u) != 0);
                if (lane == 0) {
                    prow[g * 4 + 0] = b0; prow[g * 4 + 1] = b1;
                    prow[g * 4 + 2] = b2; prow[g * 4 + 3] = b3;
                }
            }
        }
    }
}

// ---------------------------------------------------------------------------
// MFMA flash attention (no-max, exp2 domain, split-K, EXACT QK via split-bf16).
// HEAD PER WAVE, 2-chunk QK ILP, single cpv, V pipelined (R18 structure).
// Mask from interleaved pack: per pair p of group g, nib[c] = mg[c]>>(16p+half);
// element (r): bit 2*(r>>2) of nib[r&3].  (key = 64p + (r&3)+8*(r>>2)+4*half)
template<int NSEG>
__global__ __launch_bounds__(256, 4) void attn_kernel(
    const unsigned short* __restrict__ QHC, const unsigned short* __restrict__ QLC,
    const unsigned short* __restrict__ KC,  const unsigned short* __restrict__ VC,
    const unsigned long long* __restrict__ pack,
    float* __restrict__ pl, float* __restrict__ pctx)
{
    constexpr int SEGLEN = S_LEN / NSEG;
    constexpr int NGROUP = SEGLEN / 256;    // 256-key groups per segment
    constexpr int NPT    = SEGLEN / 64;     // total pairs
    const int nb    = NSEG * 64;            // blocks per batch (64 q-tiles)
    int raw   = blockIdx.x;
    int total = B_SZ * nb;
    int cpx   = total >> 3;
    int cid   = (raw & 7) * cpx + (raw >> 3);   // XCD-contiguous (total%8==0)
    int b     = cid / nb;
    int rem   = cid - b * nb;
    int seg   = rem >> 6;
    int qt    = rem & 63;
    int h     = threadIdx.x >> 6;           // wave = head
    int lane  = threadIdx.x & 63;
    int q     = lane & 31;
    int half  = lane >> 5;
    int tok0  = qt * 32;
    long tokq = (long)b * S_LEN + tok0 + q;
    int k0    = seg * SEGLEN;
    int ch0   = k0 >> 5;                    // first global chunk of segment

    f32x16 zero16;
#pragma unroll
    for (int i = 0; i < 16; ++i) zero16[i] = 0.0f;

    const unsigned long long* prow = pack + tokq * (S_LEN / 64);

    short ovv = (q == 8) ? (short)0x3F80 : (short)0;
    short8b ovf;
#pragma unroll
    for (int i = 0; i < 8; ++i) ovf[i] = ovv;

    // Q fragments: both halves read the same 512B block (broadcast lines)
    size_t qoff = ((((size_t)b * 64 + qt) * 4 + h) * 32 + q) * 8;
    short8b qhf = *(const short8b*)(QHC + qoff);
    short8b qlf = *(const short8b*)(QLC + qoff);
    f32x16 cpv = zero16;

    const unsigned short* Kb0 = KC + (((size_t)b * 64) * 4 + h) * 512
                                   + (size_t)half * 256 + (size_t)q * 8;
    const unsigned short* Vb0 = VC + (((size_t)b * 64) * 4 + h) * 256
                                   + (size_t)q * 32 + half * 4;  // valid q<8

    // prologue: K fragments for chunks ch0, ch0+1; V for chunk ch0
    short8b kfA = *(const short8b*)(Kb0 + (size_t)ch0 * 2048);
    short8b kfB = *(const short8b*)(Kb0 + (size_t)(ch0 + 1) * 2048);
    short8b vf1c, vf2c;
    if (q < 8) {
        const unsigned short* vr = Vb0 + (size_t)ch0 * 1024;
        short4b a0 = *(const short4b*)(vr);
        short4b a1 = *(const short4b*)(vr + 8);
        short4b a2 = *(const short4b*)(vr + 16);
        short4b a3 = *(const short4b*)(vr + 24);
        vf1c = __builtin_shufflevector(a0, a1, 0, 1, 2, 3, 4, 5, 6, 7);
        vf2c = __builtin_shufflevector(a2, a3, 0, 1, 2, 3, 4, 5, 6, 7);
    } else { vf1c = ovf; vf2c = ovf; }

#pragma unroll
    for (int g = 0; g < NGROUP; ++g) {
        unsigned long long mg[4];
        mg[0] = prow[(k0 >> 6) + g * 4 + 0];
        mg[1] = prow[(k0 >> 6) + g * 4 + 1];
        mg[2] = prow[(k0 >> 6) + g * 4 + 2];
        mg[3] = prow[(k0 >> 6) + g * 4 + 3];

#pragma unroll 1
        for (int p = 0; p < 4; ++p) {
            int pa  = g * 4 + p;                // absolute pair index
            int chA = ch0 + 2 * pa;
            int chB = chA + 1;

            // prefetch next pair's K fragments
            short8b kfA_n = kfA, kfB_n = kfB;
            if (pa + 1 < NPT) {
                kfA_n = *(const short8b*)(Kb0 + (size_t)(chA + 2) * 2048);
                kfB_n = *(const short8b*)(Kb0 + (size_t)(chB + 2) * 2048);
            }

            unsigned shA = (unsigned)(p * 16 + half);
            unsigned nA[4], nB[4];
#pragma unroll
            for (int c = 0; c < 4; ++c) {
                nA[c] = (unsigned)(mg[c] >> shA);
                nB[c] = (unsigned)(mg[c] >> (shA + 8u));
            }

            // ---- interleaved QK MFMAs: A1, B1, A2, B2
            __builtin_amdgcn_s_setprio(1);
            f32x16 accA = __builtin_amdgcn_mfma_f32_32x32x16_bf16(kfA, qhf, zero16, 0, 0, 0);
            f32x16 accB = __builtin_amdgcn_mfma_f32_32x32x16_bf16(kfB, qhf, zero16, 0, 0, 0);
            accA = __builtin_amdgcn_mfma_f32_32x32x16_bf16(kfA, qlf, accA, 0, 0, 0);
            accB = __builtin_amdgcn_mfma_f32_32x32x16_bf16(kfB, qlf, accB, 0, 0, 0);
            __builtin_amdgcn_s_setprio(0);

            // prefetch V for chunk B (hides under chunk A's exp/cvt/PV)
            short8b vf1n, vf2n;
            if (q < 8) {
                const unsigned short* vr = Vb0 + (size_t)chB * 1024;
                short4b a0 = *(const short4b*)(vr);
                short4b a1 = *(const short4b*)(vr + 8);
                short4b a2 = *(const short4b*)(vr + 16);
                short4b a3 = *(const short4b*)(vr + 24);
                vf1n = __builtin_shufflevector(a0, a1, 0, 1, 2, 3, 4, 5, 6, 7);
                vf2n = __builtin_shufflevector(a2, a3, 0, 1, 2, 3, 4, 5, 6, 7);
            } else { vf1n = ovf; vf2n = ovf; }

            // ---- chunk A: exp/cvt/PV
            {
                unsigned pr[8];
#pragma unroll
                for (int j = 0; j < 8; ++j) {
                    const int c0 = (2 * j) & 3, c1 = (2 * j + 1) & 3;
                    const int s  = 2 * (j >> 1);
                    float p0 = ((nA[c0] >> s) & 1u) ? 0.0f
                             : __builtin_amdgcn_exp2f(accA[2 * j]);
                    float p1 = ((nA[c1] >> s) & 1u) ? 0.0f
                             : __builtin_amdgcn_exp2f(accA[2 * j + 1]);
                    pr[j] = cvtpk_bf16(p0, p1);
                }
                uint4v t1, t2;
                t1.x = pr[0]; t1.y = pr[1]; t1.z = pr[2]; t1.w = pr[3];
                t2.x = pr[4]; t2.y = pr[5]; t2.z = pr[6]; t2.w = pr[7];
                short8b pfa = __builtin_bit_cast(short8b, t1);
                short8b pfb = __builtin_bit_cast(short8b, t2);

                __builtin_amdgcn_s_setprio(1);
                cpv = __builtin_amdgcn_mfma_f32_32x32x16_bf16(vf1c, pfa, cpv, 0, 0, 0);
                cpv = __builtin_amdgcn_mfma_f32_32x32x16_bf16(vf2c, pfb, cpv, 0, 0, 0);
                __builtin_amdgcn_s_setprio(0);
            }

            // prefetch V for next pair's chunk A
            short8b vf1nn, vf2nn;
            if (pa + 1 < NPT && q < 8) {
                const unsigned short* vr = Vb0 + (size_t)(chA + 2) * 1024;
                short4b a0 = *(const short4b*)(vr);
                short4b a1 = *(const short4b*)(vr + 8);
                short4b a2 = *(const short4b*)(vr + 16);
                short4b a3 = *(const short4b*)(vr + 24);
                vf1nn = __builtin_shufflevector(a0, a1, 0, 1, 2, 3, 4, 5, 6, 7);
                vf2nn = __builtin_shufflevector(a2, a3, 0, 1, 2, 3, 4, 5, 6, 7);
            } else { vf1nn = ovf; vf2nn = ovf; }

            // ---- chunk B: exp/cvt/PV
            {
                unsigned pr[8];
#pragma unroll
                for (int j = 0; j < 8; ++j) {
                    const int c0 = (2 * j) & 3, c1 = (2 * j + 1) & 3;
                    const int s  = 2 * (j >> 1);
                    float p0 = ((nB[c0] >> s) & 1u) ? 0.0f
                             : __builtin_amdgcn_exp2f(accB[2 * j]);
                    float p1 = ((nB[c1] >> s) & 1u) ? 0.0f
                             : __builtin_amdgcn_exp2f(accB[2 * j + 1]);
                    pr[j] = cvtpk_bf16(p0, p1);
                }
                uint4v t1, t2;
                t1.x = pr[0]; t1.y = pr[1]; t1.z = pr[2]; t1.w = pr[3];
                t2.x = pr[4]; t2.y = pr[5]; t2.z = pr[6]; t2.w = pr[7];
                short8b pfa = __builtin_bit_cast(short8b, t1);
                short8b pfb = __builtin_bit_cast(short8b, t2);

                __builtin_amdgcn_s_setprio(1);
                cpv = __builtin_amdgcn_mfma_f32_32x32x16_bf16(vf1n, pfa, cpv, 0, 0, 0);
                cpv = __builtin_amdgcn_mfma_f32_32x32x16_bf16(vf2n, pfb, cpv, 0, 0, 0);
                __builtin_amdgcn_s_setprio(0);
            }

            kfA = kfA_n;
            kfB = kfB_n;
            vf1c = vf1nn;
            vf2c = vf2nn;
        }
    }

    // C_PV: col=q; lower half regs0-3 = dv0-3, reg4 = row8 = l-sum;
    // upper half regs0-3 = dv4-7.
    float4 cv = make_float4(cpv[0], cpv[1], cpv[2], cpv[3]);
    *(float4*)(pctx + ((size_t)seg * NTOK + tokq) * 32 + h * 8 + half * 4) = cv;
    if (half == 0)
        pl[(size_t)seg * NTOK * 4 + tokq * 4 + h] = cpv[4];
}

// ---------------------------------------------------------------------------
// Merge split-K partials (plain sums) -> sa; attn_out = sa@WO + bO + resid; LN.
template<int NSEG>
__global__ __launch_bounds__(256) void combine_epilogue(
    const float* __restrict__ pl, const float* __restrict__ pctx,
    const float* __restrict__ WO, const float* __restrict__ bO,
    const float* __restrict__ resid,
    float* __restrict__ sa_out, float* __restrict__ out0)
{
    __shared__ float sas[8][32];
    __shared__ float Ws[32][32];
    int t = threadIdx.x;
    long base = (long)blockIdx.x * 256;      // 8 tokens x 32
    int r = t >> 5, j = t & 31;
    long tok = (long)blockIdx.x * 8 + r;
    int h = j >> 3;

#pragma unroll
    for (int i = 0; i < 4; ++i) {
        int f = i * 256 + t;
        Ws[f >> 5][f & 31] = WO[f];
    }

    float L = 0.f, ctx = 0.f;
#pragma unroll
    for (int s2 = 0; s2 < NSEG; ++s2) {
        L   += pl[(size_t)s2 * NTOK * 4 + tok * 4 + h];
        ctx += pctx[((size_t)s2 * NTOK + tok) * 32 + j];
    }
    float sa = ctx / L;
    sa_out[base + t] = sa;
    sas[r][j] = sa;
    __syncthreads();

    float y = bO[j] + resid[base + t];
#pragma unroll
    for (int i = 0; i < 32; ++i) y = fmaf(sas[r][i], Ws[i][j], y);

    float sum = y;
#pragma unroll
    for (int o = 16; o >= 1; o >>= 1) sum += __shfl_xor(sum, o, 32);
    float mu = sum * (1.0f / 32.0f);
    float d  = y - mu;
    float sq = d * d;
#pragma unroll
    for (int o = 16; o >= 1; o >>= 1) sq += __shfl_xor(sq, o, 32);
    float var = sq * (1.0f / 32.0f);
    out0[base + t] = d * rsqrtf(var + LN_EPS);
}

// ---------------------------------------------------------------------------
extern "C" void kernel_launch(void* const* d_in, const int* in_sizes, int n_in,
                              void* d_out, int out_size, void* d_ws, size_t ws_size,
                              hipStream_t stream)
{
    const float* inQ = (const float*)d_in[0];
    const float* inK = (const float*)d_in[1];
    const float* inV = (const float*)d_in[2];
    const void*  mask = d_in[3];
    const float* WQ = (const float*)d_in[4];
    const float* bQ = (const float*)d_in[5];
    const float* WK = (const float*)d_in[6];
    const float* bK = (const float*)d_in[7];
    const float* WV = (const float*)d_in[8];
    const float* bV = (const float*)d_in[9];
    const float* WO = (const float*)d_in[10];
    const float* bO = (const float*)d_in[11];

    float* out0 = (float*)d_out;                    // layernorm output
    float* sa   = (float*)d_out + (long)NTOK * 32;  // self_attn output

    char* ws = (char*)d_ws;
    unsigned short* QHC = (unsigned short*)(ws + 256);
    unsigned short* QLC = QHC + (size_t)NTOK * 32;
    unsigned short* KC  = QLC + (size_t)NTOK * 32;
    unsigned short* VC  = KC  + (size_t)NTOK * 64;
    unsigned long long* pack = (unsigned long long*)(VC + (size_t)NTOK * 32);
    float* pbase = (float*)(pack + (size_t)NTOK * (S_LEN / 64));

    size_t fixed  = 256 + 5ul * NTOK * 32 * 2 + (size_t)NTOK * (S_LEN / 64) * 8;
    size_t perseg = (size_t)NTOK * 36 * 4;
    int NS = 1;
    if      (fixed + 4 * perseg <= ws_size) NS = 4;
    else if (fixed + 2 * perseg <= ws_size) NS = 2;

    float* pl   = pbase;
    float* pctx = pl + (long)NS * NTOK * 4;

    prep_kernel<<<3 * PROJ_BLKS + NTOK / 4, 256, 0, stream>>>(
        mask, inQ, inK, inV, WQ, bQ, WK, bK, WV, bV, QHC, QLC, KC, VC, pack);

    int cgrid = NTOK / 8;
    switch (NS) {
    case 4: {
        int agrid = B_SZ * 4 * 64;
        attn_kernel<4><<<agrid, 256, 0, stream>>>(QHC, QLC, KC, VC, pack, pl, pctx);
        combine_epilogue<4><<<cgrid, 256, 0, stream>>>(pl, pctx, WO, bO, inQ, sa, out0);
        break;
    }
    case 2: {
        int agrid = B_SZ * 2 * 64;
        attn_kernel<2><<<agrid, 256, 0, stream>>>(QHC, QLC, KC, VC, pack, pl, pctx);
        combine_epilogue<2><<<cgrid, 256, 0, stream>>>(pl, pctx, WO, bO, inQ, sa, out0);
        break;
    }
    default: {
        int agrid = B_SZ * 1 * 64;
        attn_kernel<1><<<agrid, 256, 0, stream>>>(QHC, QLC, KC, VC, pack, pl, pctx);
        combine_epilogue<1><<<cgrid, 256, 0, stream>>>(pl, pctx, WO, bO, inQ, sa, out0);
        break;
    }
    }
}

// Round 20
// 69.649 us; speedup vs baseline: 2.2657x; 1.0145x over previous
//
#include <hip/hip_runtime.h>
#include <math.h>

#define D_MODEL 32
#define S_LEN   2048
#define B_SZ    8
#define NTOK    (B_SZ * S_LEN)
#define LN_EPS  1e-5f
#define LOG2E   1.44269504088896340736f
#define QK_SCALE 0.35355339059327373f   /* 1/sqrt(8) */
#define PROJ_BLKS (NTOK / 8)            /* 2048 blocks per projection matrix */

typedef __attribute__((ext_vector_type(8)))  short    short8b;
typedef __attribute__((ext_vector_type(4)))  short    short4b;
typedef __attribute__((ext_vector_type(4)))  unsigned uint4v;
typedef __attribute__((ext_vector_type(16))) float    f32x16;

__device__ __forceinline__ unsigned short f2bf(float f) {   // RNE f32->bf16
    unsigned u = __builtin_bit_cast(unsigned, f);
    unsigned r = (u + 0x7FFFu + ((u >> 16) & 1u)) >> 16;
    return (unsigned short)r;
}
__device__ __forceinline__ float bf2f(unsigned short h) {
    return __builtin_bit_cast(float, (unsigned)h << 16);
}
__device__ __forceinline__ unsigned cvtpk_bf16(float lo, float hi) {
    unsigned r;
    asm("v_cvt_pk_bf16_f32 %0, %1, %2" : "=v"(r) : "v"(lo), "v"(hi));
    return r;
}

// Chunk-major layouts (shorts):
//  QHC/QLC: (((b*64 + qt)*4 + h)*32 + q)*8 + d          (1 MB each)
//  KC:      ((((b*64 + ch)*4 + h)*2 + half)*32 + k)*8+d (2 MB, hi|lo halves)
//  VC:      (((b*64 + ch)*4 + h)*8 + dv)*32 + k         (1 MB)
// Mask pack (INTERLEAVED): prow[g*4+c] bit L = mask[row][256g + 4L + c]

// ---------------------------------------------------------------------------
// Fused prep: projection (blocks 0..3*PROJ_BLKS-1) + mask bitpack (rest).
// Verbatim R19 (verified).
__global__ __launch_bounds__(256) void prep_kernel(
    const void* __restrict__ mask,
    const float* __restrict__ xQ, const float* __restrict__ xK,
    const float* __restrict__ xV,
    const float* __restrict__ WQ, const float* __restrict__ bQ,
    const float* __restrict__ WK, const float* __restrict__ bK,
    const float* __restrict__ WV, const float* __restrict__ bV,
    unsigned short* __restrict__ QHC, unsigned short* __restrict__ QLC,
    unsigned short* __restrict__ KC,  unsigned short* __restrict__ VC,
    unsigned long long* __restrict__ pack)
{
    int bid = blockIdx.x;
    int t   = threadIdx.x;

    if (bid < 3 * PROJ_BLKS) {
        int which = bid / PROJ_BLKS;
        int xb    = bid - which * PROJ_BLKS;
        const float* x; const float* W; const float* bias; float scale;
        if (which == 0)      { x = xQ; W = WQ; bias = bQ; scale = QK_SCALE * LOG2E; }
        else if (which == 1) { x = xK; W = WK; bias = bK; scale = 1.0f; }
        else                 { x = xV; W = WV; bias = bV; scale = 1.0f; }

        __shared__ float xs[8][32];
        __shared__ float Ws[32][32];
        long base = (long)xb * 256;    // 8 rows x 32 cols
        xs[t >> 5][t & 31] = x[base + t];
#pragma unroll
        for (int i = 0; i < 4; ++i) {
            int f = i * 256 + t;
            Ws[f >> 5][f & 31] = W[f];
        }
        __syncthreads();
        int r = t >> 5, j = t & 31;
        float acc = bias[j];
#pragma unroll
        for (int i = 0; i < 32; ++i) acc = fmaf(xs[r][i], Ws[i][j], acc);
        acc *= scale;

        long tok = (long)xb * 8 + r;
        long b   = tok >> 11;
        long ti  = tok & (S_LEN - 1);
        int  ch  = (int)(ti >> 5), kq = (int)(ti & 31);
        int  h   = j >> 3, d = j & 7;

        if (which == 0) {
            size_t qi = ((((size_t)b * 64 + ch) * 4 + h) * 32 + kq) * 8 + d;
            unsigned short hv = f2bf(acc);
            QHC[qi] = hv;
            QLC[qi] = f2bf(acc - bf2f(hv));
        } else if (which == 1) {
            size_t ki = (((((size_t)b * 64 + ch) * 4 + h) * 2 + 0) * 32 + kq) * 8 + d;
            unsigned short hv = f2bf(acc);
            KC[ki]       = hv;                       // half 0 (hi)
            KC[ki + 256] = f2bf(acc - bf2f(hv));     // half 1 (lo)
        } else {
            size_t vi = (((size_t)b * 64 + ch) * 4 + h) * 256 + (size_t)d * 32 + kq;
            VC[vi] = f2bf(acc);
        }
    } else {
        int mb   = bid - 3 * PROJ_BLKS;
        long row = (long)mb * 4 + (t >> 6);
        int lane = t & 63;

        int probe = ((const int*)mask)[lane];
        bool is32 = (__ballot((probe & ~0xFF) == 0) == ~0ULL);

        unsigned long long* prow = pack + row * (S_LEN / 64);
        if (is32) {
            const int4* mr4 = (const int4*)((const int*)mask + row * S_LEN);
#pragma unroll
            for (int g = 0; g < 8; ++g) {
                int4 v = mr4[g * 64 + lane];        // keys 256g+4*lane+{0..3}
                unsigned long long b0 = __ballot(v.x != 0);
                unsigned long long b1 = __ballot(v.y != 0);
                unsigned long long b2 = __ballot(v.z != 0);
                unsigned long long b3 = __ballot(v.w != 0);
                if (lane == 0) {
                    prow[g * 4 + 0] = b0; prow[g * 4 + 1] = b1;
                    prow[g * 4 + 2] = b2; prow[g * 4 + 3] = b3;
                }
            }
        } else {
            const int* mri = (const int*)((const unsigned char*)mask + row * S_LEN);
#pragma unroll
            for (int g = 0; g < 8; ++g) {
                int v = mri[g * 64 + lane];         // bytes = keys 256g+4*lane+{0..3}
                unsigned long long b0 = __ballot((v & 0x000000FF) != 0);
                unsigned long long b1 = __ballot((v & 0x0000FF00) != 0);
                unsigned long long b2 = __ballot((v & 0x00FF0000) != 0);
                unsigned long long b3 = __ballot((v & 0xFF000000u) != 0);
                if (lane == 0) {
                    prow[g * 4 + 0] = b0; prow[g * 4 + 1] = b1;
                    prow[g * 4 + 2] = b2; prow[g * 4 + 3] = b3;
                }
            }
        }
    }
}

// ---------------------------------------------------------------------------
// MFMA flash attention (no-max, exp2 domain, split-K, EXACT QK via split-bf16).
// HEAD PER WAVE, 2-chunk QK ILP, single cpv, V pipelined, interleaved mask
// pack. Verbatim R19 body; only NSEG shrinks (fewer, longer waves).
template<int NSEG>
__global__ __launch_bounds__(256, 4) void attn_kernel(
    const unsigned short* __restrict__ QHC, const unsigned short* __restrict__ QLC,
    const unsigned short* __restrict__ KC,  const unsigned short* __restrict__ VC,
    const unsigned long long* __restrict__ pack,
    float* __restrict__ pl, float* __restrict__ pctx)
{
    constexpr int SEGLEN = S_LEN / NSEG;
    constexpr int NGROUP = SEGLEN / 256;    // 256-key groups per segment
    constexpr int NPT    = SEGLEN / 64;     // total pairs
    const int nb    = NSEG * 64;            // blocks per batch (64 q-tiles)
    int raw   = blockIdx.x;
    int total = B_SZ * nb;
    int cpx   = total >> 3;
    int cid   = (raw & 7) * cpx + (raw >> 3);   // XCD-contiguous (total%8==0)
    int b     = cid / nb;
    int rem   = cid - b * nb;
    int seg   = rem >> 6;
    int qt    = rem & 63;
    int h     = threadIdx.x >> 6;           // wave = head
    int lane  = threadIdx.x & 63;
    int q     = lane & 31;
    int half  = lane >> 5;
    int tok0  = qt * 32;
    long tokq = (long)b * S_LEN + tok0 + q;
    int k0    = seg * SEGLEN;
    int ch0   = k0 >> 5;                    // first global chunk of segment

    f32x16 zero16;
#pragma unroll
    for (int i = 0; i < 16; ++i) zero16[i] = 0.0f;

    const unsigned long long* prow = pack + tokq * (S_LEN / 64);

    short ovv = (q == 8) ? (short)0x3F80 : (short)0;
    short8b ovf;
#pragma unroll
    for (int i = 0; i < 8; ++i) ovf[i] = ovv;

    // Q fragments: both halves read the same 512B block (broadcast lines)
    size_t qoff = ((((size_t)b * 64 + qt) * 4 + h) * 32 + q) * 8;
    short8b qhf = *(const short8b*)(QHC + qoff);
    short8b qlf = *(const short8b*)(QLC + qoff);
    f32x16 cpv = zero16;

    const unsigned short* Kb0 = KC + (((size_t)b * 64) * 4 + h) * 512
                                   + (size_t)half * 256 + (size_t)q * 8;
    const unsigned short* Vb0 = VC + (((size_t)b * 64) * 4 + h) * 256
                                   + (size_t)q * 32 + half * 4;  // valid q<8

    // prologue: K fragments for chunks ch0, ch0+1; V for chunk ch0
    short8b kfA = *(const short8b*)(Kb0 + (size_t)ch0 * 2048);
    short8b kfB = *(const short8b*)(Kb0 + (size_t)(ch0 + 1) * 2048);
    short8b vf1c, vf2c;
    if (q < 8) {
        const unsigned short* vr = Vb0 + (size_t)ch0 * 1024;
        short4b a0 = *(const short4b*)(vr);
        short4b a1 = *(const short4b*)(vr + 8);
        short4b a2 = *(const short4b*)(vr + 16);
        short4b a3 = *(const short4b*)(vr + 24);
        vf1c = __builtin_shufflevector(a0, a1, 0, 1, 2, 3, 4, 5, 6, 7);
        vf2c = __builtin_shufflevector(a2, a3, 0, 1, 2, 3, 4, 5, 6, 7);
    } else { vf1c = ovf; vf2c = ovf; }

#pragma unroll
    for (int g = 0; g < NGROUP; ++g) {
        unsigned long long mg[4];
        mg[0] = prow[(k0 >> 6) + g * 4 + 0];
        mg[1] = prow[(k0 >> 6) + g * 4 + 1];
        mg[2] = prow[(k0 >> 6) + g * 4 + 2];
        mg[3] = prow[(k0 >> 6) + g * 4 + 3];

#pragma unroll 1
        for (int p = 0; p < 4; ++p) {
            int pa  = g * 4 + p;                // absolute pair index
            int chA = ch0 + 2 * pa;
            int chB = chA + 1;

            // prefetch next pair's K fragments
            short8b kfA_n = kfA, kfB_n = kfB;
            if (pa + 1 < NPT) {
                kfA_n = *(const short8b*)(Kb0 + (size_t)(chA + 2) * 2048);
                kfB_n = *(const short8b*)(Kb0 + (size_t)(chB + 2) * 2048);
            }

            unsigned shA = (unsigned)(p * 16 + half);
            unsigned nA[4], nB[4];
#pragma unroll
            for (int c = 0; c < 4; ++c) {
                nA[c] = (unsigned)(mg[c] >> shA);
                nB[c] = (unsigned)(mg[c] >> (shA + 8u));
            }

            // ---- interleaved QK MFMAs: A1, B1, A2, B2
            __builtin_amdgcn_s_setprio(1);
            f32x16 accA = __builtin_amdgcn_mfma_f32_32x32x16_bf16(kfA, qhf, zero16, 0, 0, 0);
            f32x16 accB = __builtin_amdgcn_mfma_f32_32x32x16_bf16(kfB, qhf, zero16, 0, 0, 0);
            accA = __builtin_amdgcn_mfma_f32_32x32x16_bf16(kfA, qlf, accA, 0, 0, 0);
            accB = __builtin_amdgcn_mfma_f32_32x32x16_bf16(kfB, qlf, accB, 0, 0, 0);
            __builtin_amdgcn_s_setprio(0);

            // prefetch V for chunk B (hides under chunk A's exp/cvt/PV)
            short8b vf1n, vf2n;
            if (q < 8) {
                const unsigned short* vr = Vb0 + (size_t)chB * 1024;
                short4b a0 = *(const short4b*)(vr);
                short4b a1 = *(const short4b*)(vr + 8);
                short4b a2 = *(const short4b*)(vr + 16);
                short4b a3 = *(const short4b*)(vr + 24);
                vf1n = __builtin_shufflevector(a0, a1, 0, 1, 2, 3, 4, 5, 6, 7);
                vf2n = __builtin_shufflevector(a2, a3, 0, 1, 2, 3, 4, 5, 6, 7);
            } else { vf1n = ovf; vf2n = ovf; }

            // ---- chunk A: exp/cvt/PV
            {
                unsigned pr[8];
#pragma unroll
                for (int j = 0; j < 8; ++j) {
                    const int c0 = (2 * j) & 3, c1 = (2 * j + 1) & 3;
                    const int s  = 2 * (j >> 1);
                    float p0 = ((nA[c0] >> s) & 1u) ? 0.0f
                             : __builtin_amdgcn_exp2f(accA[2 * j]);
                    float p1 = ((nA[c1] >> s) & 1u) ? 0.0f
                             : __builtin_amdgcn_exp2f(accA[2 * j + 1]);
                    pr[j] = cvtpk_bf16(p0, p1);
                }
                uint4v t1, t2;
                t1.x = pr[0]; t1.y = pr[1]; t1.z = pr[2]; t1.w = pr[3];
                t2.x = pr[4]; t2.y = pr[5]; t2.z = pr[6]; t2.w = pr[7];
                short8b pfa = __builtin_bit_cast(short8b, t1);
                short8b pfb = __builtin_bit_cast(short8b, t2);

                __builtin_amdgcn_s_setprio(1);
                cpv = __builtin_amdgcn_mfma_f32_32x32x16_bf16(vf1c, pfa, cpv, 0, 0, 0);
                cpv = __builtin_amdgcn_mfma_f32_32x32x16_bf16(vf2c, pfb, cpv, 0, 0, 0);
                __builtin_amdgcn_s_setprio(0);
            }

            // prefetch V for next pair's chunk A
            short8b vf1nn, vf2nn;
            if (pa + 1 < NPT && q < 8) {
                const unsigned short* vr = Vb0 + (size_t)(chA + 2) * 1024;
                short4b a0 = *(const short4b*)(vr);
                short4b a1 = *(const short4b*)(vr + 8);
                short4b a2 = *(const short4b*)(vr + 16);
                short4b a3 = *(const short4b*)(vr + 24);
                vf1nn = __builtin_shufflevector(a0, a1, 0, 1, 2, 3, 4, 5, 6, 7);
                vf2nn = __builtin_shufflevector(a2, a3, 0, 1, 2, 3, 4, 5, 6, 7);
            } else { vf1nn = ovf; vf2nn = ovf; }

            // ---- chunk B: exp/cvt/PV
            {
                unsigned pr[8];
#pragma unroll
                for (int j = 0; j < 8; ++j) {
                    const int c0 = (2 * j) & 3, c1 = (2 * j + 1) & 3;
                    const int s  = 2 * (j >> 1);
                    float p0 = ((nB[c0] >> s) & 1u) ? 0.0f
                             : __builtin_amdgcn_exp2f(accB[2 * j]);
                    float p1 = ((nB[c1] >> s) & 1u) ? 0.0f
                             : __builtin_amdgcn_exp2f(accB[2 * j + 1]);
                    pr[j] = cvtpk_bf16(p0, p1);
                }
                uint4v t1, t2;
                t1.x = pr[0]; t1.y = pr[1]; t1.z = pr[2]; t1.w = pr[3];
                t2.x = pr[4]; t2.y = pr[5]; t2.z = pr[6]; t2.w = pr[7];
                short8b pfa = __builtin_bit_cast(short8b, t1);
                short8b pfb = __builtin_bit_cast(short8b, t2);

                __builtin_amdgcn_s_setprio(1);
                cpv = __builtin_amdgcn_mfma_f32_32x32x16_bf16(vf1n, pfa, cpv, 0, 0, 0);
                cpv = __builtin_amdgcn_mfma_f32_32x32x16_bf16(vf2n, pfb, cpv, 0, 0, 0);
                __builtin_amdgcn_s_setprio(0);
            }

            kfA = kfA_n;
            kfB = kfB_n;
            vf1c = vf1nn;
            vf2c = vf2nn;
        }
    }

    // C_PV: col=q; lower half regs0-3 = dv0-3, reg4 = row8 = l-sum;
    // upper half regs0-3 = dv4-7.
    float4 cv = make_float4(cpv[0], cpv[1], cpv[2], cpv[3]);
    *(float4*)(pctx + ((size_t)seg * NTOK + tokq) * 32 + h * 8 + half * 4) = cv;
    if (half == 0)
        pl[(size_t)seg * NTOK * 4 + tokq * 4 + h] = cpv[4];
}

// ---------------------------------------------------------------------------
// Merge split-K partials (plain sums) -> sa; attn_out = sa@WO + bO + resid; LN.
template<int NSEG>
__global__ __launch_bounds__(256) void combine_epilogue(
    const float* __restrict__ pl, const float* __restrict__ pctx,
    const float* __restrict__ WO, const float* __restrict__ bO,
    const float* __restrict__ resid,
    float* __restrict__ sa_out, float* __restrict__ out0)
{
    __shared__ float sas[8][32];
    __shared__ float Ws[32][32];
    int t = threadIdx.x;
    long base = (long)blockIdx.x * 256;      // 8 tokens x 32
    int r = t >> 5, j = t & 31;
    long tok = (long)blockIdx.x * 8 + r;
    int h = j >> 3;

#pragma unroll
    for (int i = 0; i < 4; ++i) {
        int f = i * 256 + t;
        Ws[f >> 5][f & 31] = WO[f];
    }

    float L = 0.f, ctx = 0.f;
#pragma unroll
    for (int s2 = 0; s2 < NSEG; ++s2) {
        L   += pl[(size_t)s2 * NTOK * 4 + tok * 4 + h];
        ctx += pctx[((size_t)s2 * NTOK + tok) * 32 + j];
    }
    float sa = ctx / L;
    sa_out[base + t] = sa;
    sas[r][j] = sa;
    __syncthreads();

    float y = bO[j] + resid[base + t];
#pragma unroll
    for (int i = 0; i < 32; ++i) y = fmaf(sas[r][i], Ws[i][j], y);

    float sum = y;
#pragma unroll
    for (int o = 16; o >= 1; o >>= 1) sum += __shfl_xor(sum, o, 32);
    float mu = sum * (1.0f / 32.0f);
    float d  = y - mu;
    float sq = d * d;
#pragma unroll
    for (int o = 16; o >= 1; o >>= 1) sq += __shfl_xor(sq, o, 32);
    float var = sq * (1.0f / 32.0f);
    out0[base + t] = d * rsqrtf(var + LN_EPS);
}

// ---------------------------------------------------------------------------
extern "C" void kernel_launch(void* const* d_in, const int* in_sizes, int n_in,
                              void* d_out, int out_size, void* d_ws, size_t ws_size,
                              hipStream_t stream)
{
    const float* inQ = (const float*)d_in[0];
    const float* inK = (const float*)d_in[1];
    const float* inV = (const float*)d_in[2];
    const void*  mask = d_in[3];
    const float* WQ = (const float*)d_in[4];
    const float* bQ = (const float*)d_in[5];
    const float* WK = (const float*)d_in[6];
    const float* bK = (const float*)d_in[7];
    const float* WV = (const float*)d_in[8];
    const float* bV = (const float*)d_in[9];
    const float* WO = (const float*)d_in[10];
    const float* bO = (const float*)d_in[11];

    float* out0 = (float*)d_out;                    // layernorm output
    float* sa   = (float*)d_out + (long)NTOK * 32;  // self_attn output

    char* ws = (char*)d_ws;
    unsigned short* QHC = (unsigned short*)(ws + 256);
    unsigned short* QLC = QHC + (size_t)NTOK * 32;
    unsigned short* KC  = QLC + (size_t)NTOK * 32;
    unsigned short* VC  = KC  + (size_t)NTOK * 64;
    unsigned long long* pack = (unsigned long long*)(VC + (size_t)NTOK * 32);
    float* pbase = (float*)(pack + (size_t)NTOK * (S_LEN / 64));

    size_t fixed  = 256 + 5ul * NTOK * 32 * 2 + (size_t)NTOK * (S_LEN / 64) * 8;
    size_t perseg = (size_t)NTOK * 36 * 4;
    int NS = 1;
    if (fixed + 2 * perseg <= ws_size) NS = 2;

    float* pl   = pbase;
    float* pctx = pl + (long)NS * NTOK * 4;

    prep_kernel<<<3 * PROJ_BLKS + NTOK / 4, 256, 0, stream>>>(
        mask, inQ, inK, inV, WQ, bQ, WK, bK, WV, bV, QHC, QLC, KC, VC, pack);

    int cgrid = NTOK / 8;
    switch (NS) {
    case 2: {
        int agrid = B_SZ * 2 * 64;
        attn_kernel<2><<<agrid, 256, 0, stream>>>(QHC, QLC, KC, VC, pack, pl, pctx);
        combine_epilogue<2><<<cgrid, 256, 0, stream>>>(pl, pctx, WO, bO, inQ, sa, out0);
        break;
    }
    default: {
        int agrid = B_SZ * 1 * 64;
        attn_kernel<1><<<agrid, 256, 0, stream>>>(QHC, QLC, KC, VC, pack, pl, pctx);
        combine_epilogue<1><<<cgrid, 256, 0, stream>>>(pl, pctx, WO, bO, inQ, sa, out0);
        break;
    }
    }
}

// Round 21
// 66.846 us; speedup vs baseline: 2.3607x; 1.0419x over previous
//
#include <hip/hip_runtime.h>
#include <math.h>

#define D_MODEL 32
#define S_LEN   2048
#define B_SZ    8
#define NTOK    (B_SZ * S_LEN)
#define LN_EPS  1e-5f
#define LOG2E   1.44269504088896340736f
#define QK_SCALE 0.35355339059327373f   /* 1/sqrt(8) */
#define PROJ_BLKS (NTOK / 8)            /* 2048 blocks per projection matrix */

typedef __attribute__((ext_vector_type(8)))  short    short8b;
typedef __attribute__((ext_vector_type(4)))  short    short4b;
typedef __attribute__((ext_vector_type(4)))  unsigned uint4v;
typedef __attribute__((ext_vector_type(16))) float    f32x16;

__device__ __forceinline__ unsigned short f2bf(float f) {   // RNE f32->bf16
    unsigned u = __builtin_bit_cast(unsigned, f);
    unsigned r = (u + 0x7FFFu + ((u >> 16) & 1u)) >> 16;
    return (unsigned short)r;
}
__device__ __forceinline__ float bf2f(unsigned short h) {
    return __builtin_bit_cast(float, (unsigned)h << 16);
}
__device__ __forceinline__ unsigned cvtpk_bf16(float lo, float hi) {
    unsigned r;
    asm("v_cvt_pk_bf16_f32 %0, %1, %2" : "=v"(r) : "v"(lo), "v"(hi));
    return r;
}

// Chunk-major layouts (shorts):
//  QHC/QLC: (((b*64 + qt)*4 + h)*32 + q)*8 + d          (1 MB each)
//  KC:      ((((b*64 + ch)*4 + h)*2 + half)*32 + k)*8+d (2 MB, hi|lo halves)
//  VC:      (((b*64 + ch)*4 + h)*8 + dv)*32 + k         (1 MB)
// Mask pack (INTERLEAVED): prow[g*4+c] bit L = mask[row][256g + 4L + c]

// ---------------------------------------------------------------------------
// Fused prep: projection (blocks 0..3*PROJ_BLKS-1) + mask bitpack (rest).
// Verbatim R19/R20 (verified).
__global__ __launch_bounds__(256) void prep_kernel(
    const void* __restrict__ mask,
    const float* __restrict__ xQ, const float* __restrict__ xK,
    const float* __restrict__ xV,
    const float* __restrict__ WQ, const float* __restrict__ bQ,
    const float* __restrict__ WK, const float* __restrict__ bK,
    const float* __restrict__ WV, const float* __restrict__ bV,
    unsigned short* __restrict__ QHC, unsigned short* __restrict__ QLC,
    unsigned short* __restrict__ KC,  unsigned short* __restrict__ VC,
    unsigned long long* __restrict__ pack)
{
    int bid = blockIdx.x;
    int t   = threadIdx.x;

    if (bid < 3 * PROJ_BLKS) {
        int which = bid / PROJ_BLKS;
        int xb    = bid - which * PROJ_BLKS;
        const float* x; const float* W; const float* bias; float scale;
        if (which == 0)      { x = xQ; W = WQ; bias = bQ; scale = QK_SCALE * LOG2E; }
        else if (which == 1) { x = xK; W = WK; bias = bK; scale = 1.0f; }
        else                 { x = xV; W = WV; bias = bV; scale = 1.0f; }

        __shared__ float xs[8][32];
        __shared__ float Ws[32][32];
        long base = (long)xb * 256;    // 8 rows x 32 cols
        xs[t >> 5][t & 31] = x[base + t];
#pragma unroll
        for (int i = 0; i < 4; ++i) {
            int f = i * 256 + t;
            Ws[f >> 5][f & 31] = W[f];
        }
        __syncthreads();
        int r = t >> 5, j = t & 31;
        float acc = bias[j];
#pragma unroll
        for (int i = 0; i < 32; ++i) acc = fmaf(xs[r][i], Ws[i][j], acc);
        acc *= scale;

        long tok = (long)xb * 8 + r;
        long b   = tok >> 11;
        long ti  = tok & (S_LEN - 1);
        int  ch  = (int)(ti >> 5), kq = (int)(ti & 31);
        int  h   = j >> 3, d = j & 7;

        if (which == 0) {
            size_t qi = ((((size_t)b * 64 + ch) * 4 + h) * 32 + kq) * 8 + d;
            unsigned short hv = f2bf(acc);
            QHC[qi] = hv;
            QLC[qi] = f2bf(acc - bf2f(hv));
        } else if (which == 1) {
            size_t ki = (((((size_t)b * 64 + ch) * 4 + h) * 2 + 0) * 32 + kq) * 8 + d;
            unsigned short hv = f2bf(acc);
            KC[ki]       = hv;                       // half 0 (hi)
            KC[ki + 256] = f2bf(acc - bf2f(hv));     // half 1 (lo)
        } else {
            size_t vi = (((size_t)b * 64 + ch) * 4 + h) * 256 + (size_t)d * 32 + kq;
            VC[vi] = f2bf(acc);
        }
    } else {
        int mb   = bid - 3 * PROJ_BLKS;
        long row = (long)mb * 4 + (t >> 6);
        int lane = t & 63;

        int probe = ((const int*)mask)[lane];
        bool is32 = (__ballot((probe & ~0xFF) == 0) == ~0ULL);

        unsigned long long* prow = pack + row * (S_LEN / 64);
        if (is32) {
            const int4* mr4 = (const int4*)((const int*)mask + row * S_LEN);
#pragma unroll
            for (int g = 0; g < 8; ++g) {
                int4 v = mr4[g * 64 + lane];        // keys 256g+4*lane+{0..3}
                unsigned long long b0 = __ballot(v.x != 0);
                unsigned long long b1 = __ballot(v.y != 0);
                unsigned long long b2 = __ballot(v.z != 0);
                unsigned long long b3 = __ballot(v.w != 0);
                if (lane == 0) {
                    prow[g * 4 + 0] = b0; prow[g * 4 + 1] = b1;
                    prow[g * 4 + 2] = b2; prow[g * 4 + 3] = b3;
                }
            }
        } else {
            const int* mri = (const int*)((const unsigned char*)mask + row * S_LEN);
#pragma unroll
            for (int g = 0; g < 8; ++g) {
                int v = mri[g * 64 + lane];         // bytes = keys 256g+4*lane+{0..3}
                unsigned long long b0 = __ballot((v & 0x000000FF) != 0);
                unsigned long long b1 = __ballot((v & 0x0000FF00) != 0);
                unsigned long long b2 = __ballot((v & 0x00FF0000) != 0);
                unsigned long long b3 = __ballot((v & 0xFF000000u) != 0);
                if (lane == 0) {
                    prow[g * 4 + 0] = b0; prow[g * 4 + 1] = b1;
                    prow[g * 4 + 2] = b2; prow[g * 4 + 3] = b3;
                }
            }
        }
    }
}

// ---------------------------------------------------------------------------
// FULLY-FUSED MFMA flash attention + combine + O-projection + LayerNorm.
// Block = 512 threads = 8 waves = {2 segments x 4 heads} of one (b, 32-q tile).
// Each wave's main loop is verbatim R20 (SEGLEN=1024). Waves exchange
// (ctx, l) via padded LDS; block epilogue does sa = sum(ctx)/sum(l),
// y = sa@WO + bO + resid, LayerNorm -> out0, sa -> sa_out.
__global__ __launch_bounds__(512, 4) void attn_fused_kernel(
    const unsigned short* __restrict__ QHC, const unsigned short* __restrict__ QLC,
    const unsigned short* __restrict__ KC,  const unsigned short* __restrict__ VC,
    const unsigned long long* __restrict__ pack,
    const float* __restrict__ WO, const float* __restrict__ bO,
    const float* __restrict__ resid,
    float* __restrict__ sa_out, float* __restrict__ out0)
{
    constexpr int SEGLEN = 1024;
    constexpr int NGROUP = SEGLEN / 256;    // 4
    constexpr int NPT    = SEGLEN / 64;     // 16
    __shared__ float ctx_lds[2][32][33];    // [seg][tok][col], padded
    __shared__ float l_lds[2][32][4];       // [seg][tok][head]
    __shared__ float sa_lds[32][33];
    __shared__ float Ws[32][32];

    int raw  = blockIdx.x;                  // 512 blocks
    int cid  = (raw & 7) * 64 + (raw >> 3); // XCD-contiguous (batch==XCD)
    int b    = cid >> 6;
    int qt   = cid & 63;
    int tid  = threadIdx.x;
    int w    = tid >> 6;                    // wave 0..7
    int h    = w & 3;
    int seg  = w >> 2;
    int lane = tid & 63;
    int q    = lane & 31;
    int half = lane >> 5;
    int tok0 = qt * 32;
    long tokq = (long)b * S_LEN + tok0 + q;
    int k0   = seg * SEGLEN;
    int ch0  = k0 >> 5;

    // stage WO (used only after the final barrier)
    Ws[(tid >> 5) + ((tid & 31) >> 5) * 0][tid & 31] = 0.0f;  // (placate none)
#pragma unroll
    for (int i = 0; i < 2; ++i) {
        int f = i * 512 + tid;
        Ws[f >> 5][f & 31] = WO[f];
    }

    f32x16 zero16;
#pragma unroll
    for (int i = 0; i < 16; ++i) zero16[i] = 0.0f;

    const unsigned long long* prow = pack + tokq * (S_LEN / 64);

    short ovv = (q == 8) ? (short)0x3F80 : (short)0;
    short8b ovf;
#pragma unroll
    for (int i = 0; i < 8; ++i) ovf[i] = ovv;

    size_t qoff = ((((size_t)b * 64 + qt) * 4 + h) * 32 + q) * 8;
    short8b qhf = *(const short8b*)(QHC + qoff);
    short8b qlf = *(const short8b*)(QLC + qoff);
    f32x16 cpv = zero16;

    const unsigned short* Kb0 = KC + (((size_t)b * 64) * 4 + h) * 512
                                   + (size_t)half * 256 + (size_t)q * 8;
    const unsigned short* Vb0 = VC + (((size_t)b * 64) * 4 + h) * 256
                                   + (size_t)q * 32 + half * 4;  // valid q<8

    short8b kfA = *(const short8b*)(Kb0 + (size_t)ch0 * 2048);
    short8b kfB = *(const short8b*)(Kb0 + (size_t)(ch0 + 1) * 2048);
    short8b vf1c, vf2c;
    if (q < 8) {
        const unsigned short* vr = Vb0 + (size_t)ch0 * 1024;
        short4b a0 = *(const short4b*)(vr);
        short4b a1 = *(const short4b*)(vr + 8);
        short4b a2 = *(const short4b*)(vr + 16);
        short4b a3 = *(const short4b*)(vr + 24);
        vf1c = __builtin_shufflevector(a0, a1, 0, 1, 2, 3, 4, 5, 6, 7);
        vf2c = __builtin_shufflevector(a2, a3, 0, 1, 2, 3, 4, 5, 6, 7);
    } else { vf1c = ovf; vf2c = ovf; }

#pragma unroll
    for (int g = 0; g < NGROUP; ++g) {
        unsigned long long mg[4];
        mg[0] = prow[(k0 >> 6) + g * 4 + 0];
        mg[1] = prow[(k0 >> 6) + g * 4 + 1];
        mg[2] = prow[(k0 >> 6) + g * 4 + 2];
        mg[3] = prow[(k0 >> 6) + g * 4 + 3];

#pragma unroll 1
        for (int p = 0; p < 4; ++p) {
            int pa  = g * 4 + p;
            int chA = ch0 + 2 * pa;
            int chB = chA + 1;

            short8b kfA_n = kfA, kfB_n = kfB;
            if (pa + 1 < NPT) {
                kfA_n = *(const short8b*)(Kb0 + (size_t)(chA + 2) * 2048);
                kfB_n = *(const short8b*)(Kb0 + (size_t)(chB + 2) * 2048);
            }

            unsigned shA = (unsigned)(p * 16 + half);
            unsigned nA[4], nB[4];
#pragma unroll
            for (int c = 0; c < 4; ++c) {
                nA[c] = (unsigned)(mg[c] >> shA);
                nB[c] = (unsigned)(mg[c] >> (shA + 8u));
            }

            __builtin_amdgcn_s_setprio(1);
            f32x16 accA = __builtin_amdgcn_mfma_f32_32x32x16_bf16(kfA, qhf, zero16, 0, 0, 0);
            f32x16 accB = __builtin_amdgcn_mfma_f32_32x32x16_bf16(kfB, qhf, zero16, 0, 0, 0);
            accA = __builtin_amdgcn_mfma_f32_32x32x16_bf16(kfA, qlf, accA, 0, 0, 0);
            accB = __builtin_amdgcn_mfma_f32_32x32x16_bf16(kfB, qlf, accB, 0, 0, 0);
            __builtin_amdgcn_s_setprio(0);

            short8b vf1n, vf2n;
            if (q < 8) {
                const unsigned short* vr = Vb0 + (size_t)chB * 1024;
                short4b a0 = *(const short4b*)(vr);
                short4b a1 = *(const short4b*)(vr + 8);
                short4b a2 = *(const short4b*)(vr + 16);
                short4b a3 = *(const short4b*)(vr + 24);
                vf1n = __builtin_shufflevector(a0, a1, 0, 1, 2, 3, 4, 5, 6, 7);
                vf2n = __builtin_shufflevector(a2, a3, 0, 1, 2, 3, 4, 5, 6, 7);
            } else { vf1n = ovf; vf2n = ovf; }

            {
                unsigned pr[8];
#pragma unroll
                for (int j = 0; j < 8; ++j) {
                    const int c0 = (2 * j) & 3, c1 = (2 * j + 1) & 3;
                    const int s  = 2 * (j >> 1);
                    float p0 = ((nA[c0] >> s) & 1u) ? 0.0f
                             : __builtin_amdgcn_exp2f(accA[2 * j]);
                    float p1 = ((nA[c1] >> s) & 1u) ? 0.0f
                             : __builtin_amdgcn_exp2f(accA[2 * j + 1]);
                    pr[j] = cvtpk_bf16(p0, p1);
                }
                uint4v t1, t2;
                t1.x = pr[0]; t1.y = pr[1]; t1.z = pr[2]; t1.w = pr[3];
                t2.x = pr[4]; t2.y = pr[5]; t2.z = pr[6]; t2.w = pr[7];
                short8b pfa = __builtin_bit_cast(short8b, t1);
                short8b pfb = __builtin_bit_cast(short8b, t2);

                __builtin_amdgcn_s_setprio(1);
                cpv = __builtin_amdgcn_mfma_f32_32x32x16_bf16(vf1c, pfa, cpv, 0, 0, 0);
                cpv = __builtin_amdgcn_mfma_f32_32x32x16_bf16(vf2c, pfb, cpv, 0, 0, 0);
                __builtin_amdgcn_s_setprio(0);
            }

            short8b vf1nn, vf2nn;
            if (pa + 1 < NPT && q < 8) {
                const unsigned short* vr = Vb0 + (size_t)(chA + 2) * 1024;
                short4b a0 = *(const short4b*)(vr);
                short4b a1 = *(const short4b*)(vr + 8);
                short4b a2 = *(const short4b*)(vr + 16);
                short4b a3 = *(const short4b*)(vr + 24);
                vf1nn = __builtin_shufflevector(a0, a1, 0, 1, 2, 3, 4, 5, 6, 7);
                vf2nn = __builtin_shufflevector(a2, a3, 0, 1, 2, 3, 4, 5, 6, 7);
            } else { vf1nn = ovf; vf2nn = ovf; }

            {
                unsigned pr[8];
#pragma unroll
                for (int j = 0; j < 8; ++j) {
                    const int c0 = (2 * j) & 3, c1 = (2 * j + 1) & 3;
                    const int s  = 2 * (j >> 1);
                    float p0 = ((nB[c0] >> s) & 1u) ? 0.0f
                             : __builtin_amdgcn_exp2f(accB[2 * j]);
                    float p1 = ((nB[c1] >> s) & 1u) ? 0.0f
                             : __builtin_amdgcn_exp2f(accB[2 * j + 1]);
                    pr[j] = cvtpk_bf16(p0, p1);
                }
                uint4v t1, t2;
                t1.x = pr[0]; t1.y = pr[1]; t1.z = pr[2]; t1.w = pr[3];
                t2.x = pr[4]; t2.y = pr[5]; t2.z = pr[6]; t2.w = pr[7];
                short8b pfa = __builtin_bit_cast(short8b, t1);
                short8b pfb = __builtin_bit_cast(short8b, t2);

                __builtin_amdgcn_s_setprio(1);
                cpv = __builtin_amdgcn_mfma_f32_32x32x16_bf16(vf1n, pfa, cpv, 0, 0, 0);
                cpv = __builtin_amdgcn_mfma_f32_32x32x16_bf16(vf2n, pfb, cpv, 0, 0, 0);
                __builtin_amdgcn_s_setprio(0);
            }

            kfA = kfA_n;
            kfB = kfB_n;
            vf1c = vf1nn;
            vf2c = vf2nn;
        }
    }

    // ---- exchange partials through LDS (C_PV: col=q; rows per C/D formula)
    ctx_lds[seg][q][h * 8 + half * 4 + 0] = cpv[0];
    ctx_lds[seg][q][h * 8 + half * 4 + 1] = cpv[1];
    ctx_lds[seg][q][h * 8 + half * 4 + 2] = cpv[2];
    ctx_lds[seg][q][h * 8 + half * 4 + 3] = cpv[3];
    if (half == 0) l_lds[seg][q][h] = cpv[4];
    __syncthreads();

    // ---- combine + sa write (32 tokens x 32 cols; 512 threads, 2 passes)
    int r = (tid >> 5) & 15;
    int j = tid & 31;
#pragma unroll
    for (int pass = 0; pass < 2; ++pass) {
        int tok = pass * 16 + r;
        float L  = l_lds[0][tok][j >> 3] + l_lds[1][tok][j >> 3];
        float cx = ctx_lds[0][tok][j] + ctx_lds[1][tok][j];
        float sa = cx / L;
        sa_lds[tok][j] = sa;
        sa_out[((long)b * S_LEN + tok0 + tok) * 32 + j] = sa;
    }
    __syncthreads();

    // ---- O-projection + residual + LayerNorm
#pragma unroll
    for (int pass = 0; pass < 2; ++pass) {
        int tok = pass * 16 + r;
        long grow = ((long)b * S_LEN + tok0 + tok) * 32;
        float y = bO[j] + resid[grow + j];
#pragma unroll
        for (int i = 0; i < 32; ++i) y = fmaf(sa_lds[tok][i], Ws[i][j], y);

        float sum = y;
#pragma unroll
        for (int o = 16; o >= 1; o >>= 1) sum += __shfl_xor(sum, o, 32);
        float mu = sum * (1.0f / 32.0f);
        float d  = y - mu;
        float sq = d * d;
#pragma unroll
        for (int o = 16; o >= 1; o >>= 1) sq += __shfl_xor(sq, o, 32);
        float var = sq * (1.0f / 32.0f);
        out0[grow + j] = d * rsqrtf(var + LN_EPS);
    }
}

// ---------------------------------------------------------------------------
extern "C" void kernel_launch(void* const* d_in, const int* in_sizes, int n_in,
                              void* d_out, int out_size, void* d_ws, size_t ws_size,
                              hipStream_t stream)
{
    const float* inQ = (const float*)d_in[0];
    const float* inK = (const float*)d_in[1];
    const float* inV = (const float*)d_in[2];
    const void*  mask = d_in[3];
    const float* WQ = (const float*)d_in[4];
    const float* bQ = (const float*)d_in[5];
    const float* WK = (const float*)d_in[6];
    const float* bK = (const float*)d_in[7];
    const float* WV = (const float*)d_in[8];
    const float* bV = (const float*)d_in[9];
    const float* WO = (const float*)d_in[10];
    const float* bO = (const float*)d_in[11];

    float* out0 = (float*)d_out;                    // layernorm output
    float* sa   = (float*)d_out + (long)NTOK * 32;  // self_attn output

    char* ws = (char*)d_ws;
    unsigned short* QHC = (unsigned short*)(ws + 256);
    unsigned short* QLC = QHC + (size_t)NTOK * 32;
    unsigned short* KC  = QLC + (size_t)NTOK * 32;
    unsigned short* VC  = KC  + (size_t)NTOK * 64;
    unsigned long long* pack = (unsigned long long*)(VC + (size_t)NTOK * 32);

    prep_kernel<<<3 * PROJ_BLKS + NTOK / 4, 256, 0, stream>>>(
        mask, inQ, inK, inV, WQ, bQ, WK, bK, WV, bV, QHC, QLC, KC, VC, pack);

    attn_fused_kernel<<<B_SZ * 64, 512, 0, stream>>>(
        QHC, QLC, KC, VC, pack, WO, bO, inQ, sa, out0);
}

// Round 22
// 61.498 us; speedup vs baseline: 2.5660x; 1.0870x over previous
//
#include <hip/hip_runtime.h>
#include <math.h>

#define D_MODEL 32
#define S_LEN   2048
#define B_SZ    8
#define NTOK    (B_SZ * S_LEN)
#define LN_EPS  1e-5f
#define LOG2E   1.44269504088896340736f
#define QK_SCALE 0.35355339059327373f   /* 1/sqrt(8) */
#define PROJ_BLKS (NTOK / 8)            /* 2048 blocks per projection matrix */

typedef __attribute__((ext_vector_type(8)))  short    short8b;
typedef __attribute__((ext_vector_type(4)))  short    short4b;
typedef __attribute__((ext_vector_type(4)))  unsigned uint4v;
typedef __attribute__((ext_vector_type(16))) float    f32x16;

__device__ __forceinline__ unsigned short f2bf(float f) {   // RNE f32->bf16
    unsigned u = __builtin_bit_cast(unsigned, f);
    unsigned r = (u + 0x7FFFu + ((u >> 16) & 1u)) >> 16;
    return (unsigned short)r;
}
__device__ __forceinline__ float bf2f(unsigned short h) {
    return __builtin_bit_cast(float, (unsigned)h << 16);
}
__device__ __forceinline__ unsigned cvtpk_bf16(float lo, float hi) {
    unsigned r;
    asm("v_cvt_pk_bf16_f32 %0, %1, %2" : "=v"(r) : "v"(lo), "v"(hi));
    return r;
}

// Chunk-major layouts (shorts):
//  QHC/QLC: (((b*64 + qt)*4 + h)*32 + q)*8 + d          (1 MB each)
//  KC:      ((((b*64 + ch)*4 + h)*2 + half)*32 + k)*8+d (2 MB, hi|lo halves)
//  VC:      (((b*64 + ch)*4 + h)*8 + dv)*32 + k         (1 MB)

// ---------------------------------------------------------------------------
// Prep: projection only (mask handled inside the fused attn kernel now).
__global__ __launch_bounds__(256) void prep_kernel(
    const float* __restrict__ xQ, const float* __restrict__ xK,
    const float* __restrict__ xV,
    const float* __restrict__ WQ, const float* __restrict__ bQ,
    const float* __restrict__ WK, const float* __restrict__ bK,
    const float* __restrict__ WV, const float* __restrict__ bV,
    unsigned short* __restrict__ QHC, unsigned short* __restrict__ QLC,
    unsigned short* __restrict__ KC,  unsigned short* __restrict__ VC)
{
    int bid = blockIdx.x;
    int t   = threadIdx.x;

    int which = bid / PROJ_BLKS;
    int xb    = bid - which * PROJ_BLKS;
    const float* x; const float* W; const float* bias; float scale;
    if (which == 0)      { x = xQ; W = WQ; bias = bQ; scale = QK_SCALE * LOG2E; }
    else if (which == 1) { x = xK; W = WK; bias = bK; scale = 1.0f; }
    else                 { x = xV; W = WV; bias = bV; scale = 1.0f; }

    __shared__ float xs[8][32];
    __shared__ float Ws[32][32];
    long base = (long)xb * 256;    // 8 rows x 32 cols
    xs[t >> 5][t & 31] = x[base + t];
#pragma unroll
    for (int i = 0; i < 4; ++i) {
        int f = i * 256 + t;
        Ws[f >> 5][f & 31] = W[f];
    }
    __syncthreads();
    int r = t >> 5, j = t & 31;
    float acc = bias[j];
#pragma unroll
    for (int i = 0; i < 32; ++i) acc = fmaf(xs[r][i], Ws[i][j], acc);
    acc *= scale;

    long tok = (long)xb * 8 + r;
    long b   = tok >> 11;
    long ti  = tok & (S_LEN - 1);
    int  ch  = (int)(ti >> 5), kq = (int)(ti & 31);
    int  h   = j >> 3, d = j & 7;

    if (which == 0) {
        size_t qi = ((((size_t)b * 64 + ch) * 4 + h) * 32 + kq) * 8 + d;
        unsigned short hv = f2bf(acc);
        QHC[qi] = hv;
        QLC[qi] = f2bf(acc - bf2f(hv));
    } else if (which == 1) {
        size_t ki = (((((size_t)b * 64 + ch) * 4 + h) * 2 + 0) * 32 + kq) * 8 + d;
        unsigned short hv = f2bf(acc);
        KC[ki]       = hv;                       // half 0 (hi)
        KC[ki + 256] = f2bf(acc - bf2f(hv));     // half 1 (lo)
    } else {
        size_t vi = (((size_t)b * 64 + ch) * 4 + h) * 256 + (size_t)d * 32 + kq;
        VC[vi] = f2bf(acc);
    }
}

// ---------------------------------------------------------------------------
// FULLY-FUSED: in-loop mask ballot-pack (double-buffered, overlapped with
// compute) + MFMA flash attention + combine + O-projection + LayerNorm.
// Block = 512 threads = 8 waves = {2 segments x 4 heads} of one (b, 32q-tile).
// Per 256-key group step: pack group g+1's raw mask rows (coalesced int4
// loads + ballots, this block's 32 rows only) while computing group g from
// the LDS-packed words; one __syncthreads per step.
// Arithmetic per output is verbatim R21.
__global__ __launch_bounds__(512, 4) void attn_fused_kernel(
    const unsigned short* __restrict__ QHC, const unsigned short* __restrict__ QLC,
    const unsigned short* __restrict__ KC,  const unsigned short* __restrict__ VC,
    const void* __restrict__ mask,
    const float* __restrict__ WO, const float* __restrict__ bO,
    const float* __restrict__ resid,
    float* __restrict__ sa_out, float* __restrict__ out0)
{
    constexpr int SEGLEN = 1024;
    constexpr int NPT    = SEGLEN / 64;     // 16 pairs per segment
    __shared__ unsigned long long mpk[2][2][32][5];  // [buf][seg][row][c(+pad)]
    __shared__ float ctx_lds[2][32][33];    // [seg][tok][col], padded
    __shared__ float l_lds[2][32][4];       // [seg][tok][head]
    __shared__ float sa_lds[32][33];
    __shared__ float Ws[32][32];

    int raw  = blockIdx.x;                  // 512 blocks
    int cid  = (raw & 7) * 64 + (raw >> 3); // XCD-contiguous (batch==XCD)
    int b    = cid >> 6;
    int qt   = cid & 63;
    int tid  = threadIdx.x;
    int w    = tid >> 6;                    // wave 0..7
    int h    = w & 3;
    int seg  = w >> 2;
    int lane = tid & 63;
    int q    = lane & 31;
    int half = lane >> 5;
    int tok0 = qt * 32;
    long tokbase = (long)b * S_LEN + tok0;
    long tokq    = tokbase + q;
    int k0   = seg * SEGLEN;
    int ch0  = k0 >> 5;

    // stage WO (consumed only after the final barrier)
#pragma unroll
    for (int i = 0; i < 2; ++i) {
        int f = i * 512 + tid;
        Ws[f >> 5][f & 31] = WO[f];
    }

    // mask dtype probe (proven ballot pattern)
    int probe = ((const int*)mask)[lane];
    bool is32 = (__ballot((probe & ~0xFF) == 0) == ~0ULL);

    // ---- pack one 256-key group (both segments) for this block's 32 rows.
    // word (seg,row,c) bit L = mask[row][seg*1024 + g*256 + 4L + c]
    // wave w packs rows 4w..4w+3.
    auto pack_group = [&](int g, int buf) {
#pragma unroll
        for (int i = 0; i < 4; ++i) {
            int r = (w << 2) + i;
            if (is32) {
                const int4* rp = (const int4*)((const int*)mask
                                               + (tokbase + r) * (long)S_LEN);
#pragma unroll
                for (int s2 = 0; s2 < 2; ++s2) {
                    int4 v = rp[s2 * 256 + g * 64 + lane];
                    unsigned long long b0 = __ballot(v.x != 0);
                    unsigned long long b1 = __ballot(v.y != 0);
                    unsigned long long b2 = __ballot(v.z != 0);
                    unsigned long long b3 = __ballot(v.w != 0);
                    if (lane == 0) {
                        mpk[buf][s2][r][0] = b0; mpk[buf][s2][r][1] = b1;
                        mpk[buf][s2][r][2] = b2; mpk[buf][s2][r][3] = b3;
                    }
                }
            } else {
                const int* rp = (const int*)((const unsigned char*)mask
                                             + (tokbase + r) * (long)S_LEN);
#pragma unroll
                for (int s2 = 0; s2 < 2; ++s2) {
                    int v = rp[s2 * 256 + g * 64 + lane];
                    unsigned long long b0 = __ballot((v & 0x000000FF) != 0);
                    unsigned long long b1 = __ballot((v & 0x0000FF00) != 0);
                    unsigned long long b2 = __ballot((v & 0x00FF0000) != 0);
                    unsigned long long b3 = __ballot((v & 0xFF000000u) != 0);
                    if (lane == 0) {
                        mpk[buf][s2][r][0] = b0; mpk[buf][s2][r][1] = b1;
                        mpk[buf][s2][r][2] = b2; mpk[buf][s2][r][3] = b3;
                    }
                }
            }
        }
    };

    f32x16 zero16;
#pragma unroll
    for (int i = 0; i < 16; ++i) zero16[i] = 0.0f;

    short ovv = (q == 8) ? (short)0x3F80 : (short)0;
    short8b ovf;
#pragma unroll
    for (int i = 0; i < 8; ++i) ovf[i] = ovv;

    size_t qoff = ((((size_t)b * 64 + qt) * 4 + h) * 32 + q) * 8;
    short8b qhf = *(const short8b*)(QHC + qoff);
    short8b qlf = *(const short8b*)(QLC + qoff);
    f32x16 cpv = zero16;

    const unsigned short* Kb0 = KC + (((size_t)b * 64) * 4 + h) * 512
                                   + (size_t)half * 256 + (size_t)q * 8;
    const unsigned short* Vb0 = VC + (((size_t)b * 64) * 4 + h) * 256
                                   + (size_t)q * 32 + half * 4;  // valid q<8

    short8b kfA = *(const short8b*)(Kb0 + (size_t)ch0 * 2048);
    short8b kfB = *(const short8b*)(Kb0 + (size_t)(ch0 + 1) * 2048);
    short8b vf1c, vf2c;
    if (q < 8) {
        const unsigned short* vr = Vb0 + (size_t)ch0 * 1024;
        short4b a0 = *(const short4b*)(vr);
        short4b a1 = *(const short4b*)(vr + 8);
        short4b a2 = *(const short4b*)(vr + 16);
        short4b a3 = *(const short4b*)(vr + 24);
        vf1c = __builtin_shufflevector(a0, a1, 0, 1, 2, 3, 4, 5, 6, 7);
        vf2c = __builtin_shufflevector(a2, a3, 0, 1, 2, 3, 4, 5, 6, 7);
    } else { vf1c = ovf; vf2c = ovf; }

    // prologue: pack group 0 into buffer 0
    pack_group(0, 0);
    __syncthreads();

#pragma unroll 1
    for (int g = 0; g < 4; ++g) {
        int cur = g & 1;

        // pack next group into the other buffer (overlaps with compute below)
        if (g + 1 < 4) pack_group(g + 1, cur ^ 1);

        unsigned long long mg[4];
        mg[0] = mpk[cur][seg][q][0];
        mg[1] = mpk[cur][seg][q][1];
        mg[2] = mpk[cur][seg][q][2];
        mg[3] = mpk[cur][seg][q][3];

#pragma unroll 1
        for (int p = 0; p < 4; ++p) {
            int pa  = g * 4 + p;
            int chA = ch0 + 2 * pa;
            int chB = chA + 1;

            short8b kfA_n = kfA, kfB_n = kfB;
            if (pa + 1 < NPT) {
                kfA_n = *(const short8b*)(Kb0 + (size_t)(chA + 2) * 2048);
                kfB_n = *(const short8b*)(Kb0 + (size_t)(chB + 2) * 2048);
            }

            unsigned shA = (unsigned)(p * 16 + half);
            unsigned nA[4], nB[4];
#pragma unroll
            for (int c = 0; c < 4; ++c) {
                nA[c] = (unsigned)(mg[c] >> shA);
                nB[c] = (unsigned)(mg[c] >> (shA + 8u));
            }

            __builtin_amdgcn_s_setprio(1);
            f32x16 accA = __builtin_amdgcn_mfma_f32_32x32x16_bf16(kfA, qhf, zero16, 0, 0, 0);
            f32x16 accB = __builtin_amdgcn_mfma_f32_32x32x16_bf16(kfB, qhf, zero16, 0, 0, 0);
            accA = __builtin_amdgcn_mfma_f32_32x32x16_bf16(kfA, qlf, accA, 0, 0, 0);
            accB = __builtin_amdgcn_mfma_f32_32x32x16_bf16(kfB, qlf, accB, 0, 0, 0);
            __builtin_amdgcn_s_setprio(0);

            short8b vf1n, vf2n;
            if (q < 8) {
                const unsigned short* vr = Vb0 + (size_t)chB * 1024;
                short4b a0 = *(const short4b*)(vr);
                short4b a1 = *(const short4b*)(vr + 8);
                short4b a2 = *(const short4b*)(vr + 16);
                short4b a3 = *(const short4b*)(vr + 24);
                vf1n = __builtin_shufflevector(a0, a1, 0, 1, 2, 3, 4, 5, 6, 7);
                vf2n = __builtin_shufflevector(a2, a3, 0, 1, 2, 3, 4, 5, 6, 7);
            } else { vf1n = ovf; vf2n = ovf; }

            {
                unsigned pr[8];
#pragma unroll
                for (int j = 0; j < 8; ++j) {
                    const int c0 = (2 * j) & 3, c1 = (2 * j + 1) & 3;
                    const int s  = 2 * (j >> 1);
                    float p0 = ((nA[c0] >> s) & 1u) ? 0.0f
                             : __builtin_amdgcn_exp2f(accA[2 * j]);
                    float p1 = ((nA[c1] >> s) & 1u) ? 0.0f
                             : __builtin_amdgcn_exp2f(accA[2 * j + 1]);
                    pr[j] = cvtpk_bf16(p0, p1);
                }
                uint4v t1, t2;
                t1.x = pr[0]; t1.y = pr[1]; t1.z = pr[2]; t1.w = pr[3];
                t2.x = pr[4]; t2.y = pr[5]; t2.z = pr[6]; t2.w = pr[7];
                short8b pfa = __builtin_bit_cast(short8b, t1);
                short8b pfb = __builtin_bit_cast(short8b, t2);

                __builtin_amdgcn_s_setprio(1);
                cpv = __builtin_amdgcn_mfma_f32_32x32x16_bf16(vf1c, pfa, cpv, 0, 0, 0);
                cpv = __builtin_amdgcn_mfma_f32_32x32x16_bf16(vf2c, pfb, cpv, 0, 0, 0);
                __builtin_amdgcn_s_setprio(0);
            }

            short8b vf1nn, vf2nn;
            if (pa + 1 < NPT && q < 8) {
                const unsigned short* vr = Vb0 + (size_t)(chA + 2) * 1024;
                short4b a0 = *(const short4b*)(vr);
                short4b a1 = *(const short4b*)(vr + 8);
                short4b a2 = *(const short4b*)(vr + 16);
                short4b a3 = *(const short4b*)(vr + 24);
                vf1nn = __builtin_shufflevector(a0, a1, 0, 1, 2, 3, 4, 5, 6, 7);
                vf2nn = __builtin_shufflevector(a2, a3, 0, 1, 2, 3, 4, 5, 6, 7);
            } else { vf1nn = ovf; vf2nn = ovf; }

            {
                unsigned pr[8];
#pragma unroll
                for (int j = 0; j < 8; ++j) {
                    const int c0 = (2 * j) & 3, c1 = (2 * j + 1) & 3;
                    const int s  = 2 * (j >> 1);
                    float p0 = ((nB[c0] >> s) & 1u) ? 0.0f
                             : __builtin_amdgcn_exp2f(accB[2 * j]);
                    float p1 = ((nB[c1] >> s) & 1u) ? 0.0f
                             : __builtin_amdgcn_exp2f(accB[2 * j + 1]);
                    pr[j] = cvtpk_bf16(p0, p1);
                }
                uint4v t1, t2;
                t1.x = pr[0]; t1.y = pr[1]; t1.z = pr[2]; t1.w = pr[3];
                t2.x = pr[4]; t2.y = pr[5]; t2.z = pr[6]; t2.w = pr[7];
                short8b pfa = __builtin_bit_cast(short8b, t1);
                short8b pfb = __builtin_bit_cast(short8b, t2);

                __builtin_amdgcn_s_setprio(1);
                cpv = __builtin_amdgcn_mfma_f32_32x32x16_bf16(vf1n, pfa, cpv, 0, 0, 0);
                cpv = __builtin_amdgcn_mfma_f32_32x32x16_bf16(vf2n, pfb, cpv, 0, 0, 0);
                __builtin_amdgcn_s_setprio(0);
            }

            kfA = kfA_n;
            kfB = kfB_n;
            vf1c = vf1nn;
            vf2c = vf2nn;
        }

        __syncthreads();   // next group's pack complete; gs compute reads done
    }

    // ---- exchange partials through LDS (C_PV: col=q; rows per C/D formula)
    ctx_lds[seg][q][h * 8 + half * 4 + 0] = cpv[0];
    ctx_lds[seg][q][h * 8 + half * 4 + 1] = cpv[1];
    ctx_lds[seg][q][h * 8 + half * 4 + 2] = cpv[2];
    ctx_lds[seg][q][h * 8 + half * 4 + 3] = cpv[3];
    if (half == 0) l_lds[seg][q][h] = cpv[4];
    __syncthreads();

    // ---- combine + sa write (32 tokens x 32 cols; 512 threads, 2 passes)
    int r = (tid >> 5) & 15;
    int j = tid & 31;
#pragma unroll
    for (int pass = 0; pass < 2; ++pass) {
        int tok = pass * 16 + r;
        float L  = l_lds[0][tok][j >> 3] + l_lds[1][tok][j >> 3];
        float cx = ctx_lds[0][tok][j] + ctx_lds[1][tok][j];
        float sa = cx / L;
        sa_lds[tok][j] = sa;
        sa_out[(tokbase + tok) * 32 + j] = sa;
    }
    __syncthreads();

    // ---- O-projection + residual + LayerNorm
#pragma unroll
    for (int pass = 0; pass < 2; ++pass) {
        int tok = pass * 16 + r;
        long grow = (tokbase + tok) * 32;
        float y = bO[j] + resid[grow + j];
#pragma unroll
        for (int i = 0; i < 32; ++i) y = fmaf(sa_lds[tok][i], Ws[i][j], y);

        float sum = y;
#pragma unroll
        for (int o = 16; o >= 1; o >>= 1) sum += __shfl_xor(sum, o, 32);
        float mu = sum * (1.0f / 32.0f);
        float d  = y - mu;
        float sq = d * d;
#pragma unroll
        for (int o = 16; o >= 1; o >>= 1) sq += __shfl_xor(sq, o, 32);
        float var = sq * (1.0f / 32.0f);
        out0[grow + j] = d * rsqrtf(var + LN_EPS);
    }
}

// ---------------------------------------------------------------------------
extern "C" void kernel_launch(void* const* d_in, const int* in_sizes, int n_in,
                              void* d_out, int out_size, void* d_ws, size_t ws_size,
                              hipStream_t stream)
{
    const float* inQ = (const float*)d_in[0];
    const float* inK = (const float*)d_in[1];
    const float* inV = (const float*)d_in[2];
    const void*  mask = d_in[3];
    const float* WQ = (const float*)d_in[4];
    const float* bQ = (const float*)d_in[5];
    const float* WK = (const float*)d_in[6];
    const float* bK = (const float*)d_in[7];
    const float* WV = (const float*)d_in[8];
    const float* bV = (const float*)d_in[9];
    const float* WO = (const float*)d_in[10];
    const float* bO = (const float*)d_in[11];

    float* out0 = (float*)d_out;                    // layernorm output
    float* sa   = (float*)d_out + (long)NTOK * 32;  // self_attn output

    char* ws = (char*)d_ws;
    unsigned short* QHC = (unsigned short*)(ws + 256);
    unsigned short* QLC = QHC + (size_t)NTOK * 32;
    unsigned short* KC  = QLC + (size_t)NTOK * 32;
    unsigned short* VC  = KC  + (size_t)NTOK * 64;

    prep_kernel<<<3 * PROJ_BLKS, 256, 0, stream>>>(
        inQ, inK, inV, WQ, bQ, WK, bK, WV, bV, QHC, QLC, KC, VC);

    attn_fused_kernel<<<B_SZ * 64, 512, 0, stream>>>(
        QHC, QLC, KC, VC, mask, WO, bO, inQ, sa, out0);
}